// Round 7
// baseline (524.036 us; speedup 1.0000x reference)
//
#include <hip/hip_runtime.h>

// RWKV7 attention block, MI355X/gfx950.
// B=1, T=1024, C=2048, H=32, N=64. All inputs/outputs f32.
// Big GEMM step-7 v4: BM=BN=128, 3-buffer counted-vmcnt(4) pipeline +
// slot-XOR swizzle (R6: left top-5, <74us). Step-11: BN=64 variant.
// WKV scan v9: segmented two-pass, 16 SEGMENTS of 64 steps (was 8x128).
// R6 measured p2 at 1412 cy/step with 1 wave/SIMD (1 block/CU) -> ~1000
// cy/step exposed stall. 16 segs: p2 = 512 blocks (2/CU, 2 waves/SIMD,
// half the critical path), p1 = 480 blocks, comb widened to 1024 thr.
// Buffers fit dead slots exactly: Send->S1, Pend->xkH+xvH, Sin->xrgH+xwaH.
// k_fuse v2: t-tile 4, 2048 blocks.

#define T_ 1024
#define C_ 2048
#define H_ 32
#define N_ 64

using half8  = __attribute__((ext_vector_type(8))) _Float16;  // 8 f16 (4 VGPRs)
using half4  = __attribute__((ext_vector_type(4))) _Float16;  // 8 B
using floatx4 = __attribute__((ext_vector_type(4))) float;    // 4 f32 acc

// DPP xor-add within 16-lane rows: quad_perm(0xB1)=xor1, quad_perm(0x4E)=xor2,
// row_half_mirror(0x141)=xor4, row_mirror(0x140)=xor8.
#define DPP_ADD(v, ctrl) \
    ((v) + __int_as_float(__builtin_amdgcn_update_dpp( \
        0, __float_as_int(v), (ctrl), 0xf, 0xf, true)))
#define REDUCE16(v) do { \
    v = DPP_ADD(v, 0xB1); v = DPP_ADD(v, 0x4E); \
    v = DPP_ADD(v, 0x141); v = DPP_ADD(v, 0x140); } while (0)

// async 16B global->LDS (direct-to-LDS DMA; HW dest = wave base + lane*16,
// all call sites construct per-lane lds ptrs matching exactly that layout)
__device__ __forceinline__ void async_cp16(const void* g, void* l) {
    __builtin_amdgcn_global_load_lds(
        (const __attribute__((address_space(1))) void*)g,
        (__attribute__((address_space(3))) void*)l, 16, 0, 0);
}

// ---------------------------------------------------------------------------
// Transpose + convert big weights: W[k][n] f32 -> WT[n][k] f16
// ---------------------------------------------------------------------------
__global__ __launch_bounds__(256) void k_tr(
    const float* __restrict__ W0, const float* __restrict__ W1,
    const float* __restrict__ W2, const float* __restrict__ W3,
    _Float16* __restrict__ D0, _Float16* __restrict__ D1,
    _Float16* __restrict__ D2, _Float16* __restrict__ D3)
{
    const int z = blockIdx.z;
    const float* S = (z == 0) ? W0 : (z == 1) ? W1 : (z == 2) ? W2 : W3;
    _Float16* D = (z == 0) ? D0 : (z == 1) ? D1 : (z == 2) ? D2 : D3;
    const int nb = blockIdx.x * 64, kb = blockIdx.y * 64;
    __shared__ __align__(16) float tile[64][65];
    const int tr = threadIdx.x >> 4, tc4 = (threadIdx.x & 15) * 4;
#pragma unroll
    for (int p = 0; p < 4; ++p) {
        int row = p * 16 + tr;
        float4 v = *(const float4*)&S[(size_t)(kb + row) * C_ + nb + tc4];
        tile[row][tc4 + 0] = v.x; tile[row][tc4 + 1] = v.y;
        tile[row][tc4 + 2] = v.z; tile[row][tc4 + 3] = v.w;
    }
    __syncthreads();
#pragma unroll
    for (int p = 0; p < 4; ++p) {
        int n = p * 16 + tr;
        half4 u;
        u[0] = (_Float16)tile[tc4 + 0][n];
        u[1] = (_Float16)tile[tc4 + 1][n];
        u[2] = (_Float16)tile[tc4 + 2][n];
        u[3] = (_Float16)tile[tc4 + 3][n];
        *(half4*)&D[(size_t)(nb + n) * C_ + kb + tc4] = u;
    }
}

// ---------------------------------------------------------------------------
// Pack+transpose LoRA weights to f16 WT[n][k].
// z=0: WT_m [128][2048] <- maa_w1[2048,128]
// z=1: WT_l [256][2048] <- gate(128) | decay(64) | aaa(16) | ma(16) | kkk(16) | mk(16)
// ---------------------------------------------------------------------------
__global__ __launch_bounds__(256) void k_trW(
    const float* __restrict__ maa_w1, const float* __restrict__ gate_w1,
    const float* __restrict__ decay_w1, const float* __restrict__ aaa_w1,
    const float* __restrict__ ma_w1, const float* __restrict__ kkk_w1,
    const float* __restrict__ mk_w1,
    _Float16* __restrict__ WTm, _Float16* __restrict__ WTl)
{
    const int z = blockIdx.z;
    const int k = blockIdx.x * 256 + threadIdx.x;   // 0..2047
    const int n = blockIdx.y;
    if (z == 0 && n >= 128) return;
    const float* src; int stride, col;
    _Float16* dst;
    if (z == 0) { src = maa_w1; stride = 128; col = n; dst = WTm; }
    else {
        dst = WTl;
        if (n < 128)      { src = gate_w1;  stride = 128; col = n; }
        else if (n < 192) { src = decay_w1; stride = 64;  col = n - 128; }
        else if (n < 208) { src = aaa_w1;   stride = 16;  col = n - 192; }
        else if (n < 224) { src = ma_w1;    stride = 16;  col = n - 208; }
        else if (n < 240) { src = kkk_w1;   stride = 16;  col = n - 224; }
        else              { src = mk_w1;    stride = 16;  col = n - 240; }
    }
    dst[(size_t)n * C_ + k] = (_Float16)src[(size_t)k * stride + col];
}

// ---------------------------------------------------------------------------
// xxxH = f16( x + (x_prev - x) * maa_x )
// ---------------------------------------------------------------------------
__global__ __launch_bounds__(256) void k_prep(
    const float* __restrict__ X, const float* __restrict__ maa_x,
    _Float16* __restrict__ xxxH)
{
    const size_t idx = (size_t)blockIdx.x * 256 + threadIdx.x;
    const int c = (int)(idx & (C_ - 1));
    float cur = X[idx];
    float prev = (idx >= C_) ? X[idx - C_] : 0.0f;
    xxxH[idx] = (_Float16)(cur + (prev - cur) * maa_x[c]);
}

// ---------------------------------------------------------------------------
// LoRA MFMA GEMM, split-K -> per-split partials (deterministic; no atomics).
// BM=64, BN=32, BK=32, ksplit=4.
// which=0: m1p[ks][1024][128] = xxxH @ WTm^T (4 n-tiles)
// which=1: l2p[ks][1024][256], A per n-tile: 0-3 xrg | 4-6 xwa | 7 xk
// ---------------------------------------------------------------------------
__global__ __launch_bounds__(256) void k_lora(
    int which,
    const _Float16* __restrict__ Axxx, const _Float16* __restrict__ Axrg,
    const _Float16* __restrict__ Axwa, const _Float16* __restrict__ Axk,
    const _Float16* __restrict__ WTm, const _Float16* __restrict__ WTl,
    float* __restrict__ m1p, float* __restrict__ l2p)
{
    const int mt = blockIdx.x;      // 16 tiles of 64 rows
    const int nt = blockIdx.y;      // tiles of 32 cols
    const int ks = blockIdx.z;      // 4 K-chunks of 512
    const _Float16* A; const _Float16* BT; float* O; int ostride;
    if (which == 0) { A = Axxx; BT = WTm; O = m1p; ostride = 128; }
    else {
        BT = WTl; O = l2p; ostride = 256;
        A = (nt < 4) ? Axrg : (nt < 7) ? Axwa : Axk;
    }
    O += (size_t)ks * T_ * ostride;
    const int m0 = mt * 64, n0 = nt * 32, k0 = ks * 512;
    const int tid = threadIdx.x;
    __shared__ __align__(16) _Float16 As[64 * 40];
    __shared__ __align__(16) _Float16 Bs[32 * 40];
    const int lane = tid & 63, wv = tid >> 6;
    const int r16 = lane & 15, q = lane >> 4;

    floatx4 acc[2];
    { floatx4 zv = {0.f, 0.f, 0.f, 0.f}; acc[0] = zv; acc[1] = zv; }

    const int arow = tid >> 2, ac8 = (tid & 3) * 8;
    const _Float16* ag = A + (size_t)(m0 + arow) * C_ + k0 + ac8;
    const _Float16* bg = BT + (size_t)(n0 + (tid >> 2)) * C_ + k0 + ac8;

    for (int kc = 0; kc < 512; kc += 32) {
        half8 av = *(const half8*)(ag + kc);
        half8 bv;
        if (tid < 128) bv = *(const half8*)(bg + kc);
        *(half8*)&As[arow * 40 + ac8] = av;
        if (tid < 128) *(half8*)&Bs[(tid >> 2) * 40 + ac8] = bv;
        __syncthreads();
        half8 af = *(const half8*)&As[(wv * 16 + r16) * 40 + q * 8];
        half8 b0 = *(const half8*)&Bs[(r16) * 40 + q * 8];
        half8 b1 = *(const half8*)&Bs[(16 + r16) * 40 + q * 8];
        acc[0] = __builtin_amdgcn_mfma_f32_16x16x32_f16(af, b0, acc[0], 0, 0, 0);
        acc[1] = __builtin_amdgcn_mfma_f32_16x16x32_f16(af, b1, acc[1], 0, 0, 0);
        __syncthreads();
    }
#pragma unroll
    for (int j = 0; j < 2; ++j)
#pragma unroll
        for (int e = 0; e < 4; ++e) {
            int row = m0 + wv * 16 + q * 4 + e;
            int col = n0 + j * 16 + r16;
            O[(size_t)row * ostride + col] = acc[j][e];
        }
}

// ---------------------------------------------------------------------------
// xmix: m1 = sum_ks(m1p), tanh; mix = einsum(m1[T,4,32], maa_w2[4,32,C]);
// emit f16 GEMM operands xrgH/xwaH/xkH/xvH.
// ---------------------------------------------------------------------------
__global__ __launch_bounds__(256) void k_xmix(
    const float* __restrict__ X, const float* __restrict__ m1p,
    const float* __restrict__ w2,
    const float* __restrict__ mrg, const float* __restrict__ mwa,
    const float* __restrict__ mk, const float* __restrict__ mv,
    _Float16* __restrict__ xrgH, _Float16* __restrict__ xwaH,
    _Float16* __restrict__ xkH, _Float16* __restrict__ xvH)
{
    const int tid = threadIdx.x;
    const int c = blockIdx.x * 256 + tid;
    const int t0 = blockIdx.y * 16;
    const size_t P = (size_t)T_ * 128;
    __shared__ __align__(16) float m1s[16][128];
#pragma unroll
    for (int p = 0; p < 2; ++p) {
        int id = tid + p * 256;
        int r = id >> 5, c4 = (id & 31) * 4;
        size_t off = (size_t)(t0 + r) * 128 + c4;
        float4 v0 = *(const float4*)&m1p[off];
        float4 v1 = *(const float4*)&m1p[P + off];
        float4 v2 = *(const float4*)&m1p[2 * P + off];
        float4 v3 = *(const float4*)&m1p[3 * P + off];
        float4 v;
        v.x = tanhf(((v0.x + v1.x) + v2.x) + v3.x);
        v.y = tanhf(((v0.y + v1.y) + v2.y) + v3.y);
        v.z = tanhf(((v0.z + v1.z) + v2.z) + v3.z);
        v.w = tanhf(((v0.w + v1.w) + v2.w) + v3.w);
        *(float4*)&m1s[r][c4] = v;
    }
    __syncthreads();
    float a0[16], a1[16], a2[16], a3[16];
#pragma unroll
    for (int t = 0; t < 16; ++t) { a0[t] = 0.f; a1[t] = 0.f; a2[t] = 0.f; a3[t] = 0.f; }
    for (int d = 0; d < 32; ++d) {
        float w0 = w2[(size_t)(0 * 32 + d) * C_ + c];
        float w1 = w2[(size_t)(1 * 32 + d) * C_ + c];
        float w2v = w2[(size_t)(2 * 32 + d) * C_ + c];
        float w3 = w2[(size_t)(3 * 32 + d) * C_ + c];
#pragma unroll
        for (int t = 0; t < 16; ++t) {
            a0[t] = fmaf(m1s[t][d],      w0,  a0[t]);
            a1[t] = fmaf(m1s[t][32 + d], w1,  a1[t]);
            a2[t] = fmaf(m1s[t][64 + d], w2v, a2[t]);
            a3[t] = fmaf(m1s[t][96 + d], w3,  a3[t]);
        }
    }
    float vrg = mrg[c], vwa = mwa[c], vmk = mk[c], vmv = mv[c];
    float prev = (t0 > 0) ? X[(size_t)(t0 - 1) * C_ + c] : 0.0f;
    for (int t = 0; t < 16; ++t) {
        size_t idx = (size_t)(t0 + t) * C_ + c;
        float cur = X[idx];
        float dx = prev - cur;
        xrgH[idx] = (_Float16)(cur + dx * (vrg + a0[t]));
        xwaH[idx] = (_Float16)(cur + dx * (vwa + a1[t]));
        xkH[idx]  = (_Float16)(cur + dx * (vmk + a2[t]));
        xvH[idx]  = (_Float16)(cur + dx * (vmv + a3[t]));
        prev = cur;
    }
}

// ---------------------------------------------------------------------------
// f16 MFMA GEMM v4 (step 7): C[1024,2048] = A(f16) @ W via WT[n][k] f16.
// BM=BN=128, BK=32, 256 thr (4 waves 2x2), 4x4 16x16x32 tiles/wave.
// 3-buffer counted-vmcnt depth-2 pipeline + slot-XOR swizzle.
// ---------------------------------------------------------------------------
__global__ __launch_bounds__(256) void k_gemm(
    const _Float16* __restrict__ A0, const _Float16* __restrict__ B0, float* __restrict__ C0,
    const _Float16* __restrict__ A1, const _Float16* __restrict__ B1, float* __restrict__ C1,
    const _Float16* __restrict__ A2, const _Float16* __restrict__ B2, float* __restrict__ C2)
{
    const int z = blockIdx.z;
    const _Float16* A = (z == 0) ? A0 : (z == 1) ? A1 : A2;
    const _Float16* Bt = (z == 0) ? B0 : (z == 1) ? B1 : B2;
    float* C = (z == 0) ? C0 : (z == 1) ? C1 : C2;
    const int mtile = blockIdx.y * 128;
    const int ntile = blockIdx.x * 128;
    const int tid = threadIdx.x;
    __shared__ __align__(16) _Float16 As[3][128 * 32];
    __shared__ __align__(16) _Float16 Bs[3][128 * 32];
    const int lane = tid & 63;
    const int wvid = tid >> 6;
    const int wm = wvid >> 1, wn = wvid & 1;
    const int r16 = lane & 15, q = lane >> 4;
    // read-side swizzled slot offset (halfwords). (row>>1)&3 == (r16>>1)&3 for
    // every fragment row (wm*64, i*16, wn*64, j*16 all vanish in bits 1..2).
    const int qs = (q ^ ((r16 >> 1) & 3)) * 8;

    floatx4 acc[4][4];
#pragma unroll
    for (int i = 0; i < 4; ++i)
#pragma unroll
        for (int j = 0; j < 4; ++j) { floatx4 zv = {0.f, 0.f, 0.f, 0.f}; acc[i][j] = zv; }

    const int srow = tid >> 2, sq = tid & 3;
    const int sqg = (sq ^ ((srow >> 1) & 3)) * 8;   // inverse swizzle on source
    const _Float16* agA = A + (size_t)(mtile + srow) * C_ + sqg;
    const _Float16* agB = Bt + (size_t)(ntile + srow) * C_ + sqg;
    const int ldso = srow * 32 + sq * 8;            // linear DMA dest (tid*16B)
    const size_t rowoff = (size_t)64 * C_;          // (srow+64): same swizzle

    // 4 async_cp16 per stage per thread => vmcnt counts in units of 4.
#define G_STAGE(pb, koff) do {                                                \
        async_cp16(agA + (koff), &As[pb][ldso]);                              \
        async_cp16(agA + (koff) + rowoff, &As[pb][ldso + 64 * 32]);           \
        async_cp16(agB + (koff), &Bs[pb][ldso]);                              \
        async_cp16(agB + (koff) + rowoff, &Bs[pb][ldso + 64 * 32]);           \
    } while (0)

    G_STAGE(0, 0);
    G_STAGE(1, 32);
    __builtin_amdgcn_sched_barrier(0);
    asm volatile("s_waitcnt vmcnt(4)" ::: "memory");   // buf0 landed
    __builtin_amdgcn_s_barrier();
    __builtin_amdgcn_sched_barrier(0);

    for (int ks = 0; ks < 64; ++ks) {
        const int p = ks % 3;
        if (ks + 2 < 64) G_STAGE((ks + 2) % 3, (ks + 2) * 32);
        half8 af[4], bf[4];
#pragma unroll
        for (int i = 0; i < 4; ++i)
            af[i] = *(const half8*)&As[p][(wm * 64 + i * 16 + r16) * 32 + qs];
#pragma unroll
        for (int j = 0; j < 4; ++j)
            bf[j] = *(const half8*)&Bs[p][(wn * 64 + j * 16 + r16) * 32 + qs];
#pragma unroll
        for (int i = 0; i < 4; ++i)
#pragma unroll
            for (int j = 0; j < 4; ++j)
                acc[i][j] = __builtin_amdgcn_mfma_f32_16x16x32_f16(af[i], bf[j], acc[i][j], 0, 0, 0);
        __builtin_amdgcn_sched_barrier(0);
        if (ks + 2 < 64)
            asm volatile("s_waitcnt vmcnt(4)" ::: "memory");  // (k+1) landed
        else
            asm volatile("s_waitcnt vmcnt(0)" ::: "memory");  // tail drain
        __builtin_amdgcn_s_barrier();
        __builtin_amdgcn_sched_barrier(0);
    }
    // C/D layout: col = lane&15, row = (lane>>4)*4 + reg
#pragma unroll
    for (int i = 0; i < 4; ++i)
#pragma unroll
        for (int j = 0; j < 4; ++j)
#pragma unroll
            for (int e = 0; e < 4; ++e) {
                int row = mtile + wm * 64 + i * 16 + q * 4 + e;
                int col = ntile + wn * 64 + j * 16 + r16;
                C[(size_t)row * C_ + col] = acc[i][j][e];
            }
#undef G_STAGE
}

// ---------------------------------------------------------------------------
// f16 MFMA GEMM BN=64 variant (step 11; 256 blocks = 1/CU there, vs 128 for
// the 128^2 tile which would idle half the CUs). R5-verified code.
// ---------------------------------------------------------------------------
__global__ __launch_bounds__(256) void k_gemm64(
    const _Float16* __restrict__ A0, const _Float16* __restrict__ B0, float* __restrict__ C0)
{
    const _Float16* A = A0;
    const _Float16* Bt = B0;
    float* C = C0;
    const int mtile = blockIdx.y * 128;
    const int ntile = blockIdx.x * 64;
    const int tid = threadIdx.x;
    __shared__ __align__(16) _Float16 As[3][128 * 32];
    __shared__ __align__(16) _Float16 Bs[3][64 * 32];
    const int lane = tid & 63;
    const int wvid = tid >> 6;
    const int wm = wvid >> 1, wn = wvid & 1;
    const int r16 = lane & 15, q = lane >> 4;
    const int qs = (q ^ ((r16 >> 1) & 3)) * 8;

    floatx4 acc[4][2];
#pragma unroll
    for (int i = 0; i < 4; ++i)
#pragma unroll
        for (int j = 0; j < 2; ++j) { floatx4 zv = {0.f, 0.f, 0.f, 0.f}; acc[i][j] = zv; }

    const int srow = tid >> 2, sq = tid & 3;
    const int sqg = (sq ^ ((srow >> 1) & 3)) * 8;
    const _Float16* agA = A + (size_t)(mtile + srow) * C_ + sqg;
    const _Float16* agB = Bt + (size_t)(ntile + srow) * C_ + sqg;
    const int ldso = srow * 32 + sq * 8;
    const size_t rowoff = (size_t)64 * C_;

#define G_STAGE(pb, koff) do {                                                \
        async_cp16(agA + (koff), &As[pb][ldso]);                              \
        async_cp16(agA + (koff) + rowoff, &As[pb][ldso + 64 * 32]);           \
        async_cp16(agB + (koff), &Bs[pb][ldso]);                              \
    } while (0)

    G_STAGE(0, 0);
    G_STAGE(1, 32);
    __builtin_amdgcn_sched_barrier(0);
    asm volatile("s_waitcnt vmcnt(3)" ::: "memory");
    __builtin_amdgcn_s_barrier();
    __builtin_amdgcn_sched_barrier(0);

    for (int ks = 0; ks < 64; ++ks) {
        const int p = ks % 3;
        if (ks + 2 < 64) G_STAGE((ks + 2) % 3, (ks + 2) * 32);
        half8 af[4], bf[2];
#pragma unroll
        for (int i = 0; i < 4; ++i)
            af[i] = *(const half8*)&As[p][(wm * 64 + i * 16 + r16) * 32 + qs];
#pragma unroll
        for (int j = 0; j < 2; ++j)
            bf[j] = *(const half8*)&Bs[p][(wn * 32 + j * 16 + r16) * 32 + qs];
#pragma unroll
        for (int i = 0; i < 4; ++i)
#pragma unroll
            for (int j = 0; j < 2; ++j)
                acc[i][j] = __builtin_amdgcn_mfma_f32_16x16x32_f16(af[i], bf[j], acc[i][j], 0, 0, 0);
        __builtin_amdgcn_sched_barrier(0);
        if (ks + 2 < 64)
            asm volatile("s_waitcnt vmcnt(3)" ::: "memory");
        else
            asm volatile("s_waitcnt vmcnt(0)" ::: "memory");
        __builtin_amdgcn_s_barrier();
        __builtin_amdgcn_sched_barrier(0);
    }
#pragma unroll
    for (int i = 0; i < 4; ++i)
#pragma unroll
        for (int j = 0; j < 2; ++j)
#pragma unroll
            for (int e = 0; e < 4; ++e) {
                int row = mtile + wm * 64 + i * 16 + q * 4 + e;
                int col = ntile + wn * 32 + j * 16 + r16;
                C[(size_t)row * C_ + col] = acc[i][j][e];
            }
#undef G_STAGE
}

// ---------------------------------------------------------------------------
// Fused stage-2 v2: dec=exp(w), kk (normalized), b = kk*a, k_final.
// t-tile 4 (grid 8x256 = 2048 blocks -> 8 blocks/CU). l2p partials
// [4][T][256]: cols 128-191 decay(tanh) | 192-207 aaa | 208-223 ma |
// 224-239 kkk(tanh) | 240-255 mk. Fixed-order reduce.
// ---------------------------------------------------------------------------
__global__ __launch_bounds__(256) void k_fuse(
    const float* __restrict__ l2p,
    float* __restrict__ K0,
    const float* __restrict__ decay_w2, const float* __restrict__ aaa_w2,
    const float* __restrict__ ma_w2, const float* __restrict__ kkk_w2,
    const float* __restrict__ mk_w2,
    const float* __restrict__ tdecay, const float* __restrict__ aaaaa,
    const float* __restrict__ misc_a, const float* __restrict__ misc_k,
    float* __restrict__ Dout, float* __restrict__ KKout, float* __restrict__ Bout)
{
    const int tid = threadIdx.x;
    const int c = blockIdx.x * 256 + tid;
    const int t0 = blockIdx.y * 4;
    const size_t P = (size_t)T_ * 256;
    __shared__ __align__(16) float wsS[4][96];   // decay64 | aaa16 | ma16
    __shared__ __align__(16) float ksS[4][32];   // kkk16 | mk16
    if (tid < 4 * 24) {
        int r = tid / 24, c4 = (tid % 24) * 4;
        size_t off = (size_t)(t0 + r) * 256 + 128 + c4;
        float4 v0 = *(const float4*)&l2p[off];
        float4 v1 = *(const float4*)&l2p[P + off];
        float4 v2 = *(const float4*)&l2p[2 * P + off];
        float4 v3 = *(const float4*)&l2p[3 * P + off];
        float4 v;
        v.x = ((v0.x + v1.x) + v2.x) + v3.x;
        v.y = ((v0.y + v1.y) + v2.y) + v3.y;
        v.z = ((v0.z + v1.z) + v2.z) + v3.z;
        v.w = ((v0.w + v1.w) + v2.w) + v3.w;
        if (c4 < 64) { v.x = tanhf(v.x); v.y = tanhf(v.y); v.z = tanhf(v.z); v.w = tanhf(v.w); }
        *(float4*)&wsS[r][c4] = v;
    }
    if (tid < 4 * 8) {
        int r = tid / 8, c4 = (tid % 8) * 4;
        size_t off = (size_t)(t0 + r) * 256 + 224 + c4;
        float4 v0 = *(const float4*)&l2p[off];
        float4 v1 = *(const float4*)&l2p[P + off];
        float4 v2 = *(const float4*)&l2p[2 * P + off];
        float4 v3 = *(const float4*)&l2p[3 * P + off];
        float4 v;
        v.x = ((v0.x + v1.x) + v2.x) + v3.x;
        v.y = ((v0.y + v1.y) + v2.y) + v3.y;
        v.z = ((v0.z + v1.z) + v2.z) + v3.z;
        v.w = ((v0.w + v1.w) + v2.w) + v3.w;
        if (c4 < 16) { v.x = tanhf(v.x); v.y = tanhf(v.y); v.z = tanhf(v.z); v.w = tanhf(v.w); }
        *(float4*)&ksS[r][c4] = v;
    }
    __syncthreads();
    float accW[4], accA[4], accMA[4], accKK[4], accMK[4];
#pragma unroll
    for (int r = 0; r < 4; ++r) { accW[r] = 0.f; accA[r] = 0.f; accMA[r] = 0.f; accKK[r] = 0.f; accMK[r] = 0.f; }
    for (int j = 0; j < 64; ++j) {
        float w = decay_w2[(size_t)j * C_ + c];
#pragma unroll
        for (int r = 0; r < 4; ++r) accW[r] = fmaf(wsS[r][j], w, accW[r]);
    }
    for (int j = 0; j < 16; ++j) {
        float wa = aaa_w2[(size_t)j * C_ + c];
        float wm = ma_w2[(size_t)j * C_ + c];
        float wk = kkk_w2[(size_t)j * C_ + c];
        float wq = mk_w2[(size_t)j * C_ + c];
#pragma unroll
        for (int r = 0; r < 4; ++r) {
            accA[r]  = fmaf(wsS[r][64 + j], wa, accA[r]);
            accMA[r] = fmaf(wsS[r][80 + j], wm, accMA[r]);
            accKK[r] = fmaf(ksS[r][j],      wk, accKK[r]);
            accMK[r] = fmaf(ksS[r][16 + j], wq, accMK[r]);
        }
    }
    float td = tdecay[c], aa = aaaaa[c], mia = misc_a[c], mik = misc_k[c];
#pragma unroll
    for (int r = 0; r < 4; ++r) {
        size_t idx = (size_t)(t0 + r) * C_ + c;
        float wraw = td + accW[r];
        float w = -__logf(1.0f + __expf(-wraw)) - 0.5f;   // -softplus(-x) - 0.5
        float a  = 1.0f / (1.0f + __expf(-(aa  + accA[r])));
        float mav = 1.0f / (1.0f + __expf(-(mia + accMA[r])));
        float mkv = 1.0f / (1.0f + __expf(-(mik + accMK[r])));
        float k0 = K0[idx];
        float kkun = k0 + accKK[r];
        float ss = kkun * kkun;
        REDUCE16(ss);
        ss += __shfl_xor(ss, 16, 64);
        ss += __shfl_xor(ss, 32, 64);
        float kn = kkun * (1.0f / fmaxf(sqrtf(ss), 1e-12f));
        Dout[idx]  = __expf(w);                 // dec, precomputed for the scan
        KKout[idx] = kn;
        Bout[idx]  = kn * a;
        K0[idx]    = k0 * (mav + a * (1.0f - mav)) * __expf(fminf(w * mkv, 0.0f));
    }
}

// ---------------------------------------------------------------------------
// WKV7 segmented scan, pass 1 (merged S+P). Grid (15 segs, 32 heads), 512 thr.
// 64-step segments (v9). Waves 0-3: S rows (init 0, +v k^T source). Waves
// 4-7: P rows (init I, vv=0). 4 row-states/lane; shared d/a/b (+k/v) staging.
// ---------------------------------------------------------------------------
__global__ __launch_bounds__(512) void k_wkv_p1(
    const float* __restrict__ DEC, const float* __restrict__ K,
    const float* __restrict__ V, const float* __restrict__ KK,
    const float* __restrict__ Bb,
    float* __restrict__ Send, float* __restrict__ Pend)
{
    const int tid = threadIdx.x;
    const int g = blockIdx.x;                  // segment 0..14
    const int h = blockIdx.y;                  // head
    const int c0 = h * 64;
    const int wv = tid >> 6, lane = tid & 63;
    const int jg = lane & 15, q = lane >> 4, j4 = jg * 4;
    const bool isS = wv < 4;
    const int row0 = (isS ? wv : wv - 4) * 16 + q * 4;   // rows row0..row0+3

    __shared__ __align__(16) float dS[2][16][64], kS[2][16][64], vS[2][16][64],
                                   aS[2][16][64], bS[2][16][64];

    // staging: pos in [0,256) covers one 4KB array-chunk; grp picks arrays.
    // per-wave lds dest = wave-uniform base + lane*16 (DMA constraint holds).
    const int pos = tid & 255, grp = tid >> 8;
    const int pst = pos >> 4, pq4 = (pos & 15) * 4;

#define P1_STAGE(buf, tcb) do {                                               \
    size_t gg = (size_t)((tcb) + pst) * C_ + c0 + pq4;                        \
    if (grp == 0) { async_cp16(&DEC[gg], &dS[buf][pst][pq4]);                 \
                    async_cp16(&KK[gg],  &aS[buf][pst][pq4]);                 \
                    async_cp16(&Bb[gg],  &bS[buf][pst][pq4]); }               \
    else          { async_cp16(&K[gg], &kS[buf][pst][pq4]);                   \
                    async_cp16(&V[gg], &vS[buf][pst][pq4]); }                 \
} while (0)

    float4 s0, s1, s2, s3;
    if (isS) {
        s0 = make_float4(0.f, 0.f, 0.f, 0.f); s1 = s0; s2 = s0; s3 = s0;
    } else {
#define IDROW(m) make_float4((j4 + 0 == row0 + (m)) ? 1.f : 0.f,              \
                             (j4 + 1 == row0 + (m)) ? 1.f : 0.f,              \
                             (j4 + 2 == row0 + (m)) ? 1.f : 0.f,              \
                             (j4 + 3 == row0 + (m)) ? 1.f : 0.f)
        s0 = IDROW(0); s1 = IDROW(1); s2 = IDROW(2); s3 = IDROW(3);
#undef IDROW
    }

    const int t0 = g * 64;
    P1_STAGE(0, t0);

    for (int tc = 0; tc < 64; tc += 16) {
        const int p = (tc >> 4) & 1;
        __syncthreads();                               // buf p ready
        if (tc + 16 < 64) P1_STAGE(p ^ 1, t0 + tc + 16);
#pragma unroll
        for (int tt = 0; tt < 16; ++tt) {
            float4 cd = *(float4*)&dS[p][tt][j4];
            float4 ca = *(float4*)&aS[p][tt][j4];
            float4 cb = *(float4*)&bS[p][tt][j4];
            float4 ck, vv;
            if (isS) {                                 // wave-uniform branch
                ck = *(float4*)&kS[p][tt][j4];
                vv = *(float4*)&vS[p][tt][row0];       // v for rows row0..+3
            } else {
                ck = make_float4(0.f, 0.f, 0.f, 0.f);
                vv = make_float4(0.f, 0.f, 0.f, 0.f);
            }
            float sa0 = -(fmaf(s0.y, ca.y, s0.x * ca.x) + fmaf(s0.w, ca.w, s0.z * ca.z));
            float sa1 = -(fmaf(s1.y, ca.y, s1.x * ca.x) + fmaf(s1.w, ca.w, s1.z * ca.z));
            float sa2 = -(fmaf(s2.y, ca.y, s2.x * ca.x) + fmaf(s2.w, ca.w, s2.z * ca.z));
            float sa3 = -(fmaf(s3.y, ca.y, s3.x * ca.x) + fmaf(s3.w, ca.w, s3.z * ca.z));
            REDUCE16(sa0); REDUCE16(sa1); REDUCE16(sa2); REDUCE16(sa3);
            s0.x = fmaf(s0.x, cd.x, fmaf(sa0, cb.x, vv.x * ck.x));
            s0.y = fmaf(s0.y, cd.y, fmaf(sa0, cb.y, vv.x * ck.y));
            s0.z = fmaf(s0.z, cd.z, fmaf(sa0, cb.z, vv.x * ck.z));
            s0.w = fmaf(s0.w, cd.w, fmaf(sa0, cb.w, vv.x * ck.w));
            s1.x = fmaf(s1.x, cd.x, fmaf(sa1, cb.x, vv.y * ck.x));
            s1.y = fmaf(s1.y, cd.y, fmaf(sa1, cb.y, vv.y * ck.y));
            s1.z = fmaf(s1.z, cd.z, fmaf(sa1, cb.z, vv.y * ck.z));
            s1.w = fmaf(s1.w, cd.w, fmaf(sa1, cb.w, vv.y * ck.w));
            s2.x = fmaf(s2.x, cd.x, fmaf(sa2, cb.x, vv.z * ck.x));
            s2.y = fmaf(s2.y, cd.y, fmaf(sa2, cb.y, vv.z * ck.y));
            s2.z = fmaf(s2.z, cd.z, fmaf(sa2, cb.z, vv.z * ck.z));
            s2.w = fmaf(s2.w, cd.w, fmaf(sa2, cb.w, vv.z * ck.w));
            s3.x = fmaf(s3.x, cd.x, fmaf(sa3, cb.x, vv.w * ck.x));
            s3.y = fmaf(s3.y, cd.y, fmaf(sa3, cb.y, vv.w * ck.y));
            s3.z = fmaf(s3.z, cd.z, fmaf(sa3, cb.z, vv.w * ck.z));
            s3.w = fmaf(s3.w, cd.w, fmaf(sa3, cb.w, vv.w * ck.w));
        }
    }
    float* dst = isS ? Send : Pend;
    size_t base = (size_t)((h * 15 + g) * 64 + row0) * 64 + j4;
    *(float4*)&dst[base +   0] = s0;
    *(float4*)&dst[base +  64] = s1;
    *(float4*)&dst[base + 128] = s2;
    *(float4*)&dst[base + 192] = s3;
#undef P1_STAGE
}

// ---------------------------------------------------------------------------
// WKV7 segmented scan, combine. 32 blocks (1/head) x 1024 thr (v9: widened
// from 256 so each of the 15 sequential 64x64 matmuls is ~4x cheaper).
// Sin(h,0) = 0; Sin(h,g) = Sin(h,g-1) @ P(h,g-1) + Send(h,g-1), g=1..15.
// Thread t: row i = t>>4, cols jq..jq+3 where jq = (t&15)*4.
// ---------------------------------------------------------------------------
__global__ __launch_bounds__(1024) void k_wkv_comb(
    const float* __restrict__ Send, const float* __restrict__ Pend,
    float* __restrict__ Sin)
{
    const int h = blockIdx.x;
    const int tid = threadIdx.x;
    const int i = tid >> 4;                    // row 0..63
    const int jq = (tid & 15) * 4;             // col group of 4
    __shared__ float Sc[64][65];               // padded: Sc[i][k] conflict-free
    __shared__ __align__(16) float Pl[64][64];

    float4 z4 = make_float4(0.f, 0.f, 0.f, 0.f);
    *(float4*)&Sin[(size_t)(h * 16) * 4096 + (size_t)i * 64 + jq] = z4;
    Sc[i][jq + 0] = 0.f; Sc[i][jq + 1] = 0.f;
    Sc[i][jq + 2] = 0.f; Sc[i][jq + 3] = 0.f;
    __syncthreads();

    for (int g = 1; g < 16; ++g) {
        const float* Pg = &Pend[(size_t)(h * 15 + g - 1) * 4096];
        {
            int idx = tid * 4;                 // 1024 thr x 4 = full 4096
            float4 v = *(const float4*)&Pg[idx];
            *(float4*)&Pl[idx >> 6][idx & 63] = v;
        }
        __syncthreads();
        float acc[4];
        {
            float4 sv = *(const float4*)&Send[
                (size_t)(h * 15 + g - 1) * 4096 + (size_t)i * 64 + jq];
            acc[0] = sv.x; acc[1] = sv.y; acc[2] = sv.z; acc[3] = sv.w;
        }
        for (int k = 0; k < 64; ++k) {
            float sik = Sc[i][k];
#pragma unroll
            for (int c = 0; c < 4; ++c) acc[c] = fmaf(sik, Pl[k][jq + c], acc[c]);
        }
        __syncthreads();                       // all reads of Sc/Pl done
        float* So = &Sin[(size_t)(h * 16 + g) * 4096 + (size_t)i * 64 + jq];
        Sc[i][jq + 0] = acc[0]; Sc[i][jq + 1] = acc[1];
        Sc[i][jq + 2] = acc[2]; Sc[i][jq + 3] = acc[3];
        *(float4*)So = make_float4(acc[0], acc[1], acc[2], acc[3]);
        __syncthreads();                       // Sc updated for next g
    }
}

// ---------------------------------------------------------------------------
// WKV7 segmented scan, pass 2. Grid (16 segs, 32 heads) = 512 blocks (2/CU,
// 2 waves/SIMD — v9; R6 measured 1412 cy/step fully latency-exposed at
// 1 wave/SIMD). 256 thr (4 waves x 16 rows; 4 row-states/lane). Replay
// 64-step segment from exact Sin(h,g), emit Y as float4.
// ---------------------------------------------------------------------------
__global__ __launch_bounds__(256) void k_wkv_p2(
    const float* __restrict__ R, const float* __restrict__ DEC,
    const float* __restrict__ K, const float* __restrict__ V,
    const float* __restrict__ KK, const float* __restrict__ Bb,
    const float* __restrict__ Sin, float* __restrict__ Y)
{
    const int tid = threadIdx.x;
    const int g = blockIdx.x;                  // segment 0..15
    const int h = blockIdx.y;
    const int c0 = h * 64;
    const int wv = tid >> 6, lane = tid & 63;
    const int jg = lane & 15, q = lane >> 4, j4 = jg * 4;
    const int row0 = wv * 16 + q * 4;          // rows row0..row0+3

    __shared__ __align__(16) float rS[2][16][64], dS[2][16][64], kS[2][16][64],
                                   aS[2][16][64], bS[2][16][64], vS[2][16][64];

    const int pst = tid >> 4, pq4 = (tid & 15) * 4;

#define P2_STAGE(buf, tcb) do {                                               \
    size_t gg = (size_t)((tcb) + pst) * C_ + c0 + pq4;                        \
    async_cp16(&R[gg],   &rS[buf][pst][pq4]);                                 \
    async_cp16(&DEC[gg], &dS[buf][pst][pq4]);                                 \
    async_cp16(&K[gg],   &kS[buf][pst][pq4]);                                 \
    async_cp16(&V[gg],   &vS[buf][pst][pq4]);                                 \
    async_cp16(&KK[gg],  &aS[buf][pst][pq4]);                                 \
    async_cp16(&Bb[gg],  &bS[buf][pst][pq4]);                                 \
} while (0)

    float4 s0, s1, s2, s3;
    {
        const float* Sb = &Sin[(size_t)((h * 16 + g) * 64 + row0) * 64 + j4];
        s0 = *(const float4*)&Sb[0];
        s1 = *(const float4*)&Sb[64];
        s2 = *(const float4*)&Sb[128];
        s3 = *(const float4*)&Sb[192];
    }

    const int t0 = g * 64;
    P2_STAGE(0, t0);

    for (int tc = 0; tc < 64; tc += 16) {
        const int p = (tc >> 4) & 1;
        __syncthreads();                               // buf p ready
        if (tc + 16 < 64) P2_STAGE(p ^ 1, t0 + tc + 16);
#pragma unroll
        for (int hh = 0; hh < 2; ++hh) {
            float po0[8], po1[8], po2[8], po3[8];
#pragma unroll
            for (int qs2 = 0; qs2 < 8; ++qs2) {
                const int tt = hh * 8 + qs2;
                float4 cr = *(float4*)&rS[p][tt][j4];
                float4 cd = *(float4*)&dS[p][tt][j4];
                float4 ck = *(float4*)&kS[p][tt][j4];
                float4 ca = *(float4*)&aS[p][tt][j4];
                float4 cb = *(float4*)&bS[p][tt][j4];
                float4 vv = *(float4*)&vS[p][tt][row0];
                float sa0 = -(fmaf(s0.y, ca.y, s0.x * ca.x) + fmaf(s0.w, ca.w, s0.z * ca.z));
                float sa1 = -(fmaf(s1.y, ca.y, s1.x * ca.x) + fmaf(s1.w, ca.w, s1.z * ca.z));
                float sa2 = -(fmaf(s2.y, ca.y, s2.x * ca.x) + fmaf(s2.w, ca.w, s2.z * ca.z));
                float sa3 = -(fmaf(s3.y, ca.y, s3.x * ca.x) + fmaf(s3.w, ca.w, s3.z * ca.z));
                REDUCE16(sa0); REDUCE16(sa1); REDUCE16(sa2); REDUCE16(sa3);
                s0.x = fmaf(s0.x, cd.x, fmaf(sa0, cb.x, vv.x * ck.x));
                s0.y = fmaf(s0.y, cd.y, fmaf(sa0, cb.y, vv.x * ck.y));
                s0.z = fmaf(s0.z, cd.z, fmaf(sa0, cb.z, vv.x * ck.z));
                s0.w = fmaf(s0.w, cd.w, fmaf(sa0, cb.w, vv.x * ck.w));
                s1.x = fmaf(s1.x, cd.x, fmaf(sa1, cb.x, vv.y * ck.x));
                s1.y = fmaf(s1.y, cd.y, fmaf(sa1, cb.y, vv.y * ck.y));
                s1.z = fmaf(s1.z, cd.z, fmaf(sa1, cb.z, vv.y * ck.z));
                s1.w = fmaf(s1.w, cd.w, fmaf(sa1, cb.w, vv.y * ck.w));
                s2.x = fmaf(s2.x, cd.x, fmaf(sa2, cb.x, vv.z * ck.x));
                s2.y = fmaf(s2.y, cd.y, fmaf(sa2, cb.y, vv.z * ck.y));
                s2.z = fmaf(s2.z, cd.z, fmaf(sa2, cb.z, vv.z * ck.z));
                s2.w = fmaf(s2.w, cd.w, fmaf(sa2, cb.w, vv.z * ck.w));
                s3.x = fmaf(s3.x, cd.x, fmaf(sa3, cb.x, vv.w * ck.x));
                s3.y = fmaf(s3.y, cd.y, fmaf(sa3, cb.y, vv.w * ck.y));
                s3.z = fmaf(s3.z, cd.z, fmaf(sa3, cb.z, vv.w * ck.z));
                s3.w = fmaf(s3.w, cd.w, fmaf(sa3, cb.w, vv.w * ck.w));
                po0[qs2] = fmaf(s0.w, cr.w, fmaf(s0.z, cr.z, fmaf(s0.y, cr.y, s0.x * cr.x)));
                po1[qs2] = fmaf(s1.w, cr.w, fmaf(s1.z, cr.z, fmaf(s1.y, cr.y, s1.x * cr.x)));
                po2[qs2] = fmaf(s2.w, cr.w, fmaf(s2.z, cr.z, fmaf(s2.y, cr.y, s2.x * cr.x)));
                po3[qs2] = fmaf(s3.w, cr.w, fmaf(s3.z, cr.z, fmaf(s3.y, cr.y, s3.x * cr.x)));
            }
            // deferred: 32 independent DPP butterflies pipeline
#pragma unroll
            for (int qs2 = 0; qs2 < 8; ++qs2) {
                REDUCE16(po0[qs2]); REDUCE16(po1[qs2]);
                REDUCE16(po2[qs2]); REDUCE16(po3[qs2]);
            }
            if (jg == 0) {
#pragma unroll
                for (int qs2 = 0; qs2 < 8; ++qs2) {
                    float4 o = make_float4(po0[qs2], po1[qs2], po2[qs2], po3[qs2]);
                    *(float4*)&Y[(size_t)(t0 + tc + hh * 8 + qs2) * C_ + c0 + row0] = o;
                }
            }
        }
    }
#undef P2_STAGE
}

// ---------------------------------------------------------------------------
// GroupNorm + bonus + fused gate, t-tiled (16 t/block so the 128 gw2 loads
// amortize): YG = f16((gn(y) + bonus) * (tanh(l2 sum) @ gate_w2)).
// ---------------------------------------------------------------------------
__global__ __launch_bounds__(256) void k_gn(
    const float* __restrict__ Y, const float* __restrict__ R, const float* __restrict__ K,
    const float* __restrict__ V, const float* __restrict__ l2p,
    const float* __restrict__ gw2,
    const float* __restrict__ faaaa, const float* __restrict__ lnw,
    const float* __restrict__ lnb, _Float16* __restrict__ YG)
{
    const int tid = threadIdx.x;
    const int c = blockIdx.x * 256 + tid;
    const int t0 = blockIdx.y * 16;
    const size_t P = (size_t)T_ * 256;
    __shared__ __align__(16) float gs[16][128];
    for (int id = tid; id < 16 * 128; id += 256) {
        int r = id >> 7, cc = id & 127;
        size_t off = (size_t)(t0 + r) * 256 + cc;
        float v = ((l2p[off] + l2p[P + off]) + l2p[2 * P + off]) + l2p[3 * P + off];
        gs[r][cc] = tanhf(v);
    }
    __syncthreads();
    float gacc[16];
#pragma unroll
    for (int r = 0; r < 16; ++r) gacc[r] = 0.f;
    for (int j = 0; j < 128; ++j) {
        float w = gw2[(size_t)j * C_ + c];
#pragma unroll
        for (int r = 0; r < 16; ++r) gacc[r] = fmaf(gs[r][j], w, gacc[r]);
    }
    float fa = faaaa[c], lw = lnw[c], lb = lnb[c];
    for (int r = 0; r < 16; ++r) {
        const size_t idx = (size_t)(t0 + r) * C_ + c;
        float y = Y[idx];
        float s1 = y, s2 = y * y;
#pragma unroll
        for (int off = 1; off < 64; off <<= 1) {
            s1 += __shfl_xor(s1, off, 64);
            s2 += __shfl_xor(s2, off, 64);
        }
        float mu = s1 * (1.0f / 64.0f);
        float var = s2 * (1.0f / 64.0f) - mu * mu;
        float gn = (y - mu) * rsqrtf(var + 0.00064f) * lw + lb;
        float p = R[idx] * K[idx] * fa;
#pragma unroll
        for (int off = 1; off < 64; off <<= 1) p += __shfl_xor(p, off, 64);
        float y2 = gn + p * V[idx];
        YG[idx] = (_Float16)(y2 * gacc[r]);
    }
}

// ---------------------------------------------------------------------------
extern "C" void kernel_launch(void* const* d_in, const int* in_sizes, int n_in,
                              void* d_out, int out_size, void* d_ws, size_t ws_size,
                              hipStream_t stream)
{
    (void)in_sizes; (void)n_in; (void)out_size; (void)ws_size;
    const float* hidden   = (const float*)d_in[0];
    const float* Wq       = (const float*)d_in[1];
    const float* Wk       = (const float*)d_in[2];
    const float* Wv       = (const float*)d_in[3];
    const float* Wo       = (const float*)d_in[4];
    const float* maa_x    = (const float*)d_in[5];
    const float* maa_rg   = (const float*)d_in[6];
    const float* maa_wa   = (const float*)d_in[7];
    const float* maa_k    = (const float*)d_in[8];
    const float* maa_v    = (const float*)d_in[9];
    const float* maa_w1   = (const float*)d_in[10];
    const float* maa_w2   = (const float*)d_in[11];
    const float* tdecay   = (const float*)d_in[12];
    const float* decay_w1 = (const float*)d_in[13];
    const float* decay_w2 = (const float*)d_in[14];
    const float* aaaaa    = (const float*)d_in[15];
    const float* aaa_w1   = (const float*)d_in[16];
    const float* aaa_w2   = (const float*)d_in[17];
    const float* kkk_w1   = (const float*)d_in[18];
    const float* kkk_w2   = (const float*)d_in[19];
    const float* gate_w1  = (const float*)d_in[20];
    const float* gate_w2  = (const float*)d_in[21];
    const float* misc_a   = (const float*)d_in[22];
    const float* ma_w1    = (const float*)d_in[23];
    const float* ma_w2    = (const float*)d_in[24];
    const float* misc_k   = (const float*)d_in[25];
    const float* mk_w1    = (const float*)d_in[26];
    const float* mk_w2    = (const float*)d_in[27];
    const float* faaaa    = (const float*)d_in[28];
    const float* lnw      = (const float*)d_in[29];
    const float* lnb      = (const float*)d_in[30];

    float* ws = (float*)d_ws;
    const size_t TC = (size_t)T_ * C_;
    // f32 buffers:
    //   S0: y   S2: b   S3: kk   S4: r   S5: dec   S6: k0 -> k   S7: v
    //   S1 slot (8MB): Send [32][15][64][64] f32 (7.5 MB)
    float* S0 = ws + 0 * TC;
    float* Send = ws + 1 * TC;
    float* S2 = ws + 2 * TC;
    float* S3 = ws + 3 * TC;
    float* S4 = ws + 4 * TC;
    float* S5 = ws + 5 * TC;
    float* S6 = ws + 6 * TC;
    float* S7 = ws + 7 * TC;
    float* m1p = ws + 8 * TC;                    // [4][T][128] partials
    float* l2p = m1p + (size_t)4 * T_ * 128;     // [4][T][256] partials
    // f16 region
    _Float16* WTq = (_Float16*)(l2p + (size_t)4 * T_ * 256);
    _Float16* WTk = WTq + (size_t)C_ * C_;
    _Float16* WTv = WTk + (size_t)C_ * C_;
    _Float16* WTo = WTv + (size_t)C_ * C_;
    _Float16* WTm = WTo + (size_t)C_ * C_;       // [128,2048]
    _Float16* WTl = WTm + (size_t)128 * C_;      // [256,2048]
    _Float16* xxxH = WTl + (size_t)256 * C_;
    _Float16* xrgH = xxxH + TC;
    _Float16* xwaH = xrgH + TC;
    _Float16* xkH  = xwaH + TC;
    _Float16* xvH  = xkH + TC;
    _Float16* ygH  = xxxH;                       // xxxH dead after step 6
    // After step 7, xrgH..xvH (16 MB contiguous f16 scratch) are dead:
    //   Sin  [32][16][64][64] f32 = 8 MB exactly -> xrgH+xwaH
    //   Pend [32][15][64][64] f32 = 7.5 MB       -> xkH+xvH
    float* Sin  = (float*)xrgH;
    float* Pend = (float*)xkH;
    float* out = (float*)d_out;

    // 1. transpose+convert big weights
    k_tr<<<dim3(32, 32, 4), 256, 0, stream>>>(Wq, Wk, Wv, Wo, WTq, WTk, WTv, WTo);
    // 2. pack+transpose LoRA weights (z=0: WTm, z=1: WTl)
    k_trW<<<dim3(8, 256, 2), 256, 0, stream>>>(maa_w1, gate_w1, decay_w1,
        aaa_w1, ma_w1, kkk_w1, mk_w1, WTm, WTl);
    // 3. xxxH
    k_prep<<<dim3((int)(TC / 256)), 256, 0, stream>>>(hidden, maa_x, xxxH);
    // 4. m1 partials = xxxH @ WTm^T
    k_lora<<<dim3(16, 4, 4), 256, 0, stream>>>(0, xxxH, xxxH, xxxH, xxxH,
        WTm, WTl, m1p, l2p);
    // 5. xmix -> f16 operands
    k_xmix<<<dim3(8, 64), 256, 0, stream>>>(hidden, m1p, maa_w2,
        maa_rg, maa_wa, maa_k, maa_v, xrgH, xwaH, xkH, xvH);
    // 6. l2 partials (gate | decay | aaa | ma | kkk | mk)
    k_lora<<<dim3(16, 8, 4), 256, 0, stream>>>(1, xxxH, xrgH, xwaH, xkH,
        WTm, WTl, m1p, l2p);
    // 7. r, k0, v (f16 MFMA, 128^2 tile, counted-vmcnt pipeline: 384 blocks)
    k_gemm<<<dim3(16, 8, 3), 256, 0, stream>>>(
        xrgH, WTq, S4,  xkH, WTk, S6,  xvH, WTv, S7);
    // 8. fused stage-2: dec, kk (normalized), b, k_final (t-tile 4)
    k_fuse<<<dim3(8, 256), 256, 0, stream>>>(l2p, S6, decay_w2, aaa_w2, ma_w2,
        kkk_w2, mk_w2, tdecay, aaaaa, misc_a, misc_k, S5, S3, S2);
    // 9. WKV7 segmented scan (16 segments of 64 steps):
    //    9a. pass 1 (merged): local end-states + transition products
    k_wkv_p1<<<dim3(15, 32), 512, 0, stream>>>(S5, S6, S7, S3, S2, Send, Pend);
    //    9b. combine: Sin(g) = Sin(g-1) @ P(g-1) + Send(g-1)
    k_wkv_comb<<<dim3(32), 1024, 0, stream>>>(Send, Pend, Sin);
    //    9c. pass 2: replay segments from exact Sin, emit Y
    k_wkv_p2<<<dim3(16, 32), 256, 0, stream>>>(S4, S5, S6, S7, S3, S2, Sin, S0);
    // 10. groupnorm + bonus + fused gate -> f16 (reuses xxxH slot)
    k_gn<<<dim3(8, 64), 256, 0, stream>>>(S0, S4, S6, S7, l2p, gate_w2,
        faaaa, lnw, lnb, ygH);
    // 11. out = (y*g) @ Wo (BN=64 variant: 256 blocks = 1/CU)
    k_gemm64<<<dim3(32, 8, 1), 256, 0, stream>>>(ygH, WTo, out);
}

// Round 8
// 512.364 us; speedup vs baseline: 1.0228x; 1.0228x over previous
//
#include <hip/hip_runtime.h>

// RWKV7 attention block, MI355X/gfx950.
// B=1, T=1024, C=2048, H=32, N=64. All inputs/outputs f32.
// Big GEMM step-7 v4: BM=BN=128, 3-buffer counted-vmcnt(4) pipeline +
// slot-XOR swizzle (57us, grid-tail-bound; further effort parked).
// Step-11 v2: BN=64 SPLIT-K=2 (512 blocks = 2/CU; was 1/CU zero-TLP) ->
// f32 partials (dead S2 + Sin regions) + k_red add.
// k_lora v2: 2-buffer LDS, ONE sync/step (was 2), next-step global loads
// issued into regs before MFMAs (old loop: 2 MFMA between 2 barriers).
// k_wkv_comb v2: prefetch g+1 P/Send into regs during g's fma chain (15
// serial iterations were each exposed-global-latency bound).
// k_prep folded into k_trW z=2 (float4-vectorized), one fewer launch.
// WKV scan v9: 16 segments of 64 steps. k_fuse v2: t-tile 4.

#define T_ 1024
#define C_ 2048
#define H_ 32
#define N_ 64

using half8  = __attribute__((ext_vector_type(8))) _Float16;  // 8 f16 (4 VGPRs)
using half4  = __attribute__((ext_vector_type(4))) _Float16;  // 8 B
using floatx4 = __attribute__((ext_vector_type(4))) float;    // 4 f32 acc

// DPP xor-add within 16-lane rows: quad_perm(0xB1)=xor1, quad_perm(0x4E)=xor2,
// row_half_mirror(0x141)=xor4, row_mirror(0x140)=xor8.
#define DPP_ADD(v, ctrl) \
    ((v) + __int_as_float(__builtin_amdgcn_update_dpp( \
        0, __float_as_int(v), (ctrl), 0xf, 0xf, true)))
#define REDUCE16(v) do { \
    v = DPP_ADD(v, 0xB1); v = DPP_ADD(v, 0x4E); \
    v = DPP_ADD(v, 0x141); v = DPP_ADD(v, 0x140); } while (0)

// async 16B global->LDS (direct-to-LDS DMA; HW dest = wave base + lane*16,
// all call sites construct per-lane lds ptrs matching exactly that layout)
__device__ __forceinline__ void async_cp16(const void* g, void* l) {
    __builtin_amdgcn_global_load_lds(
        (const __attribute__((address_space(1))) void*)g,
        (__attribute__((address_space(3))) void*)l, 16, 0, 0);
}

// ---------------------------------------------------------------------------
// Transpose + convert big weights: W[k][n] f32 -> WT[n][k] f16
// ---------------------------------------------------------------------------
__global__ __launch_bounds__(256) void k_tr(
    const float* __restrict__ W0, const float* __restrict__ W1,
    const float* __restrict__ W2, const float* __restrict__ W3,
    _Float16* __restrict__ D0, _Float16* __restrict__ D1,
    _Float16* __restrict__ D2, _Float16* __restrict__ D3)
{
    const int z = blockIdx.z;
    const float* S = (z == 0) ? W0 : (z == 1) ? W1 : (z == 2) ? W2 : W3;
    _Float16* D = (z == 0) ? D0 : (z == 1) ? D1 : (z == 2) ? D2 : D3;
    const int nb = blockIdx.x * 64, kb = blockIdx.y * 64;
    __shared__ __align__(16) float tile[64][65];
    const int tr = threadIdx.x >> 4, tc4 = (threadIdx.x & 15) * 4;
#pragma unroll
    for (int p = 0; p < 4; ++p) {
        int row = p * 16 + tr;
        float4 v = *(const float4*)&S[(size_t)(kb + row) * C_ + nb + tc4];
        tile[row][tc4 + 0] = v.x; tile[row][tc4 + 1] = v.y;
        tile[row][tc4 + 2] = v.z; tile[row][tc4 + 3] = v.w;
    }
    __syncthreads();
#pragma unroll
    for (int p = 0; p < 4; ++p) {
        int n = p * 16 + tr;
        half4 u;
        u[0] = (_Float16)tile[tc4 + 0][n];
        u[1] = (_Float16)tile[tc4 + 1][n];
        u[2] = (_Float16)tile[tc4 + 2][n];
        u[3] = (_Float16)tile[tc4 + 3][n];
        *(half4*)&D[(size_t)(nb + n) * C_ + kb + tc4] = u;
    }
}

// ---------------------------------------------------------------------------
// Pack+transpose LoRA weights to f16 WT[n][k] + fused xxxH prep (z=2).
// z=0: WT_m [128][2048] <- maa_w1[2048,128]
// z=1: WT_l [256][2048] <- gate(128) | decay(64) | aaa(16) | ma(16) | kkk(16) | mk(16)
// z=2: xxxH = f16( x + (x_prev - x) * maa_x ), float4-vectorized
// ---------------------------------------------------------------------------
__global__ __launch_bounds__(256) void k_trW(
    const float* __restrict__ maa_w1, const float* __restrict__ gate_w1,
    const float* __restrict__ decay_w1, const float* __restrict__ aaa_w1,
    const float* __restrict__ ma_w1, const float* __restrict__ kkk_w1,
    const float* __restrict__ mk_w1,
    const float* __restrict__ X, const float* __restrict__ maa_x,
    _Float16* __restrict__ WTm, _Float16* __restrict__ WTl,
    _Float16* __restrict__ xxxH)
{
    const int z = blockIdx.z;
    const int tid = threadIdx.x;
    if (z == 2) {                                   // fused k_prep
        const size_t e0 = ((size_t)(blockIdx.y * 8 + blockIdx.x) * 256 + tid) * 4;
        float4 cur = *(const float4*)&X[e0];
        float4 prev = make_float4(0.f, 0.f, 0.f, 0.f);
        if (e0 >= C_) prev = *(const float4*)&X[e0 - C_];
        const int c = (int)(e0 & (C_ - 1));
        float4 mx = *(const float4*)&maa_x[c];
        half4 o;
        o[0] = (_Float16)(cur.x + (prev.x - cur.x) * mx.x);
        o[1] = (_Float16)(cur.y + (prev.y - cur.y) * mx.y);
        o[2] = (_Float16)(cur.z + (prev.z - cur.z) * mx.z);
        o[3] = (_Float16)(cur.w + (prev.w - cur.w) * mx.w);
        *(half4*)&xxxH[e0] = o;
        return;
    }
    const int k = blockIdx.x * 256 + tid;           // 0..2047
    const int n = blockIdx.y;
    if (z == 0 && n >= 128) return;
    const float* src; int stride, col;
    _Float16* dst;
    if (z == 0) { src = maa_w1; stride = 128; col = n; dst = WTm; }
    else {
        dst = WTl;
        if (n < 128)      { src = gate_w1;  stride = 128; col = n; }
        else if (n < 192) { src = decay_w1; stride = 64;  col = n - 128; }
        else if (n < 208) { src = aaa_w1;   stride = 16;  col = n - 192; }
        else if (n < 224) { src = ma_w1;    stride = 16;  col = n - 208; }
        else if (n < 240) { src = kkk_w1;   stride = 16;  col = n - 224; }
        else              { src = mk_w1;    stride = 16;  col = n - 240; }
    }
    dst[(size_t)n * C_ + k] = (_Float16)src[(size_t)k * stride + col];
}

// ---------------------------------------------------------------------------
// LoRA MFMA GEMM v2, split-K -> per-split partials (deterministic).
// BM=64, BN=32, BK=32, ksplit=4. 2-buffer LDS, ONE __syncthreads per step;
// next-step tiles loaded global->reg before this step's MFMAs (latency
// hidden). Old loop had 2 barriers per step around only 2 MFMAs.
// which=0: m1p[ks][1024][128] = xxxH @ WTm^T (4 n-tiles)
// which=1: l2p[ks][1024][256], A per n-tile: 0-3 xrg | 4-6 xwa | 7 xk
// ---------------------------------------------------------------------------
__global__ __launch_bounds__(256) void k_lora(
    int which,
    const _Float16* __restrict__ Axxx, const _Float16* __restrict__ Axrg,
    const _Float16* __restrict__ Axwa, const _Float16* __restrict__ Axk,
    const _Float16* __restrict__ WTm, const _Float16* __restrict__ WTl,
    float* __restrict__ m1p, float* __restrict__ l2p)
{
    const int mt = blockIdx.x;      // 16 tiles of 64 rows
    const int nt = blockIdx.y;      // tiles of 32 cols
    const int ks = blockIdx.z;      // 4 K-chunks of 512
    const _Float16* A; const _Float16* BT; float* O; int ostride;
    if (which == 0) { A = Axxx; BT = WTm; O = m1p; ostride = 128; }
    else {
        BT = WTl; O = l2p; ostride = 256;
        A = (nt < 4) ? Axrg : (nt < 7) ? Axwa : Axk;
    }
    O += (size_t)ks * T_ * ostride;
    const int m0 = mt * 64, n0 = nt * 32, k0 = ks * 512;
    const int tid = threadIdx.x;
    __shared__ __align__(16) _Float16 As[2][64 * 40];
    __shared__ __align__(16) _Float16 Bs[2][32 * 40];
    const int lane = tid & 63, wv = tid >> 6;
    const int r16 = lane & 15, q = lane >> 4;

    floatx4 acc[2];
    { floatx4 zv = {0.f, 0.f, 0.f, 0.f}; acc[0] = zv; acc[1] = zv; }

    const int arow = tid >> 2, ac8 = (tid & 3) * 8;
    const _Float16* ag = A + (size_t)(m0 + arow) * C_ + k0 + ac8;
    const _Float16* bg = BT + (size_t)(n0 + arow) * C_ + k0 + ac8;

    {
        half8 av = *(const half8*)ag;
        *(half8*)&As[0][arow * 40 + ac8] = av;
        if (tid < 128) {
            half8 bv = *(const half8*)bg;
            *(half8*)&Bs[0][arow * 40 + ac8] = bv;
        }
    }
    __syncthreads();

    for (int it = 0; it < 16; ++it) {
        const int p = it & 1;
        half8 av2, bv2;
        if (it < 15) {                        // prefetch next tile into regs
            av2 = *(const half8*)(ag + (it + 1) * 32);
            if (tid < 128) bv2 = *(const half8*)(bg + (it + 1) * 32);
        }
        half8 af = *(const half8*)&As[p][(wv * 16 + r16) * 40 + q * 8];
        half8 b0 = *(const half8*)&Bs[p][(r16) * 40 + q * 8];
        half8 b1 = *(const half8*)&Bs[p][(16 + r16) * 40 + q * 8];
        acc[0] = __builtin_amdgcn_mfma_f32_16x16x32_f16(af, b0, acc[0], 0, 0, 0);
        acc[1] = __builtin_amdgcn_mfma_f32_16x16x32_f16(af, b1, acc[1], 0, 0, 0);
        if (it < 15) {                        // write next tile to other buf
            *(half8*)&As[p ^ 1][arow * 40 + ac8] = av2;
            if (tid < 128) *(half8*)&Bs[p ^ 1][arow * 40 + ac8] = bv2;
        }
        __syncthreads();                      // next-buf writes visible
    }
#pragma unroll
    for (int j = 0; j < 2; ++j)
#pragma unroll
        for (int e = 0; e < 4; ++e) {
            int row = m0 + wv * 16 + q * 4 + e;
            int col = n0 + j * 16 + r16;
            O[(size_t)row * ostride + col] = acc[j][e];
        }
}

// ---------------------------------------------------------------------------
// xmix: m1 = sum_ks(m1p), tanh; mix = einsum(m1[T,4,32], maa_w2[4,32,C]);
// emit f16 GEMM operands xrgH/xwaH/xkH/xvH.
// ---------------------------------------------------------------------------
__global__ __launch_bounds__(256) void k_xmix(
    const float* __restrict__ X, const float* __restrict__ m1p,
    const float* __restrict__ w2,
    const float* __restrict__ mrg, const float* __restrict__ mwa,
    const float* __restrict__ mk, const float* __restrict__ mv,
    _Float16* __restrict__ xrgH, _Float16* __restrict__ xwaH,
    _Float16* __restrict__ xkH, _Float16* __restrict__ xvH)
{
    const int tid = threadIdx.x;
    const int c = blockIdx.x * 256 + tid;
    const int t0 = blockIdx.y * 16;
    const size_t P = (size_t)T_ * 128;
    __shared__ __align__(16) float m1s[16][128];
#pragma unroll
    for (int p = 0; p < 2; ++p) {
        int id = tid + p * 256;
        int r = id >> 5, c4 = (id & 31) * 4;
        size_t off = (size_t)(t0 + r) * 128 + c4;
        float4 v0 = *(const float4*)&m1p[off];
        float4 v1 = *(const float4*)&m1p[P + off];
        float4 v2 = *(const float4*)&m1p[2 * P + off];
        float4 v3 = *(const float4*)&m1p[3 * P + off];
        float4 v;
        v.x = tanhf(((v0.x + v1.x) + v2.x) + v3.x);
        v.y = tanhf(((v0.y + v1.y) + v2.y) + v3.y);
        v.z = tanhf(((v0.z + v1.z) + v2.z) + v3.z);
        v.w = tanhf(((v0.w + v1.w) + v2.w) + v3.w);
        *(float4*)&m1s[r][c4] = v;
    }
    __syncthreads();
    float a0[16], a1[16], a2[16], a3[16];
#pragma unroll
    for (int t = 0; t < 16; ++t) { a0[t] = 0.f; a1[t] = 0.f; a2[t] = 0.f; a3[t] = 0.f; }
    for (int d = 0; d < 32; ++d) {
        float w0 = w2[(size_t)(0 * 32 + d) * C_ + c];
        float w1 = w2[(size_t)(1 * 32 + d) * C_ + c];
        float w2v = w2[(size_t)(2 * 32 + d) * C_ + c];
        float w3 = w2[(size_t)(3 * 32 + d) * C_ + c];
#pragma unroll
        for (int t = 0; t < 16; ++t) {
            a0[t] = fmaf(m1s[t][d],      w0,  a0[t]);
            a1[t] = fmaf(m1s[t][32 + d], w1,  a1[t]);
            a2[t] = fmaf(m1s[t][64 + d], w2v, a2[t]);
            a3[t] = fmaf(m1s[t][96 + d], w3,  a3[t]);
        }
    }
    float vrg = mrg[c], vwa = mwa[c], vmk = mk[c], vmv = mv[c];
    float prev = (t0 > 0) ? X[(size_t)(t0 - 1) * C_ + c] : 0.0f;
    for (int t = 0; t < 16; ++t) {
        size_t idx = (size_t)(t0 + t) * C_ + c;
        float cur = X[idx];
        float dx = prev - cur;
        xrgH[idx] = (_Float16)(cur + dx * (vrg + a0[t]));
        xwaH[idx] = (_Float16)(cur + dx * (vwa + a1[t]));
        xkH[idx]  = (_Float16)(cur + dx * (vmk + a2[t]));
        xvH[idx]  = (_Float16)(cur + dx * (vmv + a3[t]));
        prev = cur;
    }
}

// ---------------------------------------------------------------------------
// f16 MFMA GEMM v4 (step 7): C[1024,2048] = A(f16) @ W via WT[n][k] f16.
// BM=BN=128, BK=32, 256 thr (4 waves 2x2), 4x4 16x16x32 tiles/wave.
// 3-buffer counted-vmcnt depth-2 pipeline + slot-XOR swizzle.
// ---------------------------------------------------------------------------
__global__ __launch_bounds__(256) void k_gemm(
    const _Float16* __restrict__ A0, const _Float16* __restrict__ B0, float* __restrict__ C0,
    const _Float16* __restrict__ A1, const _Float16* __restrict__ B1, float* __restrict__ C1,
    const _Float16* __restrict__ A2, const _Float16* __restrict__ B2, float* __restrict__ C2)
{
    const int z = blockIdx.z;
    const _Float16* A = (z == 0) ? A0 : (z == 1) ? A1 : A2;
    const _Float16* Bt = (z == 0) ? B0 : (z == 1) ? B1 : B2;
    float* C = (z == 0) ? C0 : (z == 1) ? C1 : C2;
    const int mtile = blockIdx.y * 128;
    const int ntile = blockIdx.x * 128;
    const int tid = threadIdx.x;
    __shared__ __align__(16) _Float16 As[3][128 * 32];
    __shared__ __align__(16) _Float16 Bs[3][128 * 32];
    const int lane = tid & 63;
    const int wvid = tid >> 6;
    const int wm = wvid >> 1, wn = wvid & 1;
    const int r16 = lane & 15, q = lane >> 4;
    // read-side swizzled slot offset (halfwords). (row>>1)&3 == (r16>>1)&3 for
    // every fragment row (wm*64, i*16, wn*64, j*16 all vanish in bits 1..2).
    const int qs = (q ^ ((r16 >> 1) & 3)) * 8;

    floatx4 acc[4][4];
#pragma unroll
    for (int i = 0; i < 4; ++i)
#pragma unroll
        for (int j = 0; j < 4; ++j) { floatx4 zv = {0.f, 0.f, 0.f, 0.f}; acc[i][j] = zv; }

    const int srow = tid >> 2, sq = tid & 3;
    const int sqg = (sq ^ ((srow >> 1) & 3)) * 8;   // inverse swizzle on source
    const _Float16* agA = A + (size_t)(mtile + srow) * C_ + sqg;
    const _Float16* agB = Bt + (size_t)(ntile + srow) * C_ + sqg;
    const int ldso = srow * 32 + sq * 8;            // linear DMA dest (tid*16B)
    const size_t rowoff = (size_t)64 * C_;          // (srow+64): same swizzle

    // 4 async_cp16 per stage per thread => vmcnt counts in units of 4.
#define G_STAGE(pb, koff) do {                                                \
        async_cp16(agA + (koff), &As[pb][ldso]);                              \
        async_cp16(agA + (koff) + rowoff, &As[pb][ldso + 64 * 32]);           \
        async_cp16(agB + (koff), &Bs[pb][ldso]);                              \
        async_cp16(agB + (koff) + rowoff, &Bs[pb][ldso + 64 * 32]);           \
    } while (0)

    G_STAGE(0, 0);
    G_STAGE(1, 32);
    __builtin_amdgcn_sched_barrier(0);
    asm volatile("s_waitcnt vmcnt(4)" ::: "memory");   // buf0 landed
    __builtin_amdgcn_s_barrier();
    __builtin_amdgcn_sched_barrier(0);

    for (int ks = 0; ks < 64; ++ks) {
        const int p = ks % 3;
        if (ks + 2 < 64) G_STAGE((ks + 2) % 3, (ks + 2) * 32);
        half8 af[4], bf[4];
#pragma unroll
        for (int i = 0; i < 4; ++i)
            af[i] = *(const half8*)&As[p][(wm * 64 + i * 16 + r16) * 32 + qs];
#pragma unroll
        for (int j = 0; j < 4; ++j)
            bf[j] = *(const half8*)&Bs[p][(wn * 64 + j * 16 + r16) * 32 + qs];
#pragma unroll
        for (int i = 0; i < 4; ++i)
#pragma unroll
            for (int j = 0; j < 4; ++j)
                acc[i][j] = __builtin_amdgcn_mfma_f32_16x16x32_f16(af[i], bf[j], acc[i][j], 0, 0, 0);
        __builtin_amdgcn_sched_barrier(0);
        if (ks + 2 < 64)
            asm volatile("s_waitcnt vmcnt(4)" ::: "memory");  // (k+1) landed
        else
            asm volatile("s_waitcnt vmcnt(0)" ::: "memory");  // tail drain
        __builtin_amdgcn_s_barrier();
        __builtin_amdgcn_sched_barrier(0);
    }
    // C/D layout: col = lane&15, row = (lane>>4)*4 + reg
#pragma unroll
    for (int i = 0; i < 4; ++i)
#pragma unroll
        for (int j = 0; j < 4; ++j)
#pragma unroll
            for (int e = 0; e < 4; ++e) {
                int row = mtile + wm * 64 + i * 16 + q * 4 + e;
                int col = ntile + wn * 64 + j * 16 + r16;
                C[(size_t)row * C_ + col] = acc[i][j][e];
            }
#undef G_STAGE
}

// ---------------------------------------------------------------------------
// f16 MFMA GEMM BN=64 SPLIT-K variant (step 11): z picks K-half, writes f32
// partial. Grid (32,8,2) = 512 blocks = 2/CU (was 256 = 1/CU, zero TLP).
// ---------------------------------------------------------------------------
__global__ __launch_bounds__(256) void k_gemm64(
    const _Float16* __restrict__ A0, const _Float16* __restrict__ B0,
    float* __restrict__ P0, float* __restrict__ P1)
{
    const _Float16* A = A0;
    const _Float16* Bt = B0;
    float* C = (blockIdx.z == 0) ? P0 : P1;
    const int k0 = blockIdx.z * 1024;
    const int mtile = blockIdx.y * 128;
    const int ntile = blockIdx.x * 64;
    const int tid = threadIdx.x;
    __shared__ __align__(16) _Float16 As[3][128 * 32];
    __shared__ __align__(16) _Float16 Bs[3][64 * 32];
    const int lane = tid & 63;
    const int wvid = tid >> 6;
    const int wm = wvid >> 1, wn = wvid & 1;
    const int r16 = lane & 15, q = lane >> 4;
    const int qs = (q ^ ((r16 >> 1) & 3)) * 8;

    floatx4 acc[4][2];
#pragma unroll
    for (int i = 0; i < 4; ++i)
#pragma unroll
        for (int j = 0; j < 2; ++j) { floatx4 zv = {0.f, 0.f, 0.f, 0.f}; acc[i][j] = zv; }

    const int srow = tid >> 2, sq = tid & 3;
    const int sqg = (sq ^ ((srow >> 1) & 3)) * 8;
    const _Float16* agA = A + (size_t)(mtile + srow) * C_ + k0 + sqg;
    const _Float16* agB = Bt + (size_t)(ntile + srow) * C_ + k0 + sqg;
    const int ldso = srow * 32 + sq * 8;
    const size_t rowoff = (size_t)64 * C_;

#define G_STAGE(pb, koff) do {                                                \
        async_cp16(agA + (koff), &As[pb][ldso]);                              \
        async_cp16(agA + (koff) + rowoff, &As[pb][ldso + 64 * 32]);           \
        async_cp16(agB + (koff), &Bs[pb][ldso]);                              \
    } while (0)

    G_STAGE(0, 0);
    G_STAGE(1, 32);
    __builtin_amdgcn_sched_barrier(0);
    asm volatile("s_waitcnt vmcnt(3)" ::: "memory");
    __builtin_amdgcn_s_barrier();
    __builtin_amdgcn_sched_barrier(0);

    for (int ks = 0; ks < 32; ++ks) {
        const int p = ks % 3;
        if (ks + 2 < 32) G_STAGE((ks + 2) % 3, (ks + 2) * 32);
        half8 af[4], bf[2];
#pragma unroll
        for (int i = 0; i < 4; ++i)
            af[i] = *(const half8*)&As[p][(wm * 64 + i * 16 + r16) * 32 + qs];
#pragma unroll
        for (int j = 0; j < 2; ++j)
            bf[j] = *(const half8*)&Bs[p][(wn * 32 + j * 16 + r16) * 32 + qs];
#pragma unroll
        for (int i = 0; i < 4; ++i)
#pragma unroll
            for (int j = 0; j < 2; ++j)
                acc[i][j] = __builtin_amdgcn_mfma_f32_16x16x32_f16(af[i], bf[j], acc[i][j], 0, 0, 0);
        __builtin_amdgcn_sched_barrier(0);
        if (ks + 2 < 32)
            asm volatile("s_waitcnt vmcnt(3)" ::: "memory");
        else
            asm volatile("s_waitcnt vmcnt(0)" ::: "memory");
        __builtin_amdgcn_s_barrier();
        __builtin_amdgcn_sched_barrier(0);
    }
#pragma unroll
    for (int i = 0; i < 4; ++i)
#pragma unroll
        for (int j = 0; j < 2; ++j)
#pragma unroll
            for (int e = 0; e < 4; ++e) {
                int row = mtile + wm * 64 + i * 16 + q * 4 + e;
                int col = ntile + wn * 32 + j * 16 + r16;
                C[(size_t)row * C_ + col] = acc[i][j][e];
            }
#undef G_STAGE
}

// ---------------------------------------------------------------------------
// out = P0 + P1 (split-K reduce for step 11). 2048 blocks x 256 thr x float4.
// ---------------------------------------------------------------------------
__global__ __launch_bounds__(256) void k_red(
    const float* __restrict__ P0, const float* __restrict__ P1,
    float* __restrict__ O)
{
    const size_t i = ((size_t)blockIdx.x * 256 + threadIdx.x) * 4;
    float4 a = *(const float4*)&P0[i];
    float4 b = *(const float4*)&P1[i];
    float4 o;
    o.x = a.x + b.x; o.y = a.y + b.y; o.z = a.z + b.z; o.w = a.w + b.w;
    *(float4*)&O[i] = o;
}

// ---------------------------------------------------------------------------
// Fused stage-2 v2: dec=exp(w), kk (normalized), b = kk*a, k_final.
// t-tile 4 (grid 8x256 = 2048 blocks -> 8 blocks/CU).
// ---------------------------------------------------------------------------
__global__ __launch_bounds__(256) void k_fuse(
    const float* __restrict__ l2p,
    float* __restrict__ K0,
    const float* __restrict__ decay_w2, const float* __restrict__ aaa_w2,
    const float* __restrict__ ma_w2, const float* __restrict__ kkk_w2,
    const float* __restrict__ mk_w2,
    const float* __restrict__ tdecay, const float* __restrict__ aaaaa,
    const float* __restrict__ misc_a, const float* __restrict__ misc_k,
    float* __restrict__ Dout, float* __restrict__ KKout, float* __restrict__ Bout)
{
    const int tid = threadIdx.x;
    const int c = blockIdx.x * 256 + tid;
    const int t0 = blockIdx.y * 4;
    const size_t P = (size_t)T_ * 256;
    __shared__ __align__(16) float wsS[4][96];   // decay64 | aaa16 | ma16
    __shared__ __align__(16) float ksS[4][32];   // kkk16 | mk16
    if (tid < 4 * 24) {
        int r = tid / 24, c4 = (tid % 24) * 4;
        size_t off = (size_t)(t0 + r) * 256 + 128 + c4;
        float4 v0 = *(const float4*)&l2p[off];
        float4 v1 = *(const float4*)&l2p[P + off];
        float4 v2 = *(const float4*)&l2p[2 * P + off];
        float4 v3 = *(const float4*)&l2p[3 * P + off];
        float4 v;
        v.x = ((v0.x + v1.x) + v2.x) + v3.x;
        v.y = ((v0.y + v1.y) + v2.y) + v3.y;
        v.z = ((v0.z + v1.z) + v2.z) + v3.z;
        v.w = ((v0.w + v1.w) + v2.w) + v3.w;
        if (c4 < 64) { v.x = tanhf(v.x); v.y = tanhf(v.y); v.z = tanhf(v.z); v.w = tanhf(v.w); }
        *(float4*)&wsS[r][c4] = v;
    }
    if (tid < 4 * 8) {
        int r = tid / 8, c4 = (tid % 8) * 4;
        size_t off = (size_t)(t0 + r) * 256 + 224 + c4;
        float4 v0 = *(const float4*)&l2p[off];
        float4 v1 = *(const float4*)&l2p[P + off];
        float4 v2 = *(const float4*)&l2p[2 * P + off];
        float4 v3 = *(const float4*)&l2p[3 * P + off];
        float4 v;
        v.x = ((v0.x + v1.x) + v2.x) + v3.x;
        v.y = ((v0.y + v1.y) + v2.y) + v3.y;
        v.z = ((v0.z + v1.z) + v2.z) + v3.z;
        v.w = ((v0.w + v1.w) + v2.w) + v3.w;
        if (c4 < 16) { v.x = tanhf(v.x); v.y = tanhf(v.y); v.z = tanhf(v.z); v.w = tanhf(v.w); }
        *(float4*)&ksS[r][c4] = v;
    }
    __syncthreads();
    float accW[4], accA[4], accMA[4], accKK[4], accMK[4];
#pragma unroll
    for (int r = 0; r < 4; ++r) { accW[r] = 0.f; accA[r] = 0.f; accMA[r] = 0.f; accKK[r] = 0.f; accMK[r] = 0.f; }
    for (int j = 0; j < 64; ++j) {
        float w = decay_w2[(size_t)j * C_ + c];
#pragma unroll
        for (int r = 0; r < 4; ++r) accW[r] = fmaf(wsS[r][j], w, accW[r]);
    }
    for (int j = 0; j < 16; ++j) {
        float wa = aaa_w2[(size_t)j * C_ + c];
        float wm = ma_w2[(size_t)j * C_ + c];
        float wk = kkk_w2[(size_t)j * C_ + c];
        float wq = mk_w2[(size_t)j * C_ + c];
#pragma unroll
        for (int r = 0; r < 4; ++r) {
            accA[r]  = fmaf(wsS[r][64 + j], wa, accA[r]);
            accMA[r] = fmaf(wsS[r][80 + j], wm, accMA[r]);
            accKK[r] = fmaf(ksS[r][j],      wk, accKK[r]);
            accMK[r] = fmaf(ksS[r][16 + j], wq, accMK[r]);
        }
    }
    float td = tdecay[c], aa = aaaaa[c], mia = misc_a[c], mik = misc_k[c];
#pragma unroll
    for (int r = 0; r < 4; ++r) {
        size_t idx = (size_t)(t0 + r) * C_ + c;
        float wraw = td + accW[r];
        float w = -__logf(1.0f + __expf(-wraw)) - 0.5f;   // -softplus(-x) - 0.5
        float a  = 1.0f / (1.0f + __expf(-(aa  + accA[r])));
        float mav = 1.0f / (1.0f + __expf(-(mia + accMA[r])));
        float mkv = 1.0f / (1.0f + __expf(-(mik + accMK[r])));
        float k0 = K0[idx];
        float kkun = k0 + accKK[r];
        float ss = kkun * kkun;
        REDUCE16(ss);
        ss += __shfl_xor(ss, 16, 64);
        ss += __shfl_xor(ss, 32, 64);
        float kn = kkun * (1.0f / fmaxf(sqrtf(ss), 1e-12f));
        Dout[idx]  = __expf(w);                 // dec, precomputed for the scan
        KKout[idx] = kn;
        Bout[idx]  = kn * a;
        K0[idx]    = k0 * (mav + a * (1.0f - mav)) * __expf(fminf(w * mkv, 0.0f));
    }
}

// ---------------------------------------------------------------------------
// WKV7 segmented scan, pass 1 (merged S+P). Grid (15 segs, 32 heads), 512 thr.
// 64-step segments (v9). Waves 0-3: S rows (init 0, +v k^T source). Waves
// 4-7: P rows (init I, vv=0). 4 row-states/lane; shared d/a/b (+k/v) staging.
// ---------------------------------------------------------------------------
__global__ __launch_bounds__(512) void k_wkv_p1(
    const float* __restrict__ DEC, const float* __restrict__ K,
    const float* __restrict__ V, const float* __restrict__ KK,
    const float* __restrict__ Bb,
    float* __restrict__ Send, float* __restrict__ Pend)
{
    const int tid = threadIdx.x;
    const int g = blockIdx.x;                  // segment 0..14
    const int h = blockIdx.y;                  // head
    const int c0 = h * 64;
    const int wv = tid >> 6, lane = tid & 63;
    const int jg = lane & 15, q = lane >> 4, j4 = jg * 4;
    const bool isS = wv < 4;
    const int row0 = (isS ? wv : wv - 4) * 16 + q * 4;   // rows row0..row0+3

    __shared__ __align__(16) float dS[2][16][64], kS[2][16][64], vS[2][16][64],
                                   aS[2][16][64], bS[2][16][64];

    const int pos = tid & 255, grp = tid >> 8;
    const int pst = pos >> 4, pq4 = (pos & 15) * 4;

#define P1_STAGE(buf, tcb) do {                                               \
    size_t gg = (size_t)((tcb) + pst) * C_ + c0 + pq4;                        \
    if (grp == 0) { async_cp16(&DEC[gg], &dS[buf][pst][pq4]);                 \
                    async_cp16(&KK[gg],  &aS[buf][pst][pq4]);                 \
                    async_cp16(&Bb[gg],  &bS[buf][pst][pq4]); }               \
    else          { async_cp16(&K[gg], &kS[buf][pst][pq4]);                   \
                    async_cp16(&V[gg], &vS[buf][pst][pq4]); }                 \
} while (0)

    float4 s0, s1, s2, s3;
    if (isS) {
        s0 = make_float4(0.f, 0.f, 0.f, 0.f); s1 = s0; s2 = s0; s3 = s0;
    } else {
#define IDROW(m) make_float4((j4 + 0 == row0 + (m)) ? 1.f : 0.f,              \
                             (j4 + 1 == row0 + (m)) ? 1.f : 0.f,              \
                             (j4 + 2 == row0 + (m)) ? 1.f : 0.f,              \
                             (j4 + 3 == row0 + (m)) ? 1.f : 0.f)
        s0 = IDROW(0); s1 = IDROW(1); s2 = IDROW(2); s3 = IDROW(3);
#undef IDROW
    }

    const int t0 = g * 64;
    P1_STAGE(0, t0);

    for (int tc = 0; tc < 64; tc += 16) {
        const int p = (tc >> 4) & 1;
        __syncthreads();                               // buf p ready
        if (tc + 16 < 64) P1_STAGE(p ^ 1, t0 + tc + 16);
#pragma unroll
        for (int tt = 0; tt < 16; ++tt) {
            float4 cd = *(float4*)&dS[p][tt][j4];
            float4 ca = *(float4*)&aS[p][tt][j4];
            float4 cb = *(float4*)&bS[p][tt][j4];
            float4 ck, vv;
            if (isS) {                                 // wave-uniform branch
                ck = *(float4*)&kS[p][tt][j4];
                vv = *(float4*)&vS[p][tt][row0];       // v for rows row0..+3
            } else {
                ck = make_float4(0.f, 0.f, 0.f, 0.f);
                vv = make_float4(0.f, 0.f, 0.f, 0.f);
            }
            float sa0 = -(fmaf(s0.y, ca.y, s0.x * ca.x) + fmaf(s0.w, ca.w, s0.z * ca.z));
            float sa1 = -(fmaf(s1.y, ca.y, s1.x * ca.x) + fmaf(s1.w, ca.w, s1.z * ca.z));
            float sa2 = -(fmaf(s2.y, ca.y, s2.x * ca.x) + fmaf(s2.w, ca.w, s2.z * ca.z));
            float sa3 = -(fmaf(s3.y, ca.y, s3.x * ca.x) + fmaf(s3.w, ca.w, s3.z * ca.z));
            REDUCE16(sa0); REDUCE16(sa1); REDUCE16(sa2); REDUCE16(sa3);
            s0.x = fmaf(s0.x, cd.x, fmaf(sa0, cb.x, vv.x * ck.x));
            s0.y = fmaf(s0.y, cd.y, fmaf(sa0, cb.y, vv.x * ck.y));
            s0.z = fmaf(s0.z, cd.z, fmaf(sa0, cb.z, vv.x * ck.z));
            s0.w = fmaf(s0.w, cd.w, fmaf(sa0, cb.w, vv.x * ck.w));
            s1.x = fmaf(s1.x, cd.x, fmaf(sa1, cb.x, vv.y * ck.x));
            s1.y = fmaf(s1.y, cd.y, fmaf(sa1, cb.y, vv.y * ck.y));
            s1.z = fmaf(s1.z, cd.z, fmaf(sa1, cb.z, vv.y * ck.z));
            s1.w = fmaf(s1.w, cd.w, fmaf(sa1, cb.w, vv.y * ck.w));
            s2.x = fmaf(s2.x, cd.x, fmaf(sa2, cb.x, vv.z * ck.x));
            s2.y = fmaf(s2.y, cd.y, fmaf(sa2, cb.y, vv.z * ck.y));
            s2.z = fmaf(s2.z, cd.z, fmaf(sa2, cb.z, vv.z * ck.z));
            s2.w = fmaf(s2.w, cd.w, fmaf(sa2, cb.w, vv.z * ck.w));
            s3.x = fmaf(s3.x, cd.x, fmaf(sa3, cb.x, vv.w * ck.x));
            s3.y = fmaf(s3.y, cd.y, fmaf(sa3, cb.y, vv.w * ck.y));
            s3.z = fmaf(s3.z, cd.z, fmaf(sa3, cb.z, vv.w * ck.z));
            s3.w = fmaf(s3.w, cd.w, fmaf(sa3, cb.w, vv.w * ck.w));
        }
    }
    float* dst = isS ? Send : Pend;
    size_t base = (size_t)((h * 15 + g) * 64 + row0) * 64 + j4;
    *(float4*)&dst[base +   0] = s0;
    *(float4*)&dst[base +  64] = s1;
    *(float4*)&dst[base + 128] = s2;
    *(float4*)&dst[base + 192] = s3;
#undef P1_STAGE
}

// ---------------------------------------------------------------------------
// WKV7 segmented scan, combine v2. 32 blocks (1/head) x 1024 thr.
// Sin(h,0) = 0; Sin(h,g) = Sin(h,g-1) @ P(h,g-1) + Send(h,g-1), g=1..15.
// g+1's P/Send prefetched into regs BEFORE g's fma chain (hides ~600cy
// global latency that serialized the 15 iterations).
// ---------------------------------------------------------------------------
__global__ __launch_bounds__(1024) void k_wkv_comb(
    const float* __restrict__ Send, const float* __restrict__ Pend,
    float* __restrict__ Sin)
{
    const int h = blockIdx.x;
    const int tid = threadIdx.x;
    const int i = tid >> 4;                    // row 0..63
    const int jq = (tid & 15) * 4;             // col group of 4
    const int idx = tid * 4;                   // P element base
    __shared__ float Sc[64][65];               // padded: Sc[i][k] conflict-free
    __shared__ __align__(16) float Pl[64][64];

    float4 z4 = make_float4(0.f, 0.f, 0.f, 0.f);
    *(float4*)&Sin[(size_t)(h * 16) * 4096 + (size_t)i * 64 + jq] = z4;
    Sc[i][jq + 0] = 0.f; Sc[i][jq + 1] = 0.f;
    Sc[i][jq + 2] = 0.f; Sc[i][jq + 3] = 0.f;
    float4 pv = *(const float4*)&Pend[(size_t)(h * 15) * 4096 + idx];
    float4 sv = *(const float4*)&Send[(size_t)(h * 15) * 4096 + (size_t)i * 64 + jq];
    __syncthreads();

    for (int g = 1; g < 16; ++g) {
        *(float4*)&Pl[idx >> 6][idx & 63] = pv;
        __syncthreads();                       // Pl ready; Sc(g-1) visible
        float4 pv2 = z4, sv2 = z4;
        if (g < 15) {                          // prefetch next iteration
            pv2 = *(const float4*)&Pend[(size_t)(h * 15 + g) * 4096 + idx];
            sv2 = *(const float4*)&Send[(size_t)(h * 15 + g) * 4096 + (size_t)i * 64 + jq];
        }
        float acc[4] = {sv.x, sv.y, sv.z, sv.w};
        for (int k = 0; k < 64; ++k) {
            float sik = Sc[i][k];
#pragma unroll
            for (int c = 0; c < 4; ++c) acc[c] = fmaf(sik, Pl[k][jq + c], acc[c]);
        }
        __syncthreads();                       // all reads of Sc/Pl done
        Sc[i][jq + 0] = acc[0]; Sc[i][jq + 1] = acc[1];
        Sc[i][jq + 2] = acc[2]; Sc[i][jq + 3] = acc[3];
        *(float4*)&Sin[(size_t)(h * 16 + g) * 4096 + (size_t)i * 64 + jq] =
            make_float4(acc[0], acc[1], acc[2], acc[3]);
        pv = pv2; sv = sv2;
    }
}

// ---------------------------------------------------------------------------
// WKV7 segmented scan, pass 2. Grid (16 segs, 32 heads) = 512 blocks (2/CU,
// 2 waves/SIMD). 256 thr (4 waves x 16 rows; 4 row-states/lane). Replay
// 64-step segment from exact Sin(h,g), emit Y as float4.
// ---------------------------------------------------------------------------
__global__ __launch_bounds__(256) void k_wkv_p2(
    const float* __restrict__ R, const float* __restrict__ DEC,
    const float* __restrict__ K, const float* __restrict__ V,
    const float* __restrict__ KK, const float* __restrict__ Bb,
    const float* __restrict__ Sin, float* __restrict__ Y)
{
    const int tid = threadIdx.x;
    const int g = blockIdx.x;                  // segment 0..15
    const int h = blockIdx.y;
    const int c0 = h * 64;
    const int wv = tid >> 6, lane = tid & 63;
    const int jg = lane & 15, q = lane >> 4, j4 = jg * 4;
    const int row0 = wv * 16 + q * 4;          // rows row0..row0+3

    __shared__ __align__(16) float rS[2][16][64], dS[2][16][64], kS[2][16][64],
                                   aS[2][16][64], bS[2][16][64], vS[2][16][64];

    const int pst = tid >> 4, pq4 = (tid & 15) * 4;

#define P2_STAGE(buf, tcb) do {                                               \
    size_t gg = (size_t)((tcb) + pst) * C_ + c0 + pq4;                        \
    async_cp16(&R[gg],   &rS[buf][pst][pq4]);                                 \
    async_cp16(&DEC[gg], &dS[buf][pst][pq4]);                                 \
    async_cp16(&K[gg],   &kS[buf][pst][pq4]);                                 \
    async_cp16(&V[gg],   &vS[buf][pst][pq4]);                                 \
    async_cp16(&KK[gg],  &aS[buf][pst][pq4]);                                 \
    async_cp16(&Bb[gg],  &bS[buf][pst][pq4]);                                 \
} while (0)

    float4 s0, s1, s2, s3;
    {
        const float* Sb = &Sin[(size_t)((h * 16 + g) * 64 + row0) * 64 + j4];
        s0 = *(const float4*)&Sb[0];
        s1 = *(const float4*)&Sb[64];
        s2 = *(const float4*)&Sb[128];
        s3 = *(const float4*)&Sb[192];
    }

    const int t0 = g * 64;
    P2_STAGE(0, t0);

    for (int tc = 0; tc < 64; tc += 16) {
        const int p = (tc >> 4) & 1;
        __syncthreads();                               // buf p ready
        if (tc + 16 < 64) P2_STAGE(p ^ 1, t0 + tc + 16);
#pragma unroll
        for (int hh = 0; hh < 2; ++hh) {
            float po0[8], po1[8], po2[8], po3[8];
#pragma unroll
            for (int qs2 = 0; qs2 < 8; ++qs2) {
                const int tt = hh * 8 + qs2;
                float4 cr = *(float4*)&rS[p][tt][j4];
                float4 cd = *(float4*)&dS[p][tt][j4];
                float4 ck = *(float4*)&kS[p][tt][j4];
                float4 ca = *(float4*)&aS[p][tt][j4];
                float4 cb = *(float4*)&bS[p][tt][j4];
                float4 vv = *(float4*)&vS[p][tt][row0];
                float sa0 = -(fmaf(s0.y, ca.y, s0.x * ca.x) + fmaf(s0.w, ca.w, s0.z * ca.z));
                float sa1 = -(fmaf(s1.y, ca.y, s1.x * ca.x) + fmaf(s1.w, ca.w, s1.z * ca.z));
                float sa2 = -(fmaf(s2.y, ca.y, s2.x * ca.x) + fmaf(s2.w, ca.w, s2.z * ca.z));
                float sa3 = -(fmaf(s3.y, ca.y, s3.x * ca.x) + fmaf(s3.w, ca.w, s3.z * ca.z));
                REDUCE16(sa0); REDUCE16(sa1); REDUCE16(sa2); REDUCE16(sa3);
                s0.x = fmaf(s0.x, cd.x, fmaf(sa0, cb.x, vv.x * ck.x));
                s0.y = fmaf(s0.y, cd.y, fmaf(sa0, cb.y, vv.x * ck.y));
                s0.z = fmaf(s0.z, cd.z, fmaf(sa0, cb.z, vv.x * ck.z));
                s0.w = fmaf(s0.w, cd.w, fmaf(sa0, cb.w, vv.x * ck.w));
                s1.x = fmaf(s1.x, cd.x, fmaf(sa1, cb.x, vv.y * ck.x));
                s1.y = fmaf(s1.y, cd.y, fmaf(sa1, cb.y, vv.y * ck.y));
                s1.z = fmaf(s1.z, cd.z, fmaf(sa1, cb.z, vv.y * ck.z));
                s1.w = fmaf(s1.w, cd.w, fmaf(sa1, cb.w, vv.y * ck.w));
                s2.x = fmaf(s2.x, cd.x, fmaf(sa2, cb.x, vv.z * ck.x));
                s2.y = fmaf(s2.y, cd.y, fmaf(sa2, cb.y, vv.z * ck.y));
                s2.z = fmaf(s2.z, cd.z, fmaf(sa2, cb.z, vv.z * ck.z));
                s2.w = fmaf(s2.w, cd.w, fmaf(sa2, cb.w, vv.z * ck.w));
                s3.x = fmaf(s3.x, cd.x, fmaf(sa3, cb.x, vv.w * ck.x));
                s3.y = fmaf(s3.y, cd.y, fmaf(sa3, cb.y, vv.w * ck.y));
                s3.z = fmaf(s3.z, cd.z, fmaf(sa3, cb.z, vv.w * ck.z));
                s3.w = fmaf(s3.w, cd.w, fmaf(sa3, cb.w, vv.w * ck.w));
                po0[qs2] = fmaf(s0.w, cr.w, fmaf(s0.z, cr.z, fmaf(s0.y, cr.y, s0.x * cr.x)));
                po1[qs2] = fmaf(s1.w, cr.w, fmaf(s1.z, cr.z, fmaf(s1.y, cr.y, s1.x * cr.x)));
                po2[qs2] = fmaf(s2.w, cr.w, fmaf(s2.z, cr.z, fmaf(s2.y, cr.y, s2.x * cr.x)));
                po3[qs2] = fmaf(s3.w, cr.w, fmaf(s3.z, cr.z, fmaf(s3.y, cr.y, s3.x * cr.x)));
            }
            // deferred: 32 independent DPP butterflies pipeline
#pragma unroll
            for (int qs2 = 0; qs2 < 8; ++qs2) {
                REDUCE16(po0[qs2]); REDUCE16(po1[qs2]);
                REDUCE16(po2[qs2]); REDUCE16(po3[qs2]);
            }
            if (jg == 0) {
#pragma unroll
                for (int qs2 = 0; qs2 < 8; ++qs2) {
                    float4 o = make_float4(po0[qs2], po1[qs2], po2[qs2], po3[qs2]);
                    *(float4*)&Y[(size_t)(t0 + tc + hh * 8 + qs2) * C_ + c0 + row0] = o;
                }
            }
        }
    }
#undef P2_STAGE
}

// ---------------------------------------------------------------------------
// GroupNorm + bonus + fused gate, t-tiled (16 t/block so the 128 gw2 loads
// amortize): YG = f16((gn(y) + bonus) * (tanh(l2 sum) @ gate_w2)).
// ---------------------------------------------------------------------------
__global__ __launch_bounds__(256) void k_gn(
    const float* __restrict__ Y, const float* __restrict__ R, const float* __restrict__ K,
    const float* __restrict__ V, const float* __restrict__ l2p,
    const float* __restrict__ gw2,
    const float* __restrict__ faaaa, const float* __restrict__ lnw,
    const float* __restrict__ lnb, _Float16* __restrict__ YG)
{
    const int tid = threadIdx.x;
    const int c = blockIdx.x * 256 + tid;
    const int t0 = blockIdx.y * 16;
    const size_t P = (size_t)T_ * 256;
    __shared__ __align__(16) float gs[16][128];
    for (int id = tid; id < 16 * 128; id += 256) {
        int r = id >> 7, cc = id & 127;
        size_t off = (size_t)(t0 + r) * 256 + cc;
        float v = ((l2p[off] + l2p[P + off]) + l2p[2 * P + off]) + l2p[3 * P + off];
        gs[r][cc] = tanhf(v);
    }
    __syncthreads();
    float gacc[16];
#pragma unroll
    for (int r = 0; r < 16; ++r) gacc[r] = 0.f;
    for (int j = 0; j < 128; ++j) {
        float w = gw2[(size_t)j * C_ + c];
#pragma unroll
        for (int r = 0; r < 16; ++r) gacc[r] = fmaf(gs[r][j], w, gacc[r]);
    }
    float fa = faaaa[c], lw = lnw[c], lb = lnb[c];
    for (int r = 0; r < 16; ++r) {
        const size_t idx = (size_t)(t0 + r) * C_ + c;
        float y = Y[idx];
        float s1 = y, s2 = y * y;
#pragma unroll
        for (int off = 1; off < 64; off <<= 1) {
            s1 += __shfl_xor(s1, off, 64);
            s2 += __shfl_xor(s2, off, 64);
        }
        float mu = s1 * (1.0f / 64.0f);
        float var = s2 * (1.0f / 64.0f) - mu * mu;
        float gn = (y - mu) * rsqrtf(var + 0.00064f) * lw + lb;
        float p = R[idx] * K[idx] * fa;
#pragma unroll
        for (int off = 1; off < 64; off <<= 1) p += __shfl_xor(p, off, 64);
        float y2 = gn + p * V[idx];
        YG[idx] = (_Float16)(y2 * gacc[r]);
    }
}

// ---------------------------------------------------------------------------
extern "C" void kernel_launch(void* const* d_in, const int* in_sizes, int n_in,
                              void* d_out, int out_size, void* d_ws, size_t ws_size,
                              hipStream_t stream)
{
    (void)in_sizes; (void)n_in; (void)out_size; (void)ws_size;
    const float* hidden   = (const float*)d_in[0];
    const float* Wq       = (const float*)d_in[1];
    const float* Wk       = (const float*)d_in[2];
    const float* Wv       = (const float*)d_in[3];
    const float* Wo       = (const float*)d_in[4];
    const float* maa_x    = (const float*)d_in[5];
    const float* maa_rg   = (const float*)d_in[6];
    const float* maa_wa   = (const float*)d_in[7];
    const float* maa_k    = (const float*)d_in[8];
    const float* maa_v    = (const float*)d_in[9];
    const float* maa_w1   = (const float*)d_in[10];
    const float* maa_w2   = (const float*)d_in[11];
    const float* tdecay   = (const float*)d_in[12];
    const float* decay_w1 = (const float*)d_in[13];
    const float* decay_w2 = (const float*)d_in[14];
    const float* aaaaa    = (const float*)d_in[15];
    const float* aaa_w1   = (const float*)d_in[16];
    const float* aaa_w2   = (const float*)d_in[17];
    const float* kkk_w1   = (const float*)d_in[18];
    const float* kkk_w2   = (const float*)d_in[19];
    const float* gate_w1  = (const float*)d_in[20];
    const float* gate_w2  = (const float*)d_in[21];
    const float* misc_a   = (const float*)d_in[22];
    const float* ma_w1    = (const float*)d_in[23];
    const float* ma_w2    = (const float*)d_in[24];
    const float* misc_k   = (const float*)d_in[25];
    const float* mk_w1    = (const float*)d_in[26];
    const float* mk_w2    = (const float*)d_in[27];
    const float* faaaa    = (const float*)d_in[28];
    const float* lnw      = (const float*)d_in[29];
    const float* lnb      = (const float*)d_in[30];

    float* ws = (float*)d_ws;
    const size_t TC = (size_t)T_ * C_;
    // f32 buffers:
    //   S0: y   S2: b   S3: kk   S4: r   S5: dec   S6: k0 -> k   S7: v
    //   S1 slot (8MB): Send [32][15][64][64] f32 (7.5 MB)
    float* S0 = ws + 0 * TC;
    float* Send = ws + 1 * TC;
    float* S2 = ws + 2 * TC;
    float* S3 = ws + 3 * TC;
    float* S4 = ws + 4 * TC;
    float* S5 = ws + 5 * TC;
    float* S6 = ws + 6 * TC;
    float* S7 = ws + 7 * TC;
    float* m1p = ws + 8 * TC;                    // [4][T][128] partials
    float* l2p = m1p + (size_t)4 * T_ * 128;     // [4][T][256] partials
    // f16 region
    _Float16* WTq = (_Float16*)(l2p + (size_t)4 * T_ * 256);
    _Float16* WTk = WTq + (size_t)C_ * C_;
    _Float16* WTv = WTk + (size_t)C_ * C_;
    _Float16* WTo = WTv + (size_t)C_ * C_;
    _Float16* WTm = WTo + (size_t)C_ * C_;       // [128,2048]
    _Float16* WTl = WTm + (size_t)128 * C_;      // [256,2048]
    _Float16* xxxH = WTl + (size_t)256 * C_;
    _Float16* xrgH = xxxH + TC;
    _Float16* xwaH = xrgH + TC;
    _Float16* xkH  = xwaH + TC;
    _Float16* xvH  = xkH + TC;
    _Float16* ygH  = xxxH;                       // xxxH dead after step 6
    // After step 7, xrgH..xvH (16 MB contiguous f16 scratch) are dead:
    //   Sin  [32][16][64][64] f32 = 8 MB exactly -> xrgH+xwaH
    //   Pend [32][15][64][64] f32 = 7.5 MB       -> xkH+xvH
    float* Sin  = (float*)xrgH;
    float* Pend = (float*)xkH;
    // After p2/gn: S2 and Sin regions dead -> step-11 split-K partials.
    float* GP0 = S2;
    float* GP1 = Sin;
    float* out = (float*)d_out;

    // 1. transpose+convert big weights
    k_tr<<<dim3(32, 32, 4), 256, 0, stream>>>(Wq, Wk, Wv, Wo, WTq, WTk, WTv, WTo);
    // 2. pack+transpose LoRA weights (z=0/1) + fused xxxH prep (z=2)
    k_trW<<<dim3(8, 256, 3), 256, 0, stream>>>(maa_w1, gate_w1, decay_w1,
        aaa_w1, ma_w1, kkk_w1, mk_w1, hidden, maa_x, WTm, WTl, xxxH);
    // 3. m1 partials = xxxH @ WTm^T
    k_lora<<<dim3(16, 4, 4), 256, 0, stream>>>(0, xxxH, xxxH, xxxH, xxxH,
        WTm, WTl, m1p, l2p);
    // 4. xmix -> f16 operands
    k_xmix<<<dim3(8, 64), 256, 0, stream>>>(hidden, m1p, maa_w2,
        maa_rg, maa_wa, maa_k, maa_v, xrgH, xwaH, xkH, xvH);
    // 5. l2 partials (gate | decay | aaa | ma | kkk | mk)
    k_lora<<<dim3(16, 8, 4), 256, 0, stream>>>(1, xxxH, xrgH, xwaH, xkH,
        WTm, WTl, m1p, l2p);
    // 6. r, k0, v (f16 MFMA, 128^2 tile, counted-vmcnt pipeline: 384 blocks)
    k_gemm<<<dim3(16, 8, 3), 256, 0, stream>>>(
        xrgH, WTq, S4,  xkH, WTk, S6,  xvH, WTv, S7);
    // 7. fused stage-2: dec, kk (normalized), b, k_final (t-tile 4)
    k_fuse<<<dim3(8, 256), 256, 0, stream>>>(l2p, S6, decay_w2, aaa_w2, ma_w2,
        kkk_w2, mk_w2, tdecay, aaaaa, misc_a, misc_k, S5, S3, S2);
    // 8. WKV7 segmented scan (16 segments of 64 steps):
    //    8a. pass 1 (merged): local end-states + transition products
    k_wkv_p1<<<dim3(15, 32), 512, 0, stream>>>(S5, S6, S7, S3, S2, Send, Pend);
    //    8b. combine: Sin(g) = Sin(g-1) @ P(g-1) + Send(g-1)
    k_wkv_comb<<<dim3(32), 1024, 0, stream>>>(Send, Pend, Sin);
    //    8c. pass 2: replay segments from exact Sin, emit Y
    k_wkv_p2<<<dim3(16, 32), 256, 0, stream>>>(S4, S5, S6, S7, S3, S2, Sin, S0);
    // 9. groupnorm + bonus + fused gate -> f16 (reuses xxxH slot)
    k_gn<<<dim3(8, 64), 256, 0, stream>>>(S0, S4, S6, S7, l2p, gate_w2,
        faaaa, lnw, lnb, ygH);
    // 10. out = (y*g) @ Wo, split-K=2 (512 blocks = 2/CU) + reduce
    k_gemm64<<<dim3(32, 8, 2), 256, 0, stream>>>(ygH, WTo, GP0, GP1);
    k_red<<<dim3(2048), 256, 0, stream>>>(GP0, GP1, out);
}

// Round 9
// 508.169 us; speedup vs baseline: 1.0312x; 1.0083x over previous
//
#include <hip/hip_runtime.h>

// RWKV7 attention block, MI355X/gfx950.
// B=1, T=1024, C=2048, H=32, N=64. All inputs/outputs f32.
// Big GEMM step-6 v4: BM=BN=128, 3-buffer counted-vmcnt(4) pipeline +
// slot-XOR swizzle. PARKED: pipe-budget shows 48KB LDS/block-step = LDS
// data-pipe ceiling for this structure (465 TF measured).
// R9: k_tr (weight transpose, ~96MB, serial in chain but independent until
// k_gemm) MERGED into the lora0 launch as extra z-blocks -> HBM-bound tr
// blocks co-schedule with the 256 MFMA-bound lora blocks (94% of machine
// was idle during lora0). Combined = max(tr, lora0), not sum.
// Step-10: BN=64 split-K=2 + k_red. k_lora v2 (1 sync/step, reg prefetch).
// k_wkv_comb v2 (reg prefetch). WKV scan v9: 16 segments of 64 steps.

#define T_ 1024
#define C_ 2048
#define H_ 32
#define N_ 64

using half8  = __attribute__((ext_vector_type(8))) _Float16;  // 8 f16 (4 VGPRs)
using half4  = __attribute__((ext_vector_type(4))) _Float16;  // 8 B
using floatx4 = __attribute__((ext_vector_type(4))) float;    // 4 f32 acc

// DPP xor-add within 16-lane rows: quad_perm(0xB1)=xor1, quad_perm(0x4E)=xor2,
// row_half_mirror(0x141)=xor4, row_mirror(0x140)=xor8.
#define DPP_ADD(v, ctrl) \
    ((v) + __int_as_float(__builtin_amdgcn_update_dpp( \
        0, __float_as_int(v), (ctrl), 0xf, 0xf, true)))
#define REDUCE16(v) do { \
    v = DPP_ADD(v, 0xB1); v = DPP_ADD(v, 0x4E); \
    v = DPP_ADD(v, 0x141); v = DPP_ADD(v, 0x140); } while (0)

// async 16B global->LDS (direct-to-LDS DMA; HW dest = wave base + lane*16,
// all call sites construct per-lane lds ptrs matching exactly that layout)
__device__ __forceinline__ void async_cp16(const void* g, void* l) {
    __builtin_amdgcn_global_load_lds(
        (const __attribute__((address_space(1))) void*)g,
        (__attribute__((address_space(3))) void*)l, 16, 0, 0);
}

// ---------------------------------------------------------------------------
// COMBINED: weight transpose (z<4) + LoRA stage-1 GEMM which=0 (z==4).
// z<4: W[k][n] f32 -> WT[n][k] f16, tile 64x64 (blockIdx.x/y as before).
// z==4: flat = y*32+x < 256 -> (mt,nt,ks); m1p[ks][1024][128] = xxxH @ WTm^T.
// The tr blocks are HBM-bound, lora blocks MFMA/latency-bound: co-scheduled
// they hide each other (tr's outputs first consumed 2 launches later).
// ---------------------------------------------------------------------------
__global__ __launch_bounds__(256) void k_trlora(
    const float* __restrict__ W0, const float* __restrict__ W1,
    const float* __restrict__ W2, const float* __restrict__ W3,
    _Float16* __restrict__ D0, _Float16* __restrict__ D1,
    _Float16* __restrict__ D2, _Float16* __restrict__ D3,
    const _Float16* __restrict__ Axxx, const _Float16* __restrict__ WTm,
    float* __restrict__ m1p)
{
    __shared__ __align__(16) float tile[64][65];            // tr role
    __shared__ __align__(16) _Float16 As[2][64 * 40];       // lora role
    __shared__ __align__(16) _Float16 Bs[2][32 * 40];
    const int z = blockIdx.z;
    const int tid = threadIdx.x;

    if (z < 4) {
        // ---- transpose role (== old k_tr) ----
        const float* S = (z == 0) ? W0 : (z == 1) ? W1 : (z == 2) ? W2 : W3;
        _Float16* D = (z == 0) ? D0 : (z == 1) ? D1 : (z == 2) ? D2 : D3;
        const int nb = blockIdx.x * 64, kb = blockIdx.y * 64;
        const int tr = tid >> 4, tc4 = (tid & 15) * 4;
#pragma unroll
        for (int p = 0; p < 4; ++p) {
            int row = p * 16 + tr;
            float4 v = *(const float4*)&S[(size_t)(kb + row) * C_ + nb + tc4];
            tile[row][tc4 + 0] = v.x; tile[row][tc4 + 1] = v.y;
            tile[row][tc4 + 2] = v.z; tile[row][tc4 + 3] = v.w;
        }
        __syncthreads();
#pragma unroll
        for (int p = 0; p < 4; ++p) {
            int n = p * 16 + tr;
            half4 u;
            u[0] = (_Float16)tile[tc4 + 0][n];
            u[1] = (_Float16)tile[tc4 + 1][n];
            u[2] = (_Float16)tile[tc4 + 2][n];
            u[3] = (_Float16)tile[tc4 + 3][n];
            *(half4*)&D[(size_t)(nb + n) * C_ + kb + tc4] = u;
        }
        return;
    }
    // ---- lora which=0 role ----
    const int flat = blockIdx.y * 32 + blockIdx.x;
    if (flat >= 256) return;
    const int mt = flat & 15, nt = (flat >> 4) & 3, ks = flat >> 6;
    float* O = m1p + (size_t)ks * T_ * 128;
    const int m0 = mt * 64, n0 = nt * 32, k0 = ks * 512;
    const int lane = tid & 63, wv = tid >> 6;
    const int r16 = lane & 15, q = lane >> 4;

    floatx4 acc[2];
    { floatx4 zv = {0.f, 0.f, 0.f, 0.f}; acc[0] = zv; acc[1] = zv; }

    const int arow = tid >> 2, ac8 = (tid & 3) * 8;
    const _Float16* ag = Axxx + (size_t)(m0 + arow) * C_ + k0 + ac8;
    const _Float16* bg = WTm + (size_t)(n0 + arow) * C_ + k0 + ac8;

    {
        half8 av = *(const half8*)ag;
        *(half8*)&As[0][arow * 40 + ac8] = av;
        if (tid < 128) {
            half8 bv = *(const half8*)bg;
            *(half8*)&Bs[0][arow * 40 + ac8] = bv;
        }
    }
    __syncthreads();

    for (int it = 0; it < 16; ++it) {
        const int p = it & 1;
        half8 av2, bv2;
        if (it < 15) {
            av2 = *(const half8*)(ag + (it + 1) * 32);
            if (tid < 128) bv2 = *(const half8*)(bg + (it + 1) * 32);
        }
        half8 af = *(const half8*)&As[p][(wv * 16 + r16) * 40 + q * 8];
        half8 b0 = *(const half8*)&Bs[p][(r16) * 40 + q * 8];
        half8 b1 = *(const half8*)&Bs[p][(16 + r16) * 40 + q * 8];
        acc[0] = __builtin_amdgcn_mfma_f32_16x16x32_f16(af, b0, acc[0], 0, 0, 0);
        acc[1] = __builtin_amdgcn_mfma_f32_16x16x32_f16(af, b1, acc[1], 0, 0, 0);
        if (it < 15) {
            *(half8*)&As[p ^ 1][arow * 40 + ac8] = av2;
            if (tid < 128) *(half8*)&Bs[p ^ 1][arow * 40 + ac8] = bv2;
        }
        __syncthreads();
    }
#pragma unroll
    for (int j = 0; j < 2; ++j)
#pragma unroll
        for (int e = 0; e < 4; ++e) {
            int row = m0 + wv * 16 + q * 4 + e;
            int col = n0 + j * 16 + r16;
            O[(size_t)row * 128 + col] = acc[j][e];
        }
}

// ---------------------------------------------------------------------------
// Pack+transpose LoRA weights to f16 WT[n][k] + fused xxxH prep (z=2).
// z=0: WT_m [128][2048] <- maa_w1[2048,128]
// z=1: WT_l [256][2048] <- gate(128) | decay(64) | aaa(16) | ma(16) | kkk(16) | mk(16)
// z=2: xxxH = f16( x + (x_prev - x) * maa_x ), float4-vectorized
// ---------------------------------------------------------------------------
__global__ __launch_bounds__(256) void k_trW(
    const float* __restrict__ maa_w1, const float* __restrict__ gate_w1,
    const float* __restrict__ decay_w1, const float* __restrict__ aaa_w1,
    const float* __restrict__ ma_w1, const float* __restrict__ kkk_w1,
    const float* __restrict__ mk_w1,
    const float* __restrict__ X, const float* __restrict__ maa_x,
    _Float16* __restrict__ WTm, _Float16* __restrict__ WTl,
    _Float16* __restrict__ xxxH)
{
    const int z = blockIdx.z;
    const int tid = threadIdx.x;
    if (z == 2) {                                   // fused k_prep
        const size_t e0 = ((size_t)(blockIdx.y * 8 + blockIdx.x) * 256 + tid) * 4;
        float4 cur = *(const float4*)&X[e0];
        float4 prev = make_float4(0.f, 0.f, 0.f, 0.f);
        if (e0 >= C_) prev = *(const float4*)&X[e0 - C_];
        const int c = (int)(e0 & (C_ - 1));
        float4 mx = *(const float4*)&maa_x[c];
        half4 o;
        o[0] = (_Float16)(cur.x + (prev.x - cur.x) * mx.x);
        o[1] = (_Float16)(cur.y + (prev.y - cur.y) * mx.y);
        o[2] = (_Float16)(cur.z + (prev.z - cur.z) * mx.z);
        o[3] = (_Float16)(cur.w + (prev.w - cur.w) * mx.w);
        *(half4*)&xxxH[e0] = o;
        return;
    }
    const int k = blockIdx.x * 256 + tid;           // 0..2047
    const int n = blockIdx.y;
    if (z == 0 && n >= 128) return;
    const float* src; int stride, col;
    _Float16* dst;
    if (z == 0) { src = maa_w1; stride = 128; col = n; dst = WTm; }
    else {
        dst = WTl;
        if (n < 128)      { src = gate_w1;  stride = 128; col = n; }
        else if (n < 192) { src = decay_w1; stride = 64;  col = n - 128; }
        else if (n < 208) { src = aaa_w1;   stride = 16;  col = n - 192; }
        else if (n < 224) { src = ma_w1;    stride = 16;  col = n - 208; }
        else if (n < 240) { src = kkk_w1;   stride = 16;  col = n - 224; }
        else              { src = mk_w1;    stride = 16;  col = n - 240; }
    }
    dst[(size_t)n * C_ + k] = (_Float16)src[(size_t)k * stride + col];
}

// ---------------------------------------------------------------------------
// LoRA MFMA GEMM v2 (which=1 only now), split-K -> per-split partials.
// BM=64, BN=32, BK=32, ksplit=4. 2-buffer LDS, ONE __syncthreads per step;
// next-step tiles loaded global->reg before this step's MFMAs.
// l2p[ks][1024][256], A per n-tile: 0-3 xrg | 4-6 xwa | 7 xk
// ---------------------------------------------------------------------------
__global__ __launch_bounds__(256) void k_lora(
    int which,
    const _Float16* __restrict__ Axxx, const _Float16* __restrict__ Axrg,
    const _Float16* __restrict__ Axwa, const _Float16* __restrict__ Axk,
    const _Float16* __restrict__ WTm, const _Float16* __restrict__ WTl,
    float* __restrict__ m1p, float* __restrict__ l2p)
{
    const int mt = blockIdx.x;      // 16 tiles of 64 rows
    const int nt = blockIdx.y;      // tiles of 32 cols
    const int ks = blockIdx.z;      // 4 K-chunks of 512
    const _Float16* A; const _Float16* BT; float* O; int ostride;
    if (which == 0) { A = Axxx; BT = WTm; O = m1p; ostride = 128; }
    else {
        BT = WTl; O = l2p; ostride = 256;
        A = (nt < 4) ? Axrg : (nt < 7) ? Axwa : Axk;
    }
    O += (size_t)ks * T_ * ostride;
    const int m0 = mt * 64, n0 = nt * 32, k0 = ks * 512;
    const int tid = threadIdx.x;
    __shared__ __align__(16) _Float16 As[2][64 * 40];
    __shared__ __align__(16) _Float16 Bs[2][32 * 40];
    const int lane = tid & 63, wv = tid >> 6;
    const int r16 = lane & 15, q = lane >> 4;

    floatx4 acc[2];
    { floatx4 zv = {0.f, 0.f, 0.f, 0.f}; acc[0] = zv; acc[1] = zv; }

    const int arow = tid >> 2, ac8 = (tid & 3) * 8;
    const _Float16* ag = A + (size_t)(m0 + arow) * C_ + k0 + ac8;
    const _Float16* bg = BT + (size_t)(n0 + arow) * C_ + k0 + ac8;

    {
        half8 av = *(const half8*)ag;
        *(half8*)&As[0][arow * 40 + ac8] = av;
        if (tid < 128) {
            half8 bv = *(const half8*)bg;
            *(half8*)&Bs[0][arow * 40 + ac8] = bv;
        }
    }
    __syncthreads();

    for (int it = 0; it < 16; ++it) {
        const int p = it & 1;
        half8 av2, bv2;
        if (it < 15) {                        // prefetch next tile into regs
            av2 = *(const half8*)(ag + (it + 1) * 32);
            if (tid < 128) bv2 = *(const half8*)(bg + (it + 1) * 32);
        }
        half8 af = *(const half8*)&As[p][(wv * 16 + r16) * 40 + q * 8];
        half8 b0 = *(const half8*)&Bs[p][(r16) * 40 + q * 8];
        half8 b1 = *(const half8*)&Bs[p][(16 + r16) * 40 + q * 8];
        acc[0] = __builtin_amdgcn_mfma_f32_16x16x32_f16(af, b0, acc[0], 0, 0, 0);
        acc[1] = __builtin_amdgcn_mfma_f32_16x16x32_f16(af, b1, acc[1], 0, 0, 0);
        if (it < 15) {                        // write next tile to other buf
            *(half8*)&As[p ^ 1][arow * 40 + ac8] = av2;
            if (tid < 128) *(half8*)&Bs[p ^ 1][arow * 40 + ac8] = bv2;
        }
        __syncthreads();                      // next-buf writes visible
    }
#pragma unroll
    for (int j = 0; j < 2; ++j)
#pragma unroll
        for (int e = 0; e < 4; ++e) {
            int row = m0 + wv * 16 + q * 4 + e;
            int col = n0 + j * 16 + r16;
            O[(size_t)row * ostride + col] = acc[j][e];
        }
}

// ---------------------------------------------------------------------------
// xmix: m1 = sum_ks(m1p), tanh; mix = einsum(m1[T,4,32], maa_w2[4,32,C]);
// emit f16 GEMM operands xrgH/xwaH/xkH/xvH.
// ---------------------------------------------------------------------------
__global__ __launch_bounds__(256) void k_xmix(
    const float* __restrict__ X, const float* __restrict__ m1p,
    const float* __restrict__ w2,
    const float* __restrict__ mrg, const float* __restrict__ mwa,
    const float* __restrict__ mk, const float* __restrict__ mv,
    _Float16* __restrict__ xrgH, _Float16* __restrict__ xwaH,
    _Float16* __restrict__ xkH, _Float16* __restrict__ xvH)
{
    const int tid = threadIdx.x;
    const int c = blockIdx.x * 256 + tid;
    const int t0 = blockIdx.y * 16;
    const size_t P = (size_t)T_ * 128;
    __shared__ __align__(16) float m1s[16][128];
#pragma unroll
    for (int p = 0; p < 2; ++p) {
        int id = tid + p * 256;
        int r = id >> 5, c4 = (id & 31) * 4;
        size_t off = (size_t)(t0 + r) * 128 + c4;
        float4 v0 = *(const float4*)&m1p[off];
        float4 v1 = *(const float4*)&m1p[P + off];
        float4 v2 = *(const float4*)&m1p[2 * P + off];
        float4 v3 = *(const float4*)&m1p[3 * P + off];
        float4 v;
        v.x = tanhf(((v0.x + v1.x) + v2.x) + v3.x);
        v.y = tanhf(((v0.y + v1.y) + v2.y) + v3.y);
        v.z = tanhf(((v0.z + v1.z) + v2.z) + v3.z);
        v.w = tanhf(((v0.w + v1.w) + v2.w) + v3.w);
        *(float4*)&m1s[r][c4] = v;
    }
    __syncthreads();
    float a0[16], a1[16], a2[16], a3[16];
#pragma unroll
    for (int t = 0; t < 16; ++t) { a0[t] = 0.f; a1[t] = 0.f; a2[t] = 0.f; a3[t] = 0.f; }
    for (int d = 0; d < 32; ++d) {
        float w0 = w2[(size_t)(0 * 32 + d) * C_ + c];
        float w1 = w2[(size_t)(1 * 32 + d) * C_ + c];
        float w2v = w2[(size_t)(2 * 32 + d) * C_ + c];
        float w3 = w2[(size_t)(3 * 32 + d) * C_ + c];
#pragma unroll
        for (int t = 0; t < 16; ++t) {
            a0[t] = fmaf(m1s[t][d],      w0,  a0[t]);
            a1[t] = fmaf(m1s[t][32 + d], w1,  a1[t]);
            a2[t] = fmaf(m1s[t][64 + d], w2v, a2[t]);
            a3[t] = fmaf(m1s[t][96 + d], w3,  a3[t]);
        }
    }
    float vrg = mrg[c], vwa = mwa[c], vmk = mk[c], vmv = mv[c];
    float prev = (t0 > 0) ? X[(size_t)(t0 - 1) * C_ + c] : 0.0f;
    for (int t = 0; t < 16; ++t) {
        size_t idx = (size_t)(t0 + t) * C_ + c;
        float cur = X[idx];
        float dx = prev - cur;
        xrgH[idx] = (_Float16)(cur + dx * (vrg + a0[t]));
        xwaH[idx] = (_Float16)(cur + dx * (vwa + a1[t]));
        xkH[idx]  = (_Float16)(cur + dx * (vmk + a2[t]));
        xvH[idx]  = (_Float16)(cur + dx * (vmv + a3[t]));
        prev = cur;
    }
}

// ---------------------------------------------------------------------------
// f16 MFMA GEMM v4 (step 6): C[1024,2048] = A(f16) @ W via WT[n][k] f16.
// BM=BN=128, BK=32, 256 thr (4 waves 2x2), 4x4 16x16x32 tiles/wave.
// 3-buffer counted-vmcnt depth-2 pipeline + slot-XOR swizzle.
// ---------------------------------------------------------------------------
__global__ __launch_bounds__(256) void k_gemm(
    const _Float16* __restrict__ A0, const _Float16* __restrict__ B0, float* __restrict__ C0,
    const _Float16* __restrict__ A1, const _Float16* __restrict__ B1, float* __restrict__ C1,
    const _Float16* __restrict__ A2, const _Float16* __restrict__ B2, float* __restrict__ C2)
{
    const int z = blockIdx.z;
    const _Float16* A = (z == 0) ? A0 : (z == 1) ? A1 : A2;
    const _Float16* Bt = (z == 0) ? B0 : (z == 1) ? B1 : B2;
    float* C = (z == 0) ? C0 : (z == 1) ? C1 : C2;
    const int mtile = blockIdx.y * 128;
    const int ntile = blockIdx.x * 128;
    const int tid = threadIdx.x;
    __shared__ __align__(16) _Float16 As[3][128 * 32];
    __shared__ __align__(16) _Float16 Bs[3][128 * 32];
    const int lane = tid & 63;
    const int wvid = tid >> 6;
    const int wm = wvid >> 1, wn = wvid & 1;
    const int r16 = lane & 15, q = lane >> 4;
    // read-side swizzled slot offset (halfwords). (row>>1)&3 == (r16>>1)&3 for
    // every fragment row (wm*64, i*16, wn*64, j*16 all vanish in bits 1..2).
    const int qs = (q ^ ((r16 >> 1) & 3)) * 8;

    floatx4 acc[4][4];
#pragma unroll
    for (int i = 0; i < 4; ++i)
#pragma unroll
        for (int j = 0; j < 4; ++j) { floatx4 zv = {0.f, 0.f, 0.f, 0.f}; acc[i][j] = zv; }

    const int srow = tid >> 2, sq = tid & 3;
    const int sqg = (sq ^ ((srow >> 1) & 3)) * 8;   // inverse swizzle on source
    const _Float16* agA = A + (size_t)(mtile + srow) * C_ + sqg;
    const _Float16* agB = Bt + (size_t)(ntile + srow) * C_ + sqg;
    const int ldso = srow * 32 + sq * 8;            // linear DMA dest (tid*16B)
    const size_t rowoff = (size_t)64 * C_;          // (srow+64): same swizzle

    // 4 async_cp16 per stage per thread => vmcnt counts in units of 4.
#define G_STAGE(pb, koff) do {                                                \
        async_cp16(agA + (koff), &As[pb][ldso]);                              \
        async_cp16(agA + (koff) + rowoff, &As[pb][ldso + 64 * 32]);           \
        async_cp16(agB + (koff), &Bs[pb][ldso]);                              \
        async_cp16(agB + (koff) + rowoff, &Bs[pb][ldso + 64 * 32]);           \
    } while (0)

    G_STAGE(0, 0);
    G_STAGE(1, 32);
    __builtin_amdgcn_sched_barrier(0);
    asm volatile("s_waitcnt vmcnt(4)" ::: "memory");   // buf0 landed
    __builtin_amdgcn_s_barrier();
    __builtin_amdgcn_sched_barrier(0);

    for (int ks = 0; ks < 64; ++ks) {
        const int p = ks % 3;
        if (ks + 2 < 64) G_STAGE((ks + 2) % 3, (ks + 2) * 32);
        half8 af[4], bf[4];
#pragma unroll
        for (int i = 0; i < 4; ++i)
            af[i] = *(const half8*)&As[p][(wm * 64 + i * 16 + r16) * 32 + qs];
#pragma unroll
        for (int j = 0; j < 4; ++j)
            bf[j] = *(const half8*)&Bs[p][(wn * 64 + j * 16 + r16) * 32 + qs];
#pragma unroll
        for (int i = 0; i < 4; ++i)
#pragma unroll
            for (int j = 0; j < 4; ++j)
                acc[i][j] = __builtin_amdgcn_mfma_f32_16x16x32_f16(af[i], bf[j], acc[i][j], 0, 0, 0);
        __builtin_amdgcn_sched_barrier(0);
        if (ks + 2 < 64)
            asm volatile("s_waitcnt vmcnt(4)" ::: "memory");  // (k+1) landed
        else
            asm volatile("s_waitcnt vmcnt(0)" ::: "memory");  // tail drain
        __builtin_amdgcn_s_barrier();
        __builtin_amdgcn_sched_barrier(0);
    }
    // C/D layout: col = lane&15, row = (lane>>4)*4 + reg
#pragma unroll
    for (int i = 0; i < 4; ++i)
#pragma unroll
        for (int j = 0; j < 4; ++j)
#pragma unroll
            for (int e = 0; e < 4; ++e) {
                int row = mtile + wm * 64 + i * 16 + q * 4 + e;
                int col = ntile + wn * 64 + j * 16 + r16;
                C[(size_t)row * C_ + col] = acc[i][j][e];
            }
#undef G_STAGE
}

// ---------------------------------------------------------------------------
// f16 MFMA GEMM BN=64 SPLIT-K variant (step 10): z picks K-half, writes f32
// partial. Grid (32,8,2) = 512 blocks = 2/CU.
// ---------------------------------------------------------------------------
__global__ __launch_bounds__(256) void k_gemm64(
    const _Float16* __restrict__ A0, const _Float16* __restrict__ B0,
    float* __restrict__ P0, float* __restrict__ P1)
{
    const _Float16* A = A0;
    const _Float16* Bt = B0;
    float* C = (blockIdx.z == 0) ? P0 : P1;
    const int k0 = blockIdx.z * 1024;
    const int mtile = blockIdx.y * 128;
    const int ntile = blockIdx.x * 64;
    const int tid = threadIdx.x;
    __shared__ __align__(16) _Float16 As[3][128 * 32];
    __shared__ __align__(16) _Float16 Bs[3][64 * 32];
    const int lane = tid & 63;
    const int wvid = tid >> 6;
    const int wm = wvid >> 1, wn = wvid & 1;
    const int r16 = lane & 15, q = lane >> 4;
    const int qs = (q ^ ((r16 >> 1) & 3)) * 8;

    floatx4 acc[4][2];
#pragma unroll
    for (int i = 0; i < 4; ++i)
#pragma unroll
        for (int j = 0; j < 2; ++j) { floatx4 zv = {0.f, 0.f, 0.f, 0.f}; acc[i][j] = zv; }

    const int srow = tid >> 2, sq = tid & 3;
    const int sqg = (sq ^ ((srow >> 1) & 3)) * 8;
    const _Float16* agA = A + (size_t)(mtile + srow) * C_ + k0 + sqg;
    const _Float16* agB = Bt + (size_t)(ntile + srow) * C_ + k0 + sqg;
    const int ldso = srow * 32 + sq * 8;
    const size_t rowoff = (size_t)64 * C_;

#define G_STAGE(pb, koff) do {                                                \
        async_cp16(agA + (koff), &As[pb][ldso]);                              \
        async_cp16(agA + (koff) + rowoff, &As[pb][ldso + 64 * 32]);           \
        async_cp16(agB + (koff), &Bs[pb][ldso]);                              \
    } while (0)

    G_STAGE(0, 0);
    G_STAGE(1, 32);
    __builtin_amdgcn_sched_barrier(0);
    asm volatile("s_waitcnt vmcnt(3)" ::: "memory");
    __builtin_amdgcn_s_barrier();
    __builtin_amdgcn_sched_barrier(0);

    for (int ks = 0; ks < 32; ++ks) {
        const int p = ks % 3;
        if (ks + 2 < 32) G_STAGE((ks + 2) % 3, (ks + 2) * 32);
        half8 af[4], bf[2];
#pragma unroll
        for (int i = 0; i < 4; ++i)
            af[i] = *(const half8*)&As[p][(wm * 64 + i * 16 + r16) * 32 + qs];
#pragma unroll
        for (int j = 0; j < 2; ++j)
            bf[j] = *(const half8*)&Bs[p][(wn * 32 + j * 16 + r16) * 32 + qs];
#pragma unroll
        for (int i = 0; i < 4; ++i)
#pragma unroll
            for (int j = 0; j < 2; ++j)
                acc[i][j] = __builtin_amdgcn_mfma_f32_16x16x32_f16(af[i], bf[j], acc[i][j], 0, 0, 0);
        __builtin_amdgcn_sched_barrier(0);
        if (ks + 2 < 32)
            asm volatile("s_waitcnt vmcnt(3)" ::: "memory");
        else
            asm volatile("s_waitcnt vmcnt(0)" ::: "memory");
        __builtin_amdgcn_s_barrier();
        __builtin_amdgcn_sched_barrier(0);
    }
#pragma unroll
    for (int i = 0; i < 4; ++i)
#pragma unroll
        for (int j = 0; j < 2; ++j)
#pragma unroll
            for (int e = 0; e < 4; ++e) {
                int row = mtile + wm * 64 + i * 16 + q * 4 + e;
                int col = ntile + wn * 32 + j * 16 + r16;
                C[(size_t)row * C_ + col] = acc[i][j][e];
            }
#undef G_STAGE
}

// ---------------------------------------------------------------------------
// out = P0 + P1 (split-K reduce for step 10). 2048 blocks x 256 thr x float4.
// ---------------------------------------------------------------------------
__global__ __launch_bounds__(256) void k_red(
    const float* __restrict__ P0, const float* __restrict__ P1,
    float* __restrict__ O)
{
    const size_t i = ((size_t)blockIdx.x * 256 + threadIdx.x) * 4;
    float4 a = *(const float4*)&P0[i];
    float4 b = *(const float4*)&P1[i];
    float4 o;
    o.x = a.x + b.x; o.y = a.y + b.y; o.z = a.z + b.z; o.w = a.w + b.w;
    *(float4*)&O[i] = o;
}

// ---------------------------------------------------------------------------
// Fused stage-2 v2: dec=exp(w), kk (normalized), b = kk*a, k_final.
// t-tile 4 (grid 8x256 = 2048 blocks -> 8 blocks/CU).
// ---------------------------------------------------------------------------
__global__ __launch_bounds__(256) void k_fuse(
    const float* __restrict__ l2p,
    float* __restrict__ K0,
    const float* __restrict__ decay_w2, const float* __restrict__ aaa_w2,
    const float* __restrict__ ma_w2, const float* __restrict__ kkk_w2,
    const float* __restrict__ mk_w2,
    const float* __restrict__ tdecay, const float* __restrict__ aaaaa,
    const float* __restrict__ misc_a, const float* __restrict__ misc_k,
    float* __restrict__ Dout, float* __restrict__ KKout, float* __restrict__ Bout)
{
    const int tid = threadIdx.x;
    const int c = blockIdx.x * 256 + tid;
    const int t0 = blockIdx.y * 4;
    const size_t P = (size_t)T_ * 256;
    __shared__ __align__(16) float wsS[4][96];   // decay64 | aaa16 | ma16
    __shared__ __align__(16) float ksS[4][32];   // kkk16 | mk16
    if (tid < 4 * 24) {
        int r = tid / 24, c4 = (tid % 24) * 4;
        size_t off = (size_t)(t0 + r) * 256 + 128 + c4;
        float4 v0 = *(const float4*)&l2p[off];
        float4 v1 = *(const float4*)&l2p[P + off];
        float4 v2 = *(const float4*)&l2p[2 * P + off];
        float4 v3 = *(const float4*)&l2p[3 * P + off];
        float4 v;
        v.x = ((v0.x + v1.x) + v2.x) + v3.x;
        v.y = ((v0.y + v1.y) + v2.y) + v3.y;
        v.z = ((v0.z + v1.z) + v2.z) + v3.z;
        v.w = ((v0.w + v1.w) + v2.w) + v3.w;
        if (c4 < 64) { v.x = tanhf(v.x); v.y = tanhf(v.y); v.z = tanhf(v.z); v.w = tanhf(v.w); }
        *(float4*)&wsS[r][c4] = v;
    }
    if (tid < 4 * 8) {
        int r = tid / 8, c4 = (tid % 8) * 4;
        size_t off = (size_t)(t0 + r) * 256 + 224 + c4;
        float4 v0 = *(const float4*)&l2p[off];
        float4 v1 = *(const float4*)&l2p[P + off];
        float4 v2 = *(const float4*)&l2p[2 * P + off];
        float4 v3 = *(const float4*)&l2p[3 * P + off];
        float4 v;
        v.x = ((v0.x + v1.x) + v2.x) + v3.x;
        v.y = ((v0.y + v1.y) + v2.y) + v3.y;
        v.z = ((v0.z + v1.z) + v2.z) + v3.z;
        v.w = ((v0.w + v1.w) + v2.w) + v3.w;
        if (c4 < 16) { v.x = tanhf(v.x); v.y = tanhf(v.y); v.z = tanhf(v.z); v.w = tanhf(v.w); }
        *(float4*)&ksS[r][c4] = v;
    }
    __syncthreads();
    float accW[4], accA[4], accMA[4], accKK[4], accMK[4];
#pragma unroll
    for (int r = 0; r < 4; ++r) { accW[r] = 0.f; accA[r] = 0.f; accMA[r] = 0.f; accKK[r] = 0.f; accMK[r] = 0.f; }
    for (int j = 0; j < 64; ++j) {
        float w = decay_w2[(size_t)j * C_ + c];
#pragma unroll
        for (int r = 0; r < 4; ++r) accW[r] = fmaf(wsS[r][j], w, accW[r]);
    }
    for (int j = 0; j < 16; ++j) {
        float wa = aaa_w2[(size_t)j * C_ + c];
        float wm = ma_w2[(size_t)j * C_ + c];
        float wk = kkk_w2[(size_t)j * C_ + c];
        float wq = mk_w2[(size_t)j * C_ + c];
#pragma unroll
        for (int r = 0; r < 4; ++r) {
            accA[r]  = fmaf(wsS[r][64 + j], wa, accA[r]);
            accMA[r] = fmaf(wsS[r][80 + j], wm, accMA[r]);
            accKK[r] = fmaf(ksS[r][j],      wk, accKK[r]);
            accMK[r] = fmaf(ksS[r][16 + j], wq, accMK[r]);
        }
    }
    float td = tdecay[c], aa = aaaaa[c], mia = misc_a[c], mik = misc_k[c];
#pragma unroll
    for (int r = 0; r < 4; ++r) {
        size_t idx = (size_t)(t0 + r) * C_ + c;
        float wraw = td + accW[r];
        float w = -__logf(1.0f + __expf(-wraw)) - 0.5f;   // -softplus(-x) - 0.5
        float a  = 1.0f / (1.0f + __expf(-(aa  + accA[r])));
        float mav = 1.0f / (1.0f + __expf(-(mia + accMA[r])));
        float mkv = 1.0f / (1.0f + __expf(-(mik + accMK[r])));
        float k0 = K0[idx];
        float kkun = k0 + accKK[r];
        float ss = kkun * kkun;
        REDUCE16(ss);
        ss += __shfl_xor(ss, 16, 64);
        ss += __shfl_xor(ss, 32, 64);
        float kn = kkun * (1.0f / fmaxf(sqrtf(ss), 1e-12f));
        Dout[idx]  = __expf(w);                 // dec, precomputed for the scan
        KKout[idx] = kn;
        Bout[idx]  = kn * a;
        K0[idx]    = k0 * (mav + a * (1.0f - mav)) * __expf(fminf(w * mkv, 0.0f));
    }
}

// ---------------------------------------------------------------------------
// WKV7 segmented scan, pass 1 (merged S+P). Grid (15 segs, 32 heads), 512 thr.
// 64-step segments (v9). Waves 0-3: S rows (init 0, +v k^T source). Waves
// 4-7: P rows (init I, vv=0). 4 row-states/lane; shared d/a/b (+k/v) staging.
// ---------------------------------------------------------------------------
__global__ __launch_bounds__(512) void k_wkv_p1(
    const float* __restrict__ DEC, const float* __restrict__ K,
    const float* __restrict__ V, const float* __restrict__ KK,
    const float* __restrict__ Bb,
    float* __restrict__ Send, float* __restrict__ Pend)
{
    const int tid = threadIdx.x;
    const int g = blockIdx.x;                  // segment 0..14
    const int h = blockIdx.y;                  // head
    const int c0 = h * 64;
    const int wv = tid >> 6, lane = tid & 63;
    const int jg = lane & 15, q = lane >> 4, j4 = jg * 4;
    const bool isS = wv < 4;
    const int row0 = (isS ? wv : wv - 4) * 16 + q * 4;   // rows row0..row0+3

    __shared__ __align__(16) float dS[2][16][64], kS[2][16][64], vS[2][16][64],
                                   aS[2][16][64], bS[2][16][64];

    const int pos = tid & 255, grp = tid >> 8;
    const int pst = pos >> 4, pq4 = (pos & 15) * 4;

#define P1_STAGE(buf, tcb) do {                                               \
    size_t gg = (size_t)((tcb) + pst) * C_ + c0 + pq4;                        \
    if (grp == 0) { async_cp16(&DEC[gg], &dS[buf][pst][pq4]);                 \
                    async_cp16(&KK[gg],  &aS[buf][pst][pq4]);                 \
                    async_cp16(&Bb[gg],  &bS[buf][pst][pq4]); }               \
    else          { async_cp16(&K[gg], &kS[buf][pst][pq4]);                   \
                    async_cp16(&V[gg], &vS[buf][pst][pq4]); }                 \
} while (0)

    float4 s0, s1, s2, s3;
    if (isS) {
        s0 = make_float4(0.f, 0.f, 0.f, 0.f); s1 = s0; s2 = s0; s3 = s0;
    } else {
#define IDROW(m) make_float4((j4 + 0 == row0 + (m)) ? 1.f : 0.f,              \
                             (j4 + 1 == row0 + (m)) ? 1.f : 0.f,              \
                             (j4 + 2 == row0 + (m)) ? 1.f : 0.f,              \
                             (j4 + 3 == row0 + (m)) ? 1.f : 0.f)
        s0 = IDROW(0); s1 = IDROW(1); s2 = IDROW(2); s3 = IDROW(3);
#undef IDROW
    }

    const int t0 = g * 64;
    P1_STAGE(0, t0);

    for (int tc = 0; tc < 64; tc += 16) {
        const int p = (tc >> 4) & 1;
        __syncthreads();                               // buf p ready
        if (tc + 16 < 64) P1_STAGE(p ^ 1, t0 + tc + 16);
#pragma unroll
        for (int tt = 0; tt < 16; ++tt) {
            float4 cd = *(float4*)&dS[p][tt][j4];
            float4 ca = *(float4*)&aS[p][tt][j4];
            float4 cb = *(float4*)&bS[p][tt][j4];
            float4 ck, vv;
            if (isS) {                                 // wave-uniform branch
                ck = *(float4*)&kS[p][tt][j4];
                vv = *(float4*)&vS[p][tt][row0];       // v for rows row0..+3
            } else {
                ck = make_float4(0.f, 0.f, 0.f, 0.f);
                vv = make_float4(0.f, 0.f, 0.f, 0.f);
            }
            float sa0 = -(fmaf(s0.y, ca.y, s0.x * ca.x) + fmaf(s0.w, ca.w, s0.z * ca.z));
            float sa1 = -(fmaf(s1.y, ca.y, s1.x * ca.x) + fmaf(s1.w, ca.w, s1.z * ca.z));
            float sa2 = -(fmaf(s2.y, ca.y, s2.x * ca.x) + fmaf(s2.w, ca.w, s2.z * ca.z));
            float sa3 = -(fmaf(s3.y, ca.y, s3.x * ca.x) + fmaf(s3.w, ca.w, s3.z * ca.z));
            REDUCE16(sa0); REDUCE16(sa1); REDUCE16(sa2); REDUCE16(sa3);
            s0.x = fmaf(s0.x, cd.x, fmaf(sa0, cb.x, vv.x * ck.x));
            s0.y = fmaf(s0.y, cd.y, fmaf(sa0, cb.y, vv.x * ck.y));
            s0.z = fmaf(s0.z, cd.z, fmaf(sa0, cb.z, vv.x * ck.z));
            s0.w = fmaf(s0.w, cd.w, fmaf(sa0, cb.w, vv.x * ck.w));
            s1.x = fmaf(s1.x, cd.x, fmaf(sa1, cb.x, vv.y * ck.x));
            s1.y = fmaf(s1.y, cd.y, fmaf(sa1, cb.y, vv.y * ck.y));
            s1.z = fmaf(s1.z, cd.z, fmaf(sa1, cb.z, vv.y * ck.z));
            s1.w = fmaf(s1.w, cd.w, fmaf(sa1, cb.w, vv.y * ck.w));
            s2.x = fmaf(s2.x, cd.x, fmaf(sa2, cb.x, vv.z * ck.x));
            s2.y = fmaf(s2.y, cd.y, fmaf(sa2, cb.y, vv.z * ck.y));
            s2.z = fmaf(s2.z, cd.z, fmaf(sa2, cb.z, vv.z * ck.z));
            s2.w = fmaf(s2.w, cd.w, fmaf(sa2, cb.w, vv.z * ck.w));
            s3.x = fmaf(s3.x, cd.x, fmaf(sa3, cb.x, vv.w * ck.x));
            s3.y = fmaf(s3.y, cd.y, fmaf(sa3, cb.y, vv.w * ck.y));
            s3.z = fmaf(s3.z, cd.z, fmaf(sa3, cb.z, vv.w * ck.z));
            s3.w = fmaf(s3.w, cd.w, fmaf(sa3, cb.w, vv.w * ck.w));
        }
    }
    float* dst = isS ? Send : Pend;
    size_t base = (size_t)((h * 15 + g) * 64 + row0) * 64 + j4;
    *(float4*)&dst[base +   0] = s0;
    *(float4*)&dst[base +  64] = s1;
    *(float4*)&dst[base + 128] = s2;
    *(float4*)&dst[base + 192] = s3;
#undef P1_STAGE
}

// ---------------------------------------------------------------------------
// WKV7 segmented scan, combine v2. 32 blocks (1/head) x 1024 thr.
// Sin(h,0) = 0; Sin(h,g) = Sin(h,g-1) @ P(h,g-1) + Send(h,g-1), g=1..15.
// g+1's P/Send prefetched into regs BEFORE g's fma chain.
// ---------------------------------------------------------------------------
__global__ __launch_bounds__(1024) void k_wkv_comb(
    const float* __restrict__ Send, const float* __restrict__ Pend,
    float* __restrict__ Sin)
{
    const int h = blockIdx.x;
    const int tid = threadIdx.x;
    const int i = tid >> 4;                    // row 0..63
    const int jq = (tid & 15) * 4;             // col group of 4
    const int idx = tid * 4;                   // P element base
    __shared__ float Sc[64][65];               // padded: Sc[i][k] conflict-free
    __shared__ __align__(16) float Pl[64][64];

    float4 z4 = make_float4(0.f, 0.f, 0.f, 0.f);
    *(float4*)&Sin[(size_t)(h * 16) * 4096 + (size_t)i * 64 + jq] = z4;
    Sc[i][jq + 0] = 0.f; Sc[i][jq + 1] = 0.f;
    Sc[i][jq + 2] = 0.f; Sc[i][jq + 3] = 0.f;
    float4 pv = *(const float4*)&Pend[(size_t)(h * 15) * 4096 + idx];
    float4 sv = *(const float4*)&Send[(size_t)(h * 15) * 4096 + (size_t)i * 64 + jq];
    __syncthreads();

    for (int g = 1; g < 16; ++g) {
        *(float4*)&Pl[idx >> 6][idx & 63] = pv;
        __syncthreads();                       // Pl ready; Sc(g-1) visible
        float4 pv2 = z4, sv2 = z4;
        if (g < 15) {                          // prefetch next iteration
            pv2 = *(const float4*)&Pend[(size_t)(h * 15 + g) * 4096 + idx];
            sv2 = *(const float4*)&Send[(size_t)(h * 15 + g) * 4096 + (size_t)i * 64 + jq];
        }
        float acc[4] = {sv.x, sv.y, sv.z, sv.w};
        for (int k = 0; k < 64; ++k) {
            float sik = Sc[i][k];
#pragma unroll
            for (int c = 0; c < 4; ++c) acc[c] = fmaf(sik, Pl[k][jq + c], acc[c]);
        }
        __syncthreads();                       // all reads of Sc/Pl done
        Sc[i][jq + 0] = acc[0]; Sc[i][jq + 1] = acc[1];
        Sc[i][jq + 2] = acc[2]; Sc[i][jq + 3] = acc[3];
        *(float4*)&Sin[(size_t)(h * 16 + g) * 4096 + (size_t)i * 64 + jq] =
            make_float4(acc[0], acc[1], acc[2], acc[3]);
        pv = pv2; sv = sv2;
    }
}

// ---------------------------------------------------------------------------
// WKV7 segmented scan, pass 2. Grid (16 segs, 32 heads) = 512 blocks (2/CU,
// 2 waves/SIMD). 256 thr (4 waves x 16 rows; 4 row-states/lane). Replay
// 64-step segment from exact Sin(h,g), emit Y as float4.
// ---------------------------------------------------------------------------
__global__ __launch_bounds__(256) void k_wkv_p2(
    const float* __restrict__ R, const float* __restrict__ DEC,
    const float* __restrict__ K, const float* __restrict__ V,
    const float* __restrict__ KK, const float* __restrict__ Bb,
    const float* __restrict__ Sin, float* __restrict__ Y)
{
    const int tid = threadIdx.x;
    const int g = blockIdx.x;                  // segment 0..15
    const int h = blockIdx.y;
    const int c0 = h * 64;
    const int wv = tid >> 6, lane = tid & 63;
    const int jg = lane & 15, q = lane >> 4, j4 = jg * 4;
    const int row0 = wv * 16 + q * 4;          // rows row0..row0+3

    __shared__ __align__(16) float rS[2][16][64], dS[2][16][64], kS[2][16][64],
                                   aS[2][16][64], bS[2][16][64], vS[2][16][64];

    const int pst = tid >> 4, pq4 = (tid & 15) * 4;

#define P2_STAGE(buf, tcb) do {                                               \
    size_t gg = (size_t)((tcb) + pst) * C_ + c0 + pq4;                        \
    async_cp16(&R[gg],   &rS[buf][pst][pq4]);                                 \
    async_cp16(&DEC[gg], &dS[buf][pst][pq4]);                                 \
    async_cp16(&K[gg],   &kS[buf][pst][pq4]);                                 \
    async_cp16(&V[gg],   &vS[buf][pst][pq4]);                                 \
    async_cp16(&KK[gg],  &aS[buf][pst][pq4]);                                 \
    async_cp16(&Bb[gg],  &bS[buf][pst][pq4]);                                 \
} while (0)

    float4 s0, s1, s2, s3;
    {
        const float* Sb = &Sin[(size_t)((h * 16 + g) * 64 + row0) * 64 + j4];
        s0 = *(const float4*)&Sb[0];
        s1 = *(const float4*)&Sb[64];
        s2 = *(const float4*)&Sb[128];
        s3 = *(const float4*)&Sb[192];
    }

    const int t0 = g * 64;
    P2_STAGE(0, t0);

    for (int tc = 0; tc < 64; tc += 16) {
        const int p = (tc >> 4) & 1;
        __syncthreads();                               // buf p ready
        if (tc + 16 < 64) P2_STAGE(p ^ 1, t0 + tc + 16);
#pragma unroll
        for (int hh = 0; hh < 2; ++hh) {
            float po0[8], po1[8], po2[8], po3[8];
#pragma unroll
            for (int qs2 = 0; qs2 < 8; ++qs2) {
                const int tt = hh * 8 + qs2;
                float4 cr = *(float4*)&rS[p][tt][j4];
                float4 cd = *(float4*)&dS[p][tt][j4];
                float4 ck = *(float4*)&kS[p][tt][j4];
                float4 ca = *(float4*)&aS[p][tt][j4];
                float4 cb = *(float4*)&bS[p][tt][j4];
                float4 vv = *(float4*)&vS[p][tt][row0];
                float sa0 = -(fmaf(s0.y, ca.y, s0.x * ca.x) + fmaf(s0.w, ca.w, s0.z * ca.z));
                float sa1 = -(fmaf(s1.y, ca.y, s1.x * ca.x) + fmaf(s1.w, ca.w, s1.z * ca.z));
                float sa2 = -(fmaf(s2.y, ca.y, s2.x * ca.x) + fmaf(s2.w, ca.w, s2.z * ca.z));
                float sa3 = -(fmaf(s3.y, ca.y, s3.x * ca.x) + fmaf(s3.w, ca.w, s3.z * ca.z));
                REDUCE16(sa0); REDUCE16(sa1); REDUCE16(sa2); REDUCE16(sa3);
                s0.x = fmaf(s0.x, cd.x, fmaf(sa0, cb.x, vv.x * ck.x));
                s0.y = fmaf(s0.y, cd.y, fmaf(sa0, cb.y, vv.x * ck.y));
                s0.z = fmaf(s0.z, cd.z, fmaf(sa0, cb.z, vv.x * ck.z));
                s0.w = fmaf(s0.w, cd.w, fmaf(sa0, cb.w, vv.x * ck.w));
                s1.x = fmaf(s1.x, cd.x, fmaf(sa1, cb.x, vv.y * ck.x));
                s1.y = fmaf(s1.y, cd.y, fmaf(sa1, cb.y, vv.y * ck.y));
                s1.z = fmaf(s1.z, cd.z, fmaf(sa1, cb.z, vv.y * ck.z));
                s1.w = fmaf(s1.w, cd.w, fmaf(sa1, cb.w, vv.y * ck.w));
                s2.x = fmaf(s2.x, cd.x, fmaf(sa2, cb.x, vv.z * ck.x));
                s2.y = fmaf(s2.y, cd.y, fmaf(sa2, cb.y, vv.z * ck.y));
                s2.z = fmaf(s2.z, cd.z, fmaf(sa2, cb.z, vv.z * ck.z));
                s2.w = fmaf(s2.w, cd.w, fmaf(sa2, cb.w, vv.z * ck.w));
                s3.x = fmaf(s3.x, cd.x, fmaf(sa3, cb.x, vv.w * ck.x));
                s3.y = fmaf(s3.y, cd.y, fmaf(sa3, cb.y, vv.w * ck.y));
                s3.z = fmaf(s3.z, cd.z, fmaf(sa3, cb.z, vv.w * ck.z));
                s3.w = fmaf(s3.w, cd.w, fmaf(sa3, cb.w, vv.w * ck.w));
                po0[qs2] = fmaf(s0.w, cr.w, fmaf(s0.z, cr.z, fmaf(s0.y, cr.y, s0.x * cr.x)));
                po1[qs2] = fmaf(s1.w, cr.w, fmaf(s1.z, cr.z, fmaf(s1.y, cr.y, s1.x * cr.x)));
                po2[qs2] = fmaf(s2.w, cr.w, fmaf(s2.z, cr.z, fmaf(s2.y, cr.y, s2.x * cr.x)));
                po3[qs2] = fmaf(s3.w, cr.w, fmaf(s3.z, cr.z, fmaf(s3.y, cr.y, s3.x * cr.x)));
            }
            // deferred: 32 independent DPP butterflies pipeline
#pragma unroll
            for (int qs2 = 0; qs2 < 8; ++qs2) {
                REDUCE16(po0[qs2]); REDUCE16(po1[qs2]);
                REDUCE16(po2[qs2]); REDUCE16(po3[qs2]);
            }
            if (jg == 0) {
#pragma unroll
                for (int qs2 = 0; qs2 < 8; ++qs2) {
                    float4 o = make_float4(po0[qs2], po1[qs2], po2[qs2], po3[qs2]);
                    *(float4*)&Y[(size_t)(t0 + tc + hh * 8 + qs2) * C_ + c0 + row0] = o;
                }
            }
        }
    }
#undef P2_STAGE
}

// ---------------------------------------------------------------------------
// GroupNorm + bonus + fused gate, t-tiled (16 t/block so the 128 gw2 loads
// amortize): YG = f16((gn(y) + bonus) * (tanh(l2 sum) @ gate_w2)).
// ---------------------------------------------------------------------------
__global__ __launch_bounds__(256) void k_gn(
    const float* __restrict__ Y, const float* __restrict__ R, const float* __restrict__ K,
    const float* __restrict__ V, const float* __restrict__ l2p,
    const float* __restrict__ gw2,
    const float* __restrict__ faaaa, const float* __restrict__ lnw,
    const float* __restrict__ lnb, _Float16* __restrict__ YG)
{
    const int tid = threadIdx.x;
    const int c = blockIdx.x * 256 + tid;
    const int t0 = blockIdx.y * 16;
    const size_t P = (size_t)T_ * 256;
    __shared__ __align__(16) float gs[16][128];
    for (int id = tid; id < 16 * 128; id += 256) {
        int r = id >> 7, cc = id & 127;
        size_t off = (size_t)(t0 + r) * 256 + cc;
        float v = ((l2p[off] + l2p[P + off]) + l2p[2 * P + off]) + l2p[3 * P + off];
        gs[r][cc] = tanhf(v);
    }
    __syncthreads();
    float gacc[16];
#pragma unroll
    for (int r = 0; r < 16; ++r) gacc[r] = 0.f;
    for (int j = 0; j < 128; ++j) {
        float w = gw2[(size_t)j * C_ + c];
#pragma unroll
        for (int r = 0; r < 16; ++r) gacc[r] = fmaf(gs[r][j], w, gacc[r]);
    }
    float fa = faaaa[c], lw = lnw[c], lb = lnb[c];
    for (int r = 0; r < 16; ++r) {
        const size_t idx = (size_t)(t0 + r) * C_ + c;
        float y = Y[idx];
        float s1 = y, s2 = y * y;
#pragma unroll
        for (int off = 1; off < 64; off <<= 1) {
            s1 += __shfl_xor(s1, off, 64);
            s2 += __shfl_xor(s2, off, 64);
        }
        float mu = s1 * (1.0f / 64.0f);
        float var = s2 * (1.0f / 64.0f) - mu * mu;
        float gn = (y - mu) * rsqrtf(var + 0.00064f) * lw + lb;
        float p = R[idx] * K[idx] * fa;
#pragma unroll
        for (int off = 1; off < 64; off <<= 1) p += __shfl_xor(p, off, 64);
        float y2 = gn + p * V[idx];
        YG[idx] = (_Float16)(y2 * gacc[r]);
    }
}

// ---------------------------------------------------------------------------
extern "C" void kernel_launch(void* const* d_in, const int* in_sizes, int n_in,
                              void* d_out, int out_size, void* d_ws, size_t ws_size,
                              hipStream_t stream)
{
    (void)in_sizes; (void)n_in; (void)out_size; (void)ws_size;
    const float* hidden   = (const float*)d_in[0];
    const float* Wq       = (const float*)d_in[1];
    const float* Wk       = (const float*)d_in[2];
    const float* Wv       = (const float*)d_in[3];
    const float* Wo       = (const float*)d_in[4];
    const float* maa_x    = (const float*)d_in[5];
    const float* maa_rg   = (const float*)d_in[6];
    const float* maa_wa   = (const float*)d_in[7];
    const float* maa_k    = (const float*)d_in[8];
    const float* maa_v    = (const float*)d_in[9];
    const float* maa_w1   = (const float*)d_in[10];
    const float* maa_w2   = (const float*)d_in[11];
    const float* tdecay   = (const float*)d_in[12];
    const float* decay_w1 = (const float*)d_in[13];
    const float* decay_w2 = (const float*)d_in[14];
    const float* aaaaa    = (const float*)d_in[15];
    const float* aaa_w1   = (const float*)d_in[16];
    const float* aaa_w2   = (const float*)d_in[17];
    const float* kkk_w1   = (const float*)d_in[18];
    const float* kkk_w2   = (const float*)d_in[19];
    const float* gate_w1  = (const float*)d_in[20];
    const float* gate_w2  = (const float*)d_in[21];
    const float* misc_a   = (const float*)d_in[22];
    const float* ma_w1    = (const float*)d_in[23];
    const float* ma_w2    = (const float*)d_in[24];
    const float* misc_k   = (const float*)d_in[25];
    const float* mk_w1    = (const float*)d_in[26];
    const float* mk_w2    = (const float*)d_in[27];
    const float* faaaa    = (const float*)d_in[28];
    const float* lnw      = (const float*)d_in[29];
    const float* lnb      = (const float*)d_in[30];

    float* ws = (float*)d_ws;
    const size_t TC = (size_t)T_ * C_;
    // f32 buffers:
    //   S0: y   S2: b   S3: kk   S4: r   S5: dec   S6: k0 -> k   S7: v
    //   S1 slot (8MB): Send [32][15][64][64] f32 (7.5 MB)
    float* S0 = ws + 0 * TC;
    float* Send = ws + 1 * TC;
    float* S2 = ws + 2 * TC;
    float* S3 = ws + 3 * TC;
    float* S4 = ws + 4 * TC;
    float* S5 = ws + 5 * TC;
    float* S6 = ws + 6 * TC;
    float* S7 = ws + 7 * TC;
    float* m1p = ws + 8 * TC;                    // [4][T][128] partials
    float* l2p = m1p + (size_t)4 * T_ * 128;     // [4][T][256] partials
    // f16 region
    _Float16* WTq = (_Float16*)(l2p + (size_t)4 * T_ * 256);
    _Float16* WTk = WTq + (size_t)C_ * C_;
    _Float16* WTv = WTk + (size_t)C_ * C_;
    _Float16* WTo = WTv + (size_t)C_ * C_;
    _Float16* WTm = WTo + (size_t)C_ * C_;       // [128,2048]
    _Float16* WTl = WTm + (size_t)128 * C_;      // [256,2048]
    _Float16* xxxH = WTl + (size_t)256 * C_;
    _Float16* xrgH = xxxH + TC;
    _Float16* xwaH = xrgH + TC;
    _Float16* xkH  = xwaH + TC;
    _Float16* xvH  = xkH + TC;
    _Float16* ygH  = xxxH;                       // xxxH dead after step 5
    // After step 6, xrgH..xvH (16 MB contiguous f16 scratch) are dead:
    //   Sin  [32][16][64][64] f32 = 8 MB exactly -> xrgH+xwaH
    //   Pend [32][15][64][64] f32 = 7.5 MB       -> xkH+xvH
    float* Sin  = (float*)xrgH;
    float* Pend = (float*)xkH;
    // After p2/gn: S2 and Sin regions dead -> step-10 split-K partials.
    float* GP0 = S2;
    float* GP1 = Sin;
    float* out = (float*)d_out;

    // 1. pack+transpose LoRA weights (z=0/1) + fused xxxH prep (z=2)
    k_trW<<<dim3(8, 256, 3), 256, 0, stream>>>(maa_w1, gate_w1, decay_w1,
        aaa_w1, ma_w1, kkk_w1, mk_w1, hidden, maa_x, WTm, WTl, xxxH);
    // 2. COMBINED: big-weight transposes (z<4, 4096 HBM-bound blocks)
    //    co-scheduled with m1 partials = xxxH @ WTm^T (z=4, 256 MFMA blocks)
    k_trlora<<<dim3(32, 32, 5), 256, 0, stream>>>(Wq, Wk, Wv, Wo,
        WTq, WTk, WTv, WTo, xxxH, WTm, m1p);
    // 3. xmix -> f16 operands
    k_xmix<<<dim3(8, 64), 256, 0, stream>>>(hidden, m1p, maa_w2,
        maa_rg, maa_wa, maa_k, maa_v, xrgH, xwaH, xkH, xvH);
    // 4. l2 partials (gate | decay | aaa | ma | kkk | mk)
    k_lora<<<dim3(16, 8, 4), 256, 0, stream>>>(1, xxxH, xrgH, xwaH, xkH,
        WTm, WTl, m1p, l2p);
    // 5. r, k0, v (f16 MFMA, 128^2 tile, counted-vmcnt pipeline: 384 blocks)
    k_gemm<<<dim3(16, 8, 3), 256, 0, stream>>>(
        xrgH, WTq, S4,  xkH, WTk, S6,  xvH, WTv, S7);
    // 6. fused stage-2: dec, kk (normalized), b, k_final (t-tile 4)
    k_fuse<<<dim3(8, 256), 256, 0, stream>>>(l2p, S6, decay_w2, aaa_w2, ma_w2,
        kkk_w2, mk_w2, tdecay, aaaaa, misc_a, misc_k, S5, S3, S2);
    // 7. WKV7 segmented scan (16 segments of 64 steps):
    //    7a. pass 1 (merged): local end-states + transition products
    k_wkv_p1<<<dim3(15, 32), 512, 0, stream>>>(S5, S6, S7, S3, S2, Send, Pend);
    //    7b. combine: Sin(g) = Sin(g-1) @ P(g-1) + Send(g-1)
    k_wkv_comb<<<dim3(32), 1024, 0, stream>>>(Send, Pend, Sin);
    //    7c. pass 2: replay segments from exact Sin, emit Y
    k_wkv_p2<<<dim3(16, 32), 256, 0, stream>>>(S4, S5, S6, S7, S3, S2, Sin, S0);
    // 8. groupnorm + bonus + fused gate -> f16 (reuses xxxH slot)
    k_gn<<<dim3(8, 64), 256, 0, stream>>>(S0, S4, S6, S7, l2p, gate_w2,
        faaaa, lnw, lnb, ygH);
    // 9. out = (y*g) @ Wo, split-K=2 (512 blocks = 2/CU) + reduce
    k_gemm64<<<dim3(32, 8, 2), 256, 0, stream>>>(ygH, WTo, GP0, GP1);
    k_red<<<dim3(2048), 256, 0, stream>>>(GP0, GP1, out);
}

// Round 10
// 494.178 us; speedup vs baseline: 1.0604x; 1.0283x over previous
//
#include <hip/hip_runtime.h>

// RWKV7 attention block, MI355X/gfx950.
// B=1, T=1024, C=2048, H=32, N=64. All inputs/outputs f32.
// R10: k_gemm (r/k0/v, 384 blocks = 1.5/CU, 25% grid tail) MERGED with
// k_lora(which=1) (512 small blocks) into one launch via z-roles: the two
// are mutually independent (both read only xmix outputs + weights, write
// disjoint l2p vs S4/S6/S7, both feed k_fuse). lora blocks backfill the
// gemm tail/latency bubbles; LDS aliased in one 48KB block (gemm layout;
// lora uses prefix) so gemm occupancy unchanged (3/CU).
// Big GEMM: BM=BN=128, 3-buffer counted-vmcnt(4) + slot-XOR swizzle (LDS
// data-pipe ceiling for this structure). Step-10: BN=64 split-K=2 + k_red.
// k_trlora: weight transposes co-scheduled with lora0. WKV scan v9: 16
// segments of 64 steps, merged S+P pass1, reg-prefetch combine.

#define T_ 1024
#define C_ 2048
#define H_ 32
#define N_ 64

using half8  = __attribute__((ext_vector_type(8))) _Float16;  // 8 f16 (4 VGPRs)
using half4  = __attribute__((ext_vector_type(4))) _Float16;  // 8 B
using floatx4 = __attribute__((ext_vector_type(4))) float;    // 4 f32 acc

// DPP xor-add within 16-lane rows: quad_perm(0xB1)=xor1, quad_perm(0x4E)=xor2,
// row_half_mirror(0x141)=xor4, row_mirror(0x140)=xor8.
#define DPP_ADD(v, ctrl) \
    ((v) + __int_as_float(__builtin_amdgcn_update_dpp( \
        0, __float_as_int(v), (ctrl), 0xf, 0xf, true)))
#define REDUCE16(v) do { \
    v = DPP_ADD(v, 0xB1); v = DPP_ADD(v, 0x4E); \
    v = DPP_ADD(v, 0x141); v = DPP_ADD(v, 0x140); } while (0)

// async 16B global->LDS (direct-to-LDS DMA; HW dest = wave base + lane*16,
// all call sites construct per-lane lds ptrs matching exactly that layout)
__device__ __forceinline__ void async_cp16(const void* g, void* l) {
    __builtin_amdgcn_global_load_lds(
        (const __attribute__((address_space(1))) void*)g,
        (__attribute__((address_space(3))) void*)l, 16, 0, 0);
}

// ---------------------------------------------------------------------------
// COMBINED: weight transpose (z<4) + LoRA stage-1 GEMM which=0 (z==4).
// z<4: W[k][n] f32 -> WT[n][k] f16, tile 64x64.
// z==4: flat = y*32+x < 256 -> (mt,nt,ks); m1p[ks][1024][128] = xxxH @ WTm^T.
// ---------------------------------------------------------------------------
__global__ __launch_bounds__(256) void k_trlora(
    const float* __restrict__ W0, const float* __restrict__ W1,
    const float* __restrict__ W2, const float* __restrict__ W3,
    _Float16* __restrict__ D0, _Float16* __restrict__ D1,
    _Float16* __restrict__ D2, _Float16* __restrict__ D3,
    const _Float16* __restrict__ Axxx, const _Float16* __restrict__ WTm,
    float* __restrict__ m1p)
{
    __shared__ __align__(16) float tile[64][65];            // tr role
    __shared__ __align__(16) _Float16 As[2][64 * 40];       // lora role
    __shared__ __align__(16) _Float16 Bs[2][32 * 40];
    const int z = blockIdx.z;
    const int tid = threadIdx.x;

    if (z < 4) {
        // ---- transpose role ----
        const float* S = (z == 0) ? W0 : (z == 1) ? W1 : (z == 2) ? W2 : W3;
        _Float16* D = (z == 0) ? D0 : (z == 1) ? D1 : (z == 2) ? D2 : D3;
        const int nb = blockIdx.x * 64, kb = blockIdx.y * 64;
        const int tr = tid >> 4, tc4 = (tid & 15) * 4;
#pragma unroll
        for (int p = 0; p < 4; ++p) {
            int row = p * 16 + tr;
            float4 v = *(const float4*)&S[(size_t)(kb + row) * C_ + nb + tc4];
            tile[row][tc4 + 0] = v.x; tile[row][tc4 + 1] = v.y;
            tile[row][tc4 + 2] = v.z; tile[row][tc4 + 3] = v.w;
        }
        __syncthreads();
#pragma unroll
        for (int p = 0; p < 4; ++p) {
            int n = p * 16 + tr;
            half4 u;
            u[0] = (_Float16)tile[tc4 + 0][n];
            u[1] = (_Float16)tile[tc4 + 1][n];
            u[2] = (_Float16)tile[tc4 + 2][n];
            u[3] = (_Float16)tile[tc4 + 3][n];
            *(half4*)&D[(size_t)(nb + n) * C_ + kb + tc4] = u;
        }
        return;
    }
    // ---- lora which=0 role ----
    const int flat = blockIdx.y * 32 + blockIdx.x;
    if (flat >= 256) return;
    const int mt = flat & 15, nt = (flat >> 4) & 3, ks = flat >> 6;
    float* O = m1p + (size_t)ks * T_ * 128;
    const int m0 = mt * 64, n0 = nt * 32, k0 = ks * 512;
    const int lane = tid & 63, wv = tid >> 6;
    const int r16 = lane & 15, q = lane >> 4;

    floatx4 acc[2];
    { floatx4 zv = {0.f, 0.f, 0.f, 0.f}; acc[0] = zv; acc[1] = zv; }

    const int arow = tid >> 2, ac8 = (tid & 3) * 8;
    const _Float16* ag = Axxx + (size_t)(m0 + arow) * C_ + k0 + ac8;
    const _Float16* bg = WTm + (size_t)(n0 + arow) * C_ + k0 + ac8;

    {
        half8 av = *(const half8*)ag;
        *(half8*)&As[0][arow * 40 + ac8] = av;
        if (tid < 128) {
            half8 bv = *(const half8*)bg;
            *(half8*)&Bs[0][arow * 40 + ac8] = bv;
        }
    }
    __syncthreads();

    for (int it = 0; it < 16; ++it) {
        const int p = it & 1;
        half8 av2, bv2;
        if (it < 15) {
            av2 = *(const half8*)(ag + (it + 1) * 32);
            if (tid < 128) bv2 = *(const half8*)(bg + (it + 1) * 32);
        }
        half8 af = *(const half8*)&As[p][(wv * 16 + r16) * 40 + q * 8];
        half8 b0 = *(const half8*)&Bs[p][(r16) * 40 + q * 8];
        half8 b1 = *(const half8*)&Bs[p][(16 + r16) * 40 + q * 8];
        acc[0] = __builtin_amdgcn_mfma_f32_16x16x32_f16(af, b0, acc[0], 0, 0, 0);
        acc[1] = __builtin_amdgcn_mfma_f32_16x16x32_f16(af, b1, acc[1], 0, 0, 0);
        if (it < 15) {
            *(half8*)&As[p ^ 1][arow * 40 + ac8] = av2;
            if (tid < 128) *(half8*)&Bs[p ^ 1][arow * 40 + ac8] = bv2;
        }
        __syncthreads();
    }
#pragma unroll
    for (int j = 0; j < 2; ++j)
#pragma unroll
        for (int e = 0; e < 4; ++e) {
            int row = m0 + wv * 16 + q * 4 + e;
            int col = n0 + j * 16 + r16;
            O[(size_t)row * 128 + col] = acc[j][e];
        }
}

// ---------------------------------------------------------------------------
// Pack+transpose LoRA weights to f16 WT[n][k] + fused xxxH prep (z=2).
// ---------------------------------------------------------------------------
__global__ __launch_bounds__(256) void k_trW(
    const float* __restrict__ maa_w1, const float* __restrict__ gate_w1,
    const float* __restrict__ decay_w1, const float* __restrict__ aaa_w1,
    const float* __restrict__ ma_w1, const float* __restrict__ kkk_w1,
    const float* __restrict__ mk_w1,
    const float* __restrict__ X, const float* __restrict__ maa_x,
    _Float16* __restrict__ WTm, _Float16* __restrict__ WTl,
    _Float16* __restrict__ xxxH)
{
    const int z = blockIdx.z;
    const int tid = threadIdx.x;
    if (z == 2) {                                   // fused k_prep
        const size_t e0 = ((size_t)(blockIdx.y * 8 + blockIdx.x) * 256 + tid) * 4;
        float4 cur = *(const float4*)&X[e0];
        float4 prev = make_float4(0.f, 0.f, 0.f, 0.f);
        if (e0 >= C_) prev = *(const float4*)&X[e0 - C_];
        const int c = (int)(e0 & (C_ - 1));
        float4 mx = *(const float4*)&maa_x[c];
        half4 o;
        o[0] = (_Float16)(cur.x + (prev.x - cur.x) * mx.x);
        o[1] = (_Float16)(cur.y + (prev.y - cur.y) * mx.y);
        o[2] = (_Float16)(cur.z + (prev.z - cur.z) * mx.z);
        o[3] = (_Float16)(cur.w + (prev.w - cur.w) * mx.w);
        *(half4*)&xxxH[e0] = o;
        return;
    }
    const int k = blockIdx.x * 256 + tid;           // 0..2047
    const int n = blockIdx.y;
    if (z == 0 && n >= 128) return;
    const float* src; int stride, col;
    _Float16* dst;
    if (z == 0) { src = maa_w1; stride = 128; col = n; dst = WTm; }
    else {
        dst = WTl;
        if (n < 128)      { src = gate_w1;  stride = 128; col = n; }
        else if (n < 192) { src = decay_w1; stride = 64;  col = n - 128; }
        else if (n < 208) { src = aaa_w1;   stride = 16;  col = n - 192; }
        else if (n < 224) { src = ma_w1;    stride = 16;  col = n - 208; }
        else if (n < 240) { src = kkk_w1;   stride = 16;  col = n - 224; }
        else              { src = mk_w1;    stride = 16;  col = n - 240; }
    }
    dst[(size_t)n * C_ + k] = (_Float16)src[(size_t)k * stride + col];
}

// ---------------------------------------------------------------------------
// xmix: m1 = sum_ks(m1p), tanh; mix = einsum(m1[T,4,32], maa_w2[4,32,C]);
// emit f16 GEMM operands xrgH/xwaH/xkH/xvH.
// ---------------------------------------------------------------------------
__global__ __launch_bounds__(256) void k_xmix(
    const float* __restrict__ X, const float* __restrict__ m1p,
    const float* __restrict__ w2,
    const float* __restrict__ mrg, const float* __restrict__ mwa,
    const float* __restrict__ mk, const float* __restrict__ mv,
    _Float16* __restrict__ xrgH, _Float16* __restrict__ xwaH,
    _Float16* __restrict__ xkH, _Float16* __restrict__ xvH)
{
    const int tid = threadIdx.x;
    const int c = blockIdx.x * 256 + tid;
    const int t0 = blockIdx.y * 16;
    const size_t P = (size_t)T_ * 128;
    __shared__ __align__(16) float m1s[16][128];
#pragma unroll
    for (int p = 0; p < 2; ++p) {
        int id = tid + p * 256;
        int r = id >> 5, c4 = (id & 31) * 4;
        size_t off = (size_t)(t0 + r) * 128 + c4;
        float4 v0 = *(const float4*)&m1p[off];
        float4 v1 = *(const float4*)&m1p[P + off];
        float4 v2 = *(const float4*)&m1p[2 * P + off];
        float4 v3 = *(const float4*)&m1p[3 * P + off];
        float4 v;
        v.x = tanhf(((v0.x + v1.x) + v2.x) + v3.x);
        v.y = tanhf(((v0.y + v1.y) + v2.y) + v3.y);
        v.z = tanhf(((v0.z + v1.z) + v2.z) + v3.z);
        v.w = tanhf(((v0.w + v1.w) + v2.w) + v3.w);
        *(float4*)&m1s[r][c4] = v;
    }
    __syncthreads();
    float a0[16], a1[16], a2[16], a3[16];
#pragma unroll
    for (int t = 0; t < 16; ++t) { a0[t] = 0.f; a1[t] = 0.f; a2[t] = 0.f; a3[t] = 0.f; }
    for (int d = 0; d < 32; ++d) {
        float w0 = w2[(size_t)(0 * 32 + d) * C_ + c];
        float w1 = w2[(size_t)(1 * 32 + d) * C_ + c];
        float w2v = w2[(size_t)(2 * 32 + d) * C_ + c];
        float w3 = w2[(size_t)(3 * 32 + d) * C_ + c];
#pragma unroll
        for (int t = 0; t < 16; ++t) {
            a0[t] = fmaf(m1s[t][d],      w0,  a0[t]);
            a1[t] = fmaf(m1s[t][32 + d], w1,  a1[t]);
            a2[t] = fmaf(m1s[t][64 + d], w2v, a2[t]);
            a3[t] = fmaf(m1s[t][96 + d], w3,  a3[t]);
        }
    }
    float vrg = mrg[c], vwa = mwa[c], vmk = mk[c], vmv = mv[c];
    float prev = (t0 > 0) ? X[(size_t)(t0 - 1) * C_ + c] : 0.0f;
    for (int t = 0; t < 16; ++t) {
        size_t idx = (size_t)(t0 + t) * C_ + c;
        float cur = X[idx];
        float dx = prev - cur;
        xrgH[idx] = (_Float16)(cur + dx * (vrg + a0[t]));
        xwaH[idx] = (_Float16)(cur + dx * (vwa + a1[t]));
        xkH[idx]  = (_Float16)(cur + dx * (vmk + a2[t]));
        xvH[idx]  = (_Float16)(cur + dx * (vmv + a3[t]));
        prev = cur;
    }
}

// ---------------------------------------------------------------------------
// COMBINED: f16 MFMA GEMM (z<3) + LoRA stage-1 which=1 (z in [3,7)).
// The two are mutually independent: both read only xmix outputs + weights,
// write disjoint outputs (S4/S6/S7 vs l2p), and both feed k_fuse. The 512
// lora blocks backfill the 384-block gemm grid's tail and latency bubbles.
// LDS aliased: one 48KB block (gemm layout As|Bs 3x4096 halfs each); lora
// uses the prefix (2x2560 | 2x1280 halfs).
// gemm role: BM=BN=128, BK=32, 4 waves 2x2, 4x4 tiles/wave, 3-buffer
// counted-vmcnt(4) pipeline + slot-XOR swizzle.
// lora role: BM=64 BN=32 BK=32 ksplit=4, 2-buffer, reg prefetch;
// l2p[ks][1024][256], A per n-tile: 0-3 xrg | 4-6 xwa | 7 xk.
// ---------------------------------------------------------------------------
__global__ __launch_bounds__(256) void k_gemmlora(
    const _Float16* __restrict__ A0, const _Float16* __restrict__ B0, float* __restrict__ C0,
    const _Float16* __restrict__ A1, const _Float16* __restrict__ B1, float* __restrict__ C1,
    const _Float16* __restrict__ A2, const _Float16* __restrict__ B2, float* __restrict__ C2,
    const _Float16* __restrict__ Axrg, const _Float16* __restrict__ Axwa,
    const _Float16* __restrict__ Axk, const _Float16* __restrict__ WTl,
    float* __restrict__ l2p)
{
    __shared__ __align__(16) _Float16 SMEM[3 * 4096 * 2];   // 49152 B
    const int z = blockIdx.z;
    const int tid = threadIdx.x;
    const int lane = tid & 63;
    const int r16 = lane & 15, q = lane >> 4;

    if (z < 3) {
        // ================= gemm role =================
        const _Float16* A = (z == 0) ? A0 : (z == 1) ? A1 : A2;
        const _Float16* Bt = (z == 0) ? B0 : (z == 1) ? B1 : B2;
        float* C = (z == 0) ? C0 : (z == 1) ? C1 : C2;
        const int mtile = blockIdx.y * 128;
        const int ntile = blockIdx.x * 128;
        _Float16* SA = SMEM;                 // [3][4096]
        _Float16* SB = SMEM + 3 * 4096;      // [3][4096]
        const int wvid = tid >> 6;
        const int wm = wvid >> 1, wn = wvid & 1;
        const int qs = (q ^ ((r16 >> 1) & 3)) * 8;

        floatx4 acc[4][4];
#pragma unroll
        for (int i = 0; i < 4; ++i)
#pragma unroll
            for (int j = 0; j < 4; ++j) { floatx4 zv = {0.f, 0.f, 0.f, 0.f}; acc[i][j] = zv; }

        const int srow = tid >> 2, sq = tid & 3;
        const int sqg = (sq ^ ((srow >> 1) & 3)) * 8;   // inverse swizzle
        const _Float16* agA = A + (size_t)(mtile + srow) * C_ + sqg;
        const _Float16* agB = Bt + (size_t)(ntile + srow) * C_ + sqg;
        const int ldso = srow * 32 + sq * 8;            // linear DMA dest
        const size_t rowoff = (size_t)64 * C_;

#define G_STAGE(pb, koff) do {                                                \
        async_cp16(agA + (koff), &SA[(pb) * 4096 + ldso]);                    \
        async_cp16(agA + (koff) + rowoff, &SA[(pb) * 4096 + ldso + 64 * 32]); \
        async_cp16(agB + (koff), &SB[(pb) * 4096 + ldso]);                    \
        async_cp16(agB + (koff) + rowoff, &SB[(pb) * 4096 + ldso + 64 * 32]); \
    } while (0)

        G_STAGE(0, 0);
        G_STAGE(1, 32);
        __builtin_amdgcn_sched_barrier(0);
        asm volatile("s_waitcnt vmcnt(4)" ::: "memory");   // buf0 landed
        __builtin_amdgcn_s_barrier();
        __builtin_amdgcn_sched_barrier(0);

        for (int ks = 0; ks < 64; ++ks) {
            const int p = ks % 3;
            if (ks + 2 < 64) G_STAGE((ks + 2) % 3, (ks + 2) * 32);
            half8 af[4], bf[4];
#pragma unroll
            for (int i = 0; i < 4; ++i)
                af[i] = *(const half8*)&SA[p * 4096 + (wm * 64 + i * 16 + r16) * 32 + qs];
#pragma unroll
            for (int j = 0; j < 4; ++j)
                bf[j] = *(const half8*)&SB[p * 4096 + (wn * 64 + j * 16 + r16) * 32 + qs];
#pragma unroll
            for (int i = 0; i < 4; ++i)
#pragma unroll
                for (int j = 0; j < 4; ++j)
                    acc[i][j] = __builtin_amdgcn_mfma_f32_16x16x32_f16(af[i], bf[j], acc[i][j], 0, 0, 0);
            __builtin_amdgcn_sched_barrier(0);
            if (ks + 2 < 64)
                asm volatile("s_waitcnt vmcnt(4)" ::: "memory");  // (k+1) done
            else
                asm volatile("s_waitcnt vmcnt(0)" ::: "memory");  // tail drain
            __builtin_amdgcn_s_barrier();
            __builtin_amdgcn_sched_barrier(0);
        }
#undef G_STAGE
        // C/D layout: col = lane&15, row = (lane>>4)*4 + reg
#pragma unroll
        for (int i = 0; i < 4; ++i)
#pragma unroll
            for (int j = 0; j < 4; ++j)
#pragma unroll
                for (int e = 0; e < 4; ++e) {
                    int row = mtile + wm * 64 + i * 16 + q * 4 + e;
                    int col = ntile + wn * 64 + j * 16 + r16;
                    C[(size_t)row * C_ + col] = acc[i][j][e];
                }
        return;
    }
    // ================= lora which=1 role =================
    const int mt = blockIdx.x;          // 16 tiles of 64 rows
    const int nt = blockIdx.y;          // 8 tiles of 32 cols
    const int ks = z - 3;               // 4 K-chunks of 512
    const _Float16* A = (nt < 4) ? Axrg : (nt < 7) ? Axwa : Axk;
    float* O = l2p + (size_t)ks * T_ * 256;
    const int m0 = mt * 64, n0 = nt * 32, k0 = ks * 512;
    _Float16* LA = SMEM;                // [2][2560]
    _Float16* LB = SMEM + 2 * 2560;     // [2][1280]
    const int wv = tid >> 6;

    floatx4 acc[2];
    { floatx4 zv = {0.f, 0.f, 0.f, 0.f}; acc[0] = zv; acc[1] = zv; }

    const int arow = tid >> 2, ac8 = (tid & 3) * 8;
    const _Float16* ag = A + (size_t)(m0 + arow) * C_ + k0 + ac8;
    const _Float16* bg = WTl + (size_t)(n0 + arow) * C_ + k0 + ac8;

    {
        half8 av = *(const half8*)ag;
        *(half8*)&LA[arow * 40 + ac8] = av;
        if (tid < 128) {
            half8 bv = *(const half8*)bg;
            *(half8*)&LB[arow * 40 + ac8] = bv;
        }
    }
    __syncthreads();

    for (int it = 0; it < 16; ++it) {
        const int p = it & 1;
        half8 av2, bv2;
        if (it < 15) {                        // prefetch next tile into regs
            av2 = *(const half8*)(ag + (it + 1) * 32);
            if (tid < 128) bv2 = *(const half8*)(bg + (it + 1) * 32);
        }
        half8 af = *(const half8*)&LA[p * 2560 + (wv * 16 + r16) * 40 + q * 8];
        half8 b0 = *(const half8*)&LB[p * 1280 + (r16) * 40 + q * 8];
        half8 b1 = *(const half8*)&LB[p * 1280 + (16 + r16) * 40 + q * 8];
        acc[0] = __builtin_amdgcn_mfma_f32_16x16x32_f16(af, b0, acc[0], 0, 0, 0);
        acc[1] = __builtin_amdgcn_mfma_f32_16x16x32_f16(af, b1, acc[1], 0, 0, 0);
        if (it < 15) {                        // write next tile to other buf
            *(half8*)&LA[(p ^ 1) * 2560 + arow * 40 + ac8] = av2;
            if (tid < 128) *(half8*)&LB[(p ^ 1) * 1280 + arow * 40 + ac8] = bv2;
        }
        __syncthreads();
    }
#pragma unroll
    for (int j = 0; j < 2; ++j)
#pragma unroll
        for (int e = 0; e < 4; ++e) {
            int row = m0 + wv * 16 + q * 4 + e;
            int col = n0 + j * 16 + r16;
            O[(size_t)row * 256 + col] = acc[j][e];
        }
}

// ---------------------------------------------------------------------------
// f16 MFMA GEMM BN=64 SPLIT-K variant (step 9): z picks K-half, writes f32
// partial. Grid (32,8,2) = 512 blocks = 2/CU.
// ---------------------------------------------------------------------------
__global__ __launch_bounds__(256) void k_gemm64(
    const _Float16* __restrict__ A0, const _Float16* __restrict__ B0,
    float* __restrict__ P0, float* __restrict__ P1)
{
    const _Float16* A = A0;
    const _Float16* Bt = B0;
    float* C = (blockIdx.z == 0) ? P0 : P1;
    const int k0 = blockIdx.z * 1024;
    const int mtile = blockIdx.y * 128;
    const int ntile = blockIdx.x * 64;
    const int tid = threadIdx.x;
    __shared__ __align__(16) _Float16 As[3][128 * 32];
    __shared__ __align__(16) _Float16 Bs[3][64 * 32];
    const int lane = tid & 63;
    const int wvid = tid >> 6;
    const int wm = wvid >> 1, wn = wvid & 1;
    const int r16 = lane & 15, q = lane >> 4;
    const int qs = (q ^ ((r16 >> 1) & 3)) * 8;

    floatx4 acc[4][2];
#pragma unroll
    for (int i = 0; i < 4; ++i)
#pragma unroll
        for (int j = 0; j < 2; ++j) { floatx4 zv = {0.f, 0.f, 0.f, 0.f}; acc[i][j] = zv; }

    const int srow = tid >> 2, sq = tid & 3;
    const int sqg = (sq ^ ((srow >> 1) & 3)) * 8;
    const _Float16* agA = A + (size_t)(mtile + srow) * C_ + k0 + sqg;
    const _Float16* agB = Bt + (size_t)(ntile + srow) * C_ + k0 + sqg;
    const int ldso = srow * 32 + sq * 8;
    const size_t rowoff = (size_t)64 * C_;

#define G_STAGE(pb, koff) do {                                                \
        async_cp16(agA + (koff), &As[pb][ldso]);                              \
        async_cp16(agA + (koff) + rowoff, &As[pb][ldso + 64 * 32]);           \
        async_cp16(agB + (koff), &Bs[pb][ldso]);                              \
    } while (0)

    G_STAGE(0, 0);
    G_STAGE(1, 32);
    __builtin_amdgcn_sched_barrier(0);
    asm volatile("s_waitcnt vmcnt(3)" ::: "memory");
    __builtin_amdgcn_s_barrier();
    __builtin_amdgcn_sched_barrier(0);

    for (int ks = 0; ks < 32; ++ks) {
        const int p = ks % 3;
        if (ks + 2 < 32) G_STAGE((ks + 2) % 3, (ks + 2) * 32);
        half8 af[4], bf[2];
#pragma unroll
        for (int i = 0; i < 4; ++i)
            af[i] = *(const half8*)&As[p][(wm * 64 + i * 16 + r16) * 32 + qs];
#pragma unroll
        for (int j = 0; j < 2; ++j)
            bf[j] = *(const half8*)&Bs[p][(wn * 32 + j * 16 + r16) * 32 + qs];
#pragma unroll
        for (int i = 0; i < 4; ++i)
#pragma unroll
            for (int j = 0; j < 2; ++j)
                acc[i][j] = __builtin_amdgcn_mfma_f32_16x16x32_f16(af[i], bf[j], acc[i][j], 0, 0, 0);
        __builtin_amdgcn_sched_barrier(0);
        if (ks + 2 < 32)
            asm volatile("s_waitcnt vmcnt(3)" ::: "memory");
        else
            asm volatile("s_waitcnt vmcnt(0)" ::: "memory");
        __builtin_amdgcn_s_barrier();
        __builtin_amdgcn_sched_barrier(0);
    }
#pragma unroll
    for (int i = 0; i < 4; ++i)
#pragma unroll
        for (int j = 0; j < 2; ++j)
#pragma unroll
            for (int e = 0; e < 4; ++e) {
                int row = mtile + wm * 64 + i * 16 + q * 4 + e;
                int col = ntile + wn * 32 + j * 16 + r16;
                C[(size_t)row * C_ + col] = acc[i][j][e];
            }
#undef G_STAGE
}

// ---------------------------------------------------------------------------
// out = P0 + P1 (split-K reduce for step 9). 2048 blocks x 256 thr x float4.
// ---------------------------------------------------------------------------
__global__ __launch_bounds__(256) void k_red(
    const float* __restrict__ P0, const float* __restrict__ P1,
    float* __restrict__ O)
{
    const size_t i = ((size_t)blockIdx.x * 256 + threadIdx.x) * 4;
    float4 a = *(const float4*)&P0[i];
    float4 b = *(const float4*)&P1[i];
    float4 o;
    o.x = a.x + b.x; o.y = a.y + b.y; o.z = a.z + b.z; o.w = a.w + b.w;
    *(float4*)&O[i] = o;
}

// ---------------------------------------------------------------------------
// Fused stage-2 v2: dec=exp(w), kk (normalized), b = kk*a, k_final.
// t-tile 4 (grid 8x256 = 2048 blocks -> 8 blocks/CU).
// ---------------------------------------------------------------------------
__global__ __launch_bounds__(256) void k_fuse(
    const float* __restrict__ l2p,
    float* __restrict__ K0,
    const float* __restrict__ decay_w2, const float* __restrict__ aaa_w2,
    const float* __restrict__ ma_w2, const float* __restrict__ kkk_w2,
    const float* __restrict__ mk_w2,
    const float* __restrict__ tdecay, const float* __restrict__ aaaaa,
    const float* __restrict__ misc_a, const float* __restrict__ misc_k,
    float* __restrict__ Dout, float* __restrict__ KKout, float* __restrict__ Bout)
{
    const int tid = threadIdx.x;
    const int c = blockIdx.x * 256 + tid;
    const int t0 = blockIdx.y * 4;
    const size_t P = (size_t)T_ * 256;
    __shared__ __align__(16) float wsS[4][96];   // decay64 | aaa16 | ma16
    __shared__ __align__(16) float ksS[4][32];   // kkk16 | mk16
    if (tid < 4 * 24) {
        int r = tid / 24, c4 = (tid % 24) * 4;
        size_t off = (size_t)(t0 + r) * 256 + 128 + c4;
        float4 v0 = *(const float4*)&l2p[off];
        float4 v1 = *(const float4*)&l2p[P + off];
        float4 v2 = *(const float4*)&l2p[2 * P + off];
        float4 v3 = *(const float4*)&l2p[3 * P + off];
        float4 v;
        v.x = ((v0.x + v1.x) + v2.x) + v3.x;
        v.y = ((v0.y + v1.y) + v2.y) + v3.y;
        v.z = ((v0.z + v1.z) + v2.z) + v3.z;
        v.w = ((v0.w + v1.w) + v2.w) + v3.w;
        if (c4 < 64) { v.x = tanhf(v.x); v.y = tanhf(v.y); v.z = tanhf(v.z); v.w = tanhf(v.w); }
        *(float4*)&wsS[r][c4] = v;
    }
    if (tid < 4 * 8) {
        int r = tid / 8, c4 = (tid % 8) * 4;
        size_t off = (size_t)(t0 + r) * 256 + 224 + c4;
        float4 v0 = *(const float4*)&l2p[off];
        float4 v1 = *(const float4*)&l2p[P + off];
        float4 v2 = *(const float4*)&l2p[2 * P + off];
        float4 v3 = *(const float4*)&l2p[3 * P + off];
        float4 v;
        v.x = ((v0.x + v1.x) + v2.x) + v3.x;
        v.y = ((v0.y + v1.y) + v2.y) + v3.y;
        v.z = ((v0.z + v1.z) + v2.z) + v3.z;
        v.w = ((v0.w + v1.w) + v2.w) + v3.w;
        if (c4 < 16) { v.x = tanhf(v.x); v.y = tanhf(v.y); v.z = tanhf(v.z); v.w = tanhf(v.w); }
        *(float4*)&ksS[r][c4] = v;
    }
    __syncthreads();
    float accW[4], accA[4], accMA[4], accKK[4], accMK[4];
#pragma unroll
    for (int r = 0; r < 4; ++r) { accW[r] = 0.f; accA[r] = 0.f; accMA[r] = 0.f; accKK[r] = 0.f; accMK[r] = 0.f; }
    for (int j = 0; j < 64; ++j) {
        float w = decay_w2[(size_t)j * C_ + c];
#pragma unroll
        for (int r = 0; r < 4; ++r) accW[r] = fmaf(wsS[r][j], w, accW[r]);
    }
    for (int j = 0; j < 16; ++j) {
        float wa = aaa_w2[(size_t)j * C_ + c];
        float wm = ma_w2[(size_t)j * C_ + c];
        float wk = kkk_w2[(size_t)j * C_ + c];
        float wq = mk_w2[(size_t)j * C_ + c];
#pragma unroll
        for (int r = 0; r < 4; ++r) {
            accA[r]  = fmaf(wsS[r][64 + j], wa, accA[r]);
            accMA[r] = fmaf(wsS[r][80 + j], wm, accMA[r]);
            accKK[r] = fmaf(ksS[r][j],      wk, accKK[r]);
            accMK[r] = fmaf(ksS[r][16 + j], wq, accMK[r]);
        }
    }
    float td = tdecay[c], aa = aaaaa[c], mia = misc_a[c], mik = misc_k[c];
#pragma unroll
    for (int r = 0; r < 4; ++r) {
        size_t idx = (size_t)(t0 + r) * C_ + c;
        float wraw = td + accW[r];
        float w = -__logf(1.0f + __expf(-wraw)) - 0.5f;   // -softplus(-x) - 0.5
        float a  = 1.0f / (1.0f + __expf(-(aa  + accA[r])));
        float mav = 1.0f / (1.0f + __expf(-(mia + accMA[r])));
        float mkv = 1.0f / (1.0f + __expf(-(mik + accMK[r])));
        float k0 = K0[idx];
        float kkun = k0 + accKK[r];
        float ss = kkun * kkun;
        REDUCE16(ss);
        ss += __shfl_xor(ss, 16, 64);
        ss += __shfl_xor(ss, 32, 64);
        float kn = kkun * (1.0f / fmaxf(sqrtf(ss), 1e-12f));
        Dout[idx]  = __expf(w);                 // dec, precomputed for the scan
        KKout[idx] = kn;
        Bout[idx]  = kn * a;
        K0[idx]    = k0 * (mav + a * (1.0f - mav)) * __expf(fminf(w * mkv, 0.0f));
    }
}

// ---------------------------------------------------------------------------
// WKV7 segmented scan, pass 1 (merged S+P). Grid (15 segs, 32 heads), 512 thr.
// 64-step segments. Waves 0-3: S rows (init 0, +v k^T source). Waves 4-7:
// P rows (init I, vv=0). 4 row-states/lane; shared d/a/b (+k/v) staging.
// ---------------------------------------------------------------------------
__global__ __launch_bounds__(512) void k_wkv_p1(
    const float* __restrict__ DEC, const float* __restrict__ K,
    const float* __restrict__ V, const float* __restrict__ KK,
    const float* __restrict__ Bb,
    float* __restrict__ Send, float* __restrict__ Pend)
{
    const int tid = threadIdx.x;
    const int g = blockIdx.x;                  // segment 0..14
    const int h = blockIdx.y;                  // head
    const int c0 = h * 64;
    const int wv = tid >> 6, lane = tid & 63;
    const int jg = lane & 15, q = lane >> 4, j4 = jg * 4;
    const bool isS = wv < 4;
    const int row0 = (isS ? wv : wv - 4) * 16 + q * 4;   // rows row0..row0+3

    __shared__ __align__(16) float dS[2][16][64], kS[2][16][64], vS[2][16][64],
                                   aS[2][16][64], bS[2][16][64];

    const int pos = tid & 255, grp = tid >> 8;
    const int pst = pos >> 4, pq4 = (pos & 15) * 4;

#define P1_STAGE(buf, tcb) do {                                               \
    size_t gg = (size_t)((tcb) + pst) * C_ + c0 + pq4;                        \
    if (grp == 0) { async_cp16(&DEC[gg], &dS[buf][pst][pq4]);                 \
                    async_cp16(&KK[gg],  &aS[buf][pst][pq4]);                 \
                    async_cp16(&Bb[gg],  &bS[buf][pst][pq4]); }               \
    else          { async_cp16(&K[gg], &kS[buf][pst][pq4]);                   \
                    async_cp16(&V[gg], &vS[buf][pst][pq4]); }                 \
} while (0)

    float4 s0, s1, s2, s3;
    if (isS) {
        s0 = make_float4(0.f, 0.f, 0.f, 0.f); s1 = s0; s2 = s0; s3 = s0;
    } else {
#define IDROW(m) make_float4((j4 + 0 == row0 + (m)) ? 1.f : 0.f,              \
                             (j4 + 1 == row0 + (m)) ? 1.f : 0.f,              \
                             (j4 + 2 == row0 + (m)) ? 1.f : 0.f,              \
                             (j4 + 3 == row0 + (m)) ? 1.f : 0.f)
        s0 = IDROW(0); s1 = IDROW(1); s2 = IDROW(2); s3 = IDROW(3);
#undef IDROW
    }

    const int t0 = g * 64;
    P1_STAGE(0, t0);

    for (int tc = 0; tc < 64; tc += 16) {
        const int p = (tc >> 4) & 1;
        __syncthreads();                               // buf p ready
        if (tc + 16 < 64) P1_STAGE(p ^ 1, t0 + tc + 16);
#pragma unroll
        for (int tt = 0; tt < 16; ++tt) {
            float4 cd = *(float4*)&dS[p][tt][j4];
            float4 ca = *(float4*)&aS[p][tt][j4];
            float4 cb = *(float4*)&bS[p][tt][j4];
            float4 ck, vv;
            if (isS) {                                 // wave-uniform branch
                ck = *(float4*)&kS[p][tt][j4];
                vv = *(float4*)&vS[p][tt][row0];       // v for rows row0..+3
            } else {
                ck = make_float4(0.f, 0.f, 0.f, 0.f);
                vv = make_float4(0.f, 0.f, 0.f, 0.f);
            }
            float sa0 = -(fmaf(s0.y, ca.y, s0.x * ca.x) + fmaf(s0.w, ca.w, s0.z * ca.z));
            float sa1 = -(fmaf(s1.y, ca.y, s1.x * ca.x) + fmaf(s1.w, ca.w, s1.z * ca.z));
            float sa2 = -(fmaf(s2.y, ca.y, s2.x * ca.x) + fmaf(s2.w, ca.w, s2.z * ca.z));
            float sa3 = -(fmaf(s3.y, ca.y, s3.x * ca.x) + fmaf(s3.w, ca.w, s3.z * ca.z));
            REDUCE16(sa0); REDUCE16(sa1); REDUCE16(sa2); REDUCE16(sa3);
            s0.x = fmaf(s0.x, cd.x, fmaf(sa0, cb.x, vv.x * ck.x));
            s0.y = fmaf(s0.y, cd.y, fmaf(sa0, cb.y, vv.x * ck.y));
            s0.z = fmaf(s0.z, cd.z, fmaf(sa0, cb.z, vv.x * ck.z));
            s0.w = fmaf(s0.w, cd.w, fmaf(sa0, cb.w, vv.x * ck.w));
            s1.x = fmaf(s1.x, cd.x, fmaf(sa1, cb.x, vv.y * ck.x));
            s1.y = fmaf(s1.y, cd.y, fmaf(sa1, cb.y, vv.y * ck.y));
            s1.z = fmaf(s1.z, cd.z, fmaf(sa1, cb.z, vv.y * ck.z));
            s1.w = fmaf(s1.w, cd.w, fmaf(sa1, cb.w, vv.y * ck.w));
            s2.x = fmaf(s2.x, cd.x, fmaf(sa2, cb.x, vv.z * ck.x));
            s2.y = fmaf(s2.y, cd.y, fmaf(sa2, cb.y, vv.z * ck.y));
            s2.z = fmaf(s2.z, cd.z, fmaf(sa2, cb.z, vv.z * ck.z));
            s2.w = fmaf(s2.w, cd.w, fmaf(sa2, cb.w, vv.z * ck.w));
            s3.x = fmaf(s3.x, cd.x, fmaf(sa3, cb.x, vv.w * ck.x));
            s3.y = fmaf(s3.y, cd.y, fmaf(sa3, cb.y, vv.w * ck.y));
            s3.z = fmaf(s3.z, cd.z, fmaf(sa3, cb.z, vv.w * ck.z));
            s3.w = fmaf(s3.w, cd.w, fmaf(sa3, cb.w, vv.w * ck.w));
        }
    }
    float* dst = isS ? Send : Pend;
    size_t base = (size_t)((h * 15 + g) * 64 + row0) * 64 + j4;
    *(float4*)&dst[base +   0] = s0;
    *(float4*)&dst[base +  64] = s1;
    *(float4*)&dst[base + 128] = s2;
    *(float4*)&dst[base + 192] = s3;
#undef P1_STAGE
}

// ---------------------------------------------------------------------------
// WKV7 segmented scan, combine v2. 32 blocks (1/head) x 1024 thr.
// Sin(h,0) = 0; Sin(h,g) = Sin(h,g-1) @ P(h,g-1) + Send(h,g-1), g=1..15.
// g+1's P/Send prefetched into regs BEFORE g's fma chain.
// ---------------------------------------------------------------------------
__global__ __launch_bounds__(1024) void k_wkv_comb(
    const float* __restrict__ Send, const float* __restrict__ Pend,
    float* __restrict__ Sin)
{
    const int h = blockIdx.x;
    const int tid = threadIdx.x;
    const int i = tid >> 4;                    // row 0..63
    const int jq = (tid & 15) * 4;             // col group of 4
    const int idx = tid * 4;                   // P element base
    __shared__ float Sc[64][65];               // padded: Sc[i][k] conflict-free
    __shared__ __align__(16) float Pl[64][64];

    float4 z4 = make_float4(0.f, 0.f, 0.f, 0.f);
    *(float4*)&Sin[(size_t)(h * 16) * 4096 + (size_t)i * 64 + jq] = z4;
    Sc[i][jq + 0] = 0.f; Sc[i][jq + 1] = 0.f;
    Sc[i][jq + 2] = 0.f; Sc[i][jq + 3] = 0.f;
    float4 pv = *(const float4*)&Pend[(size_t)(h * 15) * 4096 + idx];
    float4 sv = *(const float4*)&Send[(size_t)(h * 15) * 4096 + (size_t)i * 64 + jq];
    __syncthreads();

    for (int g = 1; g < 16; ++g) {
        *(float4*)&Pl[idx >> 6][idx & 63] = pv;
        __syncthreads();                       // Pl ready; Sc(g-1) visible
        float4 pv2 = z4, sv2 = z4;
        if (g < 15) {                          // prefetch next iteration
            pv2 = *(const float4*)&Pend[(size_t)(h * 15 + g) * 4096 + idx];
            sv2 = *(const float4*)&Send[(size_t)(h * 15 + g) * 4096 + (size_t)i * 64 + jq];
        }
        float acc[4] = {sv.x, sv.y, sv.z, sv.w};
        for (int k = 0; k < 64; ++k) {
            float sik = Sc[i][k];
#pragma unroll
            for (int c = 0; c < 4; ++c) acc[c] = fmaf(sik, Pl[k][jq + c], acc[c]);
        }
        __syncthreads();                       // all reads of Sc/Pl done
        Sc[i][jq + 0] = acc[0]; Sc[i][jq + 1] = acc[1];
        Sc[i][jq + 2] = acc[2]; Sc[i][jq + 3] = acc[3];
        *(float4*)&Sin[(size_t)(h * 16 + g) * 4096 + (size_t)i * 64 + jq] =
            make_float4(acc[0], acc[1], acc[2], acc[3]);
        pv = pv2; sv = sv2;
    }
}

// ---------------------------------------------------------------------------
// WKV7 segmented scan, pass 2. Grid (16 segs, 32 heads) = 512 blocks (2/CU,
// 2 waves/SIMD). 256 thr (4 waves x 16 rows; 4 row-states/lane). Replay
// 64-step segment from exact Sin(h,g), emit Y as float4.
// ---------------------------------------------------------------------------
__global__ __launch_bounds__(256) void k_wkv_p2(
    const float* __restrict__ R, const float* __restrict__ DEC,
    const float* __restrict__ K, const float* __restrict__ V,
    const float* __restrict__ KK, const float* __restrict__ Bb,
    const float* __restrict__ Sin, float* __restrict__ Y)
{
    const int tid = threadIdx.x;
    const int g = blockIdx.x;                  // segment 0..15
    const int h = blockIdx.y;
    const int c0 = h * 64;
    const int wv = tid >> 6, lane = tid & 63;
    const int jg = lane & 15, q = lane >> 4, j4 = jg * 4;
    const int row0 = wv * 16 + q * 4;          // rows row0..row0+3

    __shared__ __align__(16) float rS[2][16][64], dS[2][16][64], kS[2][16][64],
                                   aS[2][16][64], bS[2][16][64], vS[2][16][64];

    const int pst = tid >> 4, pq4 = (tid & 15) * 4;

#define P2_STAGE(buf, tcb) do {                                               \
    size_t gg = (size_t)((tcb) + pst) * C_ + c0 + pq4;                        \
    async_cp16(&R[gg],   &rS[buf][pst][pq4]);                                 \
    async_cp16(&DEC[gg], &dS[buf][pst][pq4]);                                 \
    async_cp16(&K[gg],   &kS[buf][pst][pq4]);                                 \
    async_cp16(&V[gg],   &vS[buf][pst][pq4]);                                 \
    async_cp16(&KK[gg],  &aS[buf][pst][pq4]);                                 \
    async_cp16(&Bb[gg],  &bS[buf][pst][pq4]);                                 \
} while (0)

    float4 s0, s1, s2, s3;
    {
        const float* Sb = &Sin[(size_t)((h * 16 + g) * 64 + row0) * 64 + j4];
        s0 = *(const float4*)&Sb[0];
        s1 = *(const float4*)&Sb[64];
        s2 = *(const float4*)&Sb[128];
        s3 = *(const float4*)&Sb[192];
    }

    const int t0 = g * 64;
    P2_STAGE(0, t0);

    for (int tc = 0; tc < 64; tc += 16) {
        const int p = (tc >> 4) & 1;
        __syncthreads();                               // buf p ready
        if (tc + 16 < 64) P2_STAGE(p ^ 1, t0 + tc + 16);
#pragma unroll
        for (int hh = 0; hh < 2; ++hh) {
            float po0[8], po1[8], po2[8], po3[8];
#pragma unroll
            for (int qs2 = 0; qs2 < 8; ++qs2) {
                const int tt = hh * 8 + qs2;
                float4 cr = *(float4*)&rS[p][tt][j4];
                float4 cd = *(float4*)&dS[p][tt][j4];
                float4 ck = *(float4*)&kS[p][tt][j4];
                float4 ca = *(float4*)&aS[p][tt][j4];
                float4 cb = *(float4*)&bS[p][tt][j4];
                float4 vv = *(float4*)&vS[p][tt][row0];
                float sa0 = -(fmaf(s0.y, ca.y, s0.x * ca.x) + fmaf(s0.w, ca.w, s0.z * ca.z));
                float sa1 = -(fmaf(s1.y, ca.y, s1.x * ca.x) + fmaf(s1.w, ca.w, s1.z * ca.z));
                float sa2 = -(fmaf(s2.y, ca.y, s2.x * ca.x) + fmaf(s2.w, ca.w, s2.z * ca.z));
                float sa3 = -(fmaf(s3.y, ca.y, s3.x * ca.x) + fmaf(s3.w, ca.w, s3.z * ca.z));
                REDUCE16(sa0); REDUCE16(sa1); REDUCE16(sa2); REDUCE16(sa3);
                s0.x = fmaf(s0.x, cd.x, fmaf(sa0, cb.x, vv.x * ck.x));
                s0.y = fmaf(s0.y, cd.y, fmaf(sa0, cb.y, vv.x * ck.y));
                s0.z = fmaf(s0.z, cd.z, fmaf(sa0, cb.z, vv.x * ck.z));
                s0.w = fmaf(s0.w, cd.w, fmaf(sa0, cb.w, vv.x * ck.w));
                s1.x = fmaf(s1.x, cd.x, fmaf(sa1, cb.x, vv.y * ck.x));
                s1.y = fmaf(s1.y, cd.y, fmaf(sa1, cb.y, vv.y * ck.y));
                s1.z = fmaf(s1.z, cd.z, fmaf(sa1, cb.z, vv.y * ck.z));
                s1.w = fmaf(s1.w, cd.w, fmaf(sa1, cb.w, vv.y * ck.w));
                s2.x = fmaf(s2.x, cd.x, fmaf(sa2, cb.x, vv.z * ck.x));
                s2.y = fmaf(s2.y, cd.y, fmaf(sa2, cb.y, vv.z * ck.y));
                s2.z = fmaf(s2.z, cd.z, fmaf(sa2, cb.z, vv.z * ck.z));
                s2.w = fmaf(s2.w, cd.w, fmaf(sa2, cb.w, vv.z * ck.w));
                s3.x = fmaf(s3.x, cd.x, fmaf(sa3, cb.x, vv.w * ck.x));
                s3.y = fmaf(s3.y, cd.y, fmaf(sa3, cb.y, vv.w * ck.y));
                s3.z = fmaf(s3.z, cd.z, fmaf(sa3, cb.z, vv.w * ck.z));
                s3.w = fmaf(s3.w, cd.w, fmaf(sa3, cb.w, vv.w * ck.w));
                po0[qs2] = fmaf(s0.w, cr.w, fmaf(s0.z, cr.z, fmaf(s0.y, cr.y, s0.x * cr.x)));
                po1[qs2] = fmaf(s1.w, cr.w, fmaf(s1.z, cr.z, fmaf(s1.y, cr.y, s1.x * cr.x)));
                po2[qs2] = fmaf(s2.w, cr.w, fmaf(s2.z, cr.z, fmaf(s2.y, cr.y, s2.x * cr.x)));
                po3[qs2] = fmaf(s3.w, cr.w, fmaf(s3.z, cr.z, fmaf(s3.y, cr.y, s3.x * cr.x)));
            }
            // deferred: 32 independent DPP butterflies pipeline
#pragma unroll
            for (int qs2 = 0; qs2 < 8; ++qs2) {
                REDUCE16(po0[qs2]); REDUCE16(po1[qs2]);
                REDUCE16(po2[qs2]); REDUCE16(po3[qs2]);
            }
            if (jg == 0) {
#pragma unroll
                for (int qs2 = 0; qs2 < 8; ++qs2) {
                    float4 o = make_float4(po0[qs2], po1[qs2], po2[qs2], po3[qs2]);
                    *(float4*)&Y[(size_t)(t0 + tc + hh * 8 + qs2) * C_ + c0 + row0] = o;
                }
            }
        }
    }
#undef P2_STAGE
}

// ---------------------------------------------------------------------------
// GroupNorm + bonus + fused gate, t-tiled (16 t/block so the 128 gw2 loads
// amortize): YG = f16((gn(y) + bonus) * (tanh(l2 sum) @ gate_w2)).
// ---------------------------------------------------------------------------
__global__ __launch_bounds__(256) void k_gn(
    const float* __restrict__ Y, const float* __restrict__ R, const float* __restrict__ K,
    const float* __restrict__ V, const float* __restrict__ l2p,
    const float* __restrict__ gw2,
    const float* __restrict__ faaaa, const float* __restrict__ lnw,
    const float* __restrict__ lnb, _Float16* __restrict__ YG)
{
    const int tid = threadIdx.x;
    const int c = blockIdx.x * 256 + tid;
    const int t0 = blockIdx.y * 16;
    const size_t P = (size_t)T_ * 256;
    __shared__ __align__(16) float gs[16][128];
    for (int id = tid; id < 16 * 128; id += 256) {
        int r = id >> 7, cc = id & 127;
        size_t off = (size_t)(t0 + r) * 256 + cc;
        float v = ((l2p[off] + l2p[P + off]) + l2p[2 * P + off]) + l2p[3 * P + off];
        gs[r][cc] = tanhf(v);
    }
    __syncthreads();
    float gacc[16];
#pragma unroll
    for (int r = 0; r < 16; ++r) gacc[r] = 0.f;
    for (int j = 0; j < 128; ++j) {
        float w = gw2[(size_t)j * C_ + c];
#pragma unroll
        for (int r = 0; r < 16; ++r) gacc[r] = fmaf(gs[r][j], w, gacc[r]);
    }
    float fa = faaaa[c], lw = lnw[c], lb = lnb[c];
    for (int r = 0; r < 16; ++r) {
        const size_t idx = (size_t)(t0 + r) * C_ + c;
        float y = Y[idx];
        float s1 = y, s2 = y * y;
#pragma unroll
        for (int off = 1; off < 64; off <<= 1) {
            s1 += __shfl_xor(s1, off, 64);
            s2 += __shfl_xor(s2, off, 64);
        }
        float mu = s1 * (1.0f / 64.0f);
        float var = s2 * (1.0f / 64.0f) - mu * mu;
        float gn = (y - mu) * rsqrtf(var + 0.00064f) * lw + lb;
        float p = R[idx] * K[idx] * fa;
#pragma unroll
        for (int off = 1; off < 64; off <<= 1) p += __shfl_xor(p, off, 64);
        float y2 = gn + p * V[idx];
        YG[idx] = (_Float16)(y2 * gacc[r]);
    }
}

// ---------------------------------------------------------------------------
extern "C" void kernel_launch(void* const* d_in, const int* in_sizes, int n_in,
                              void* d_out, int out_size, void* d_ws, size_t ws_size,
                              hipStream_t stream)
{
    (void)in_sizes; (void)n_in; (void)out_size; (void)ws_size;
    const float* hidden   = (const float*)d_in[0];
    const float* Wq       = (const float*)d_in[1];
    const float* Wk       = (const float*)d_in[2];
    const float* Wv       = (const float*)d_in[3];
    const float* Wo       = (const float*)d_in[4];
    const float* maa_x    = (const float*)d_in[5];
    const float* maa_rg   = (const float*)d_in[6];
    const float* maa_wa   = (const float*)d_in[7];
    const float* maa_k    = (const float*)d_in[8];
    const float* maa_v    = (const float*)d_in[9];
    const float* maa_w1   = (const float*)d_in[10];
    const float* maa_w2   = (const float*)d_in[11];
    const float* tdecay   = (const float*)d_in[12];
    const float* decay_w1 = (const float*)d_in[13];
    const float* decay_w2 = (const float*)d_in[14];
    const float* aaaaa    = (const float*)d_in[15];
    const float* aaa_w1   = (const float*)d_in[16];
    const float* aaa_w2   = (const float*)d_in[17];
    const float* kkk_w1   = (const float*)d_in[18];
    const float* kkk_w2   = (const float*)d_in[19];
    const float* gate_w1  = (const float*)d_in[20];
    const float* gate_w2  = (const float*)d_in[21];
    const float* misc_a   = (const float*)d_in[22];
    const float* ma_w1    = (const float*)d_in[23];
    const float* ma_w2    = (const float*)d_in[24];
    const float* misc_k   = (const float*)d_in[25];
    const float* mk_w1    = (const float*)d_in[26];
    const float* mk_w2    = (const float*)d_in[27];
    const float* faaaa    = (const float*)d_in[28];
    const float* lnw      = (const float*)d_in[29];
    const float* lnb      = (const float*)d_in[30];

    float* ws = (float*)d_ws;
    const size_t TC = (size_t)T_ * C_;
    // f32 buffers:
    //   S0: y   S2: b   S3: kk   S4: r   S5: dec   S6: k0 -> k   S7: v
    //   S1 slot (8MB): Send [32][15][64][64] f32 (7.5 MB)
    float* S0 = ws + 0 * TC;
    float* Send = ws + 1 * TC;
    float* S2 = ws + 2 * TC;
    float* S3 = ws + 3 * TC;
    float* S4 = ws + 4 * TC;
    float* S5 = ws + 5 * TC;
    float* S6 = ws + 6 * TC;
    float* S7 = ws + 7 * TC;
    float* m1p = ws + 8 * TC;                    // [4][T][128] partials
    float* l2p = m1p + (size_t)4 * T_ * 128;     // [4][T][256] partials
    // f16 region
    _Float16* WTq = (_Float16*)(l2p + (size_t)4 * T_ * 256);
    _Float16* WTk = WTq + (size_t)C_ * C_;
    _Float16* WTv = WTk + (size_t)C_ * C_;
    _Float16* WTo = WTv + (size_t)C_ * C_;
    _Float16* WTm = WTo + (size_t)C_ * C_;       // [128,2048]
    _Float16* WTl = WTm + (size_t)128 * C_;      // [256,2048]
    _Float16* xxxH = WTl + (size_t)256 * C_;
    _Float16* xrgH = xxxH + TC;
    _Float16* xwaH = xrgH + TC;
    _Float16* xkH  = xwaH + TC;
    _Float16* xvH  = xkH + TC;
    _Float16* ygH  = xxxH;                       // xxxH dead after step 4
    // After step 4, xrgH..xvH (16 MB contiguous f16 scratch) die post-scan:
    //   Sin  [32][16][64][64] f32 = 8 MB exactly -> xrgH+xwaH
    //   Pend [32][15][64][64] f32 = 7.5 MB       -> xkH+xvH
    float* Sin  = (float*)xrgH;
    float* Pend = (float*)xkH;
    // After p2/gn: S2 and Sin regions dead -> step-9 split-K partials.
    float* GP0 = S2;
    float* GP1 = Sin;
    float* out = (float*)d_out;

    // 1. pack+transpose LoRA weights (z=0/1) + fused xxxH prep (z=2)
    k_trW<<<dim3(8, 256, 3), 256, 0, stream>>>(maa_w1, gate_w1, decay_w1,
        aaa_w1, ma_w1, kkk_w1, mk_w1, hidden, maa_x, WTm, WTl, xxxH);
    // 2. COMBINED: big-weight transposes (z<4) + m1 partials (z=4)
    k_trlora<<<dim3(32, 32, 5), 256, 0, stream>>>(Wq, Wk, Wv, Wo,
        WTq, WTk, WTv, WTo, xxxH, WTm, m1p);
    // 3. xmix -> f16 operands
    k_xmix<<<dim3(8, 64), 256, 0, stream>>>(hidden, m1p, maa_w2,
        maa_rg, maa_wa, maa_k, maa_v, xrgH, xwaH, xkH, xvH);
    // 4. COMBINED: r/k0/v GEMMs (z<3, 384 blocks) + l2 partials (z in
    //    [3,7), 512 blocks) — mutually independent, both feed k_fuse.
    k_gemmlora<<<dim3(16, 8, 7), 256, 0, stream>>>(
        xrgH, WTq, S4,  xkH, WTk, S6,  xvH, WTv, S7,
        xrgH, xwaH, xkH, WTl, l2p);
    // 5. fused stage-2: dec, kk (normalized), b, k_final (t-tile 4)
    k_fuse<<<dim3(8, 256), 256, 0, stream>>>(l2p, S6, decay_w2, aaa_w2, ma_w2,
        kkk_w2, mk_w2, tdecay, aaaaa, misc_a, misc_k, S5, S3, S2);
    // 6. WKV7 segmented scan (16 segments of 64 steps):
    k_wkv_p1<<<dim3(15, 32), 512, 0, stream>>>(S5, S6, S7, S3, S2, Send, Pend);
    k_wkv_comb<<<dim3(32), 1024, 0, stream>>>(Send, Pend, Sin);
    k_wkv_p2<<<dim3(16, 32), 256, 0, stream>>>(S4, S5, S6, S7, S3, S2, Sin, S0);
    // 7. groupnorm + bonus + fused gate -> f16 (reuses xxxH slot)
    k_gn<<<dim3(8, 64), 256, 0, stream>>>(S0, S4, S6, S7, l2p, gate_w2,
        faaaa, lnw, lnb, ygH);
    // 8. out = (y*g) @ Wo, split-K=2 (512 blocks = 2/CU) + reduce
    k_gemm64<<<dim3(32, 8, 2), 256, 0, stream>>>(ygH, WTo, GP0, GP1);
    k_red<<<dim3(2048), 256, 0, stream>>>(GP0, GP1, out);
}